// Round 8
// baseline (249.873 us; speedup 1.0000x reference)
//
#include <hip/hip_runtime.h>
#include <hip/hip_bf16.h>

#define HW 3136
#define NB 16

typedef float f32x4 __attribute__((ext_vector_type(4)));
typedef short short8 __attribute__((ext_vector_type(8)));

__device__ inline unsigned short bfb(float f) {
  union { __hip_bfloat16 h; unsigned short u; } cv;
  cv.h = __float2bfloat16(f);
  return cv.u;
}
__device__ inline unsigned pack2(float lo, float hi) {
  return (unsigned)bfb(lo) | ((unsigned)bfb(hi) << 16);
}
// order-preserving float<->uint encode for atomicMax
__device__ inline unsigned fenc(float f) {
  unsigned u = __float_as_uint(f);
  return (u & 0x80000000u) ? ~u : (u | 0x80000000u);
}
__device__ inline float fdec(unsigned e) {
  return (e & 0x80000000u) ? __uint_as_float(e & 0x7FFFFFFFu) : __uint_as_float(~e);
}
__device__ inline float bf2f(unsigned short u) {
  return __uint_as_float((unsigned)u << 16);
}

// ---------------- K0: convert W to bf16, zero pool buffers ----------------
__global__ __launch_bounds__(256) void k0_init(const float* __restrict__ conv_w,
                                               unsigned short* __restrict__ Wbf,
                                               float* __restrict__ psum,
                                               unsigned* __restrict__ pmaxe) {
  int i = blockIdx.x * 256 + threadIdx.x;
  Wbf[i] = bfb(conv_w[i]);
  if (i < 4096) psum[i] = 0.f;
  else if (i < 8192) pmaxe[i - 4096] = 0u;
}

// ---------------- K1: conv1x1 + bias + GELU -> h (bf16) ; fused channel pooling ----------------
__global__ __launch_bounds__(256) void k1_conv_gelu_pool(
    const float* __restrict__ x, const unsigned short* __restrict__ Wbf,
    const float* __restrict__ conv_b, unsigned short* __restrict__ h_out,
    float* __restrict__ psum, unsigned* __restrict__ pmaxe)
{
  __shared__ __align__(16) unsigned short Bs[64 * 264];
  const int bid = blockIdx.x;
  const int b = bid / 49, tile = bid - 49 * (bid / 49);
  const int hw0 = tile * 64;
  const int t = threadIdx.x;

  {
    int g = t & 127, half = t >> 7;
    const float* p0 = x + ((size_t)(b * 256 + 2 * g)) * HW + hw0 + half * 32;
    const float* p1 = p0 + HW;
    unsigned* Bd = (unsigned*)Bs;
#pragma unroll
    for (int i = 0; i < 32; i += 4) {
      float4 a4 = *(const float4*)(p0 + i);
      float4 c4 = *(const float4*)(p1 + i);
      int hw = half * 32 + i;
      Bd[(hw + 0) * 132 + g] = pack2(a4.x, c4.x);
      Bd[(hw + 1) * 132 + g] = pack2(a4.y, c4.y);
      Bd[(hw + 2) * 132 + g] = pack2(a4.z, c4.z);
      Bd[(hw + 3) * 132 + g] = pack2(a4.w, c4.w);
    }
  }
  __syncthreads();

  const int w = t >> 6, l = t & 63, hq = l & 15, g2 = l >> 4;
  const int wm0 = w * 64;
  const f32x4 vzero = {0.f, 0.f, 0.f, 0.f};
  f32x4 acc[4][4];
#pragma unroll
  for (int mi = 0; mi < 4; ++mi)
#pragma unroll
    for (int ni = 0; ni < 4; ++ni) acc[mi][ni] = vzero;

#pragma unroll
  for (int ks = 0; ks < 8; ++ks) {
    short8 a[4], bv[4];
#pragma unroll
    for (int mi = 0; mi < 4; ++mi)
      a[mi] = *(const short8*)(Wbf + (size_t)(wm0 + mi * 16 + hq) * 256 + ks * 32 + g2 * 8);
#pragma unroll
    for (int ni = 0; ni < 4; ++ni)
      bv[ni] = *(const short8*)(Bs + (ni * 16 + hq) * 264 + ks * 32 + g2 * 8);
#pragma unroll
    for (int mi = 0; mi < 4; ++mi)
#pragma unroll
      for (int ni = 0; ni < 4; ++ni)
        acc[mi][ni] = __builtin_amdgcn_mfma_f32_16x16x32_bf16(a[mi], bv[ni], acc[mi][ni], 0, 0, 0);
  }

#pragma unroll
  for (int mi = 0; mi < 4; ++mi) {
#pragma unroll
    for (int r = 0; r < 4; ++r) {
      int o = wm0 + mi * 16 + g2 * 4 + r;
      float bias = conv_b[o];
      float v[4];
#pragma unroll
      for (int ni = 0; ni < 4; ++ni) {
        float s = acc[mi][ni][r] + bias;
        v[ni] = 0.5f * s * (1.0f + erff(s * 0.70710678118654752f));
      }
      unsigned short* hp = h_out + ((size_t)(b * 256 + o)) * HW + hw0;
      hp[0 * 16 + hq] = bfb(v[0]);
      hp[1 * 16 + hq] = bfb(v[1]);
      hp[2 * 16 + hq] = bfb(v[2]);
      hp[3 * 16 + hq] = bfb(v[3]);
      float sm = v[0] + v[1] + v[2] + v[3];
      float mx = fmaxf(fmaxf(v[0], v[1]), fmaxf(v[2], v[3]));
#pragma unroll
      for (int d = 1; d < 16; d <<= 1) {
        sm += __shfl_xor(sm, d);
        mx = fmaxf(mx, __shfl_xor(mx, d));
      }
      if (hq == 0) {
        atomicAdd(psum + b * 256 + o, sm);
        atomicMax(pmaxe + b * 256 + o, fenc(mx));
      }
    }
  }
}

// ---------------- K2: channel attention FCs ----------------
__global__ __launch_bounds__(256) void k2_att(
    const float* __restrict__ psum, const unsigned* __restrict__ pmaxe,
    const float* __restrict__ fc1_w, const float* __restrict__ fc1_b,
    const float* __restrict__ fc2_w, const float* __restrict__ fc2_b,
    float* __restrict__ att)
{
  int b = blockIdx.x, t = threadIdx.x;
  __shared__ float hA[64], hM[64];
  if (t < 128) {
    int j = t & 63;
    bool ism = t >= 64;
    float s = fc1_b[j];
    for (int c = 0; c < 256; ++c) {
      float p = ism ? fdec(pmaxe[b * 256 + c]) : (psum[b * 256 + c] * (1.f / 3136.f));
      s += p * fc1_w[j * 256 + c];
    }
    s = fmaxf(s, 0.f);
    if (ism) hM[j] = s; else hA[j] = s;
  }
  __syncthreads();
  float s1 = fc2_b[t], s2 = s1;
  for (int j = 0; j < 64; ++j) {
    float wv = fc2_w[t * 64 + j];
    s1 += hA[j] * wv;
    s2 += hM[j] * wv;
  }
  att[b * 256 + t] = 1.f / (1.f + expf(-s1)) + 1.f / (1.f + expf(-s2));
}

// ---------------- K34 v7: fused depthwise chain, one plane per block ----------------
// LDS ~40.3KB -> 4 blocks/CU (LDS is the occupancy binder; VGPR free to ~128, NO launch_bounds cap)
//   B0 fp32 [4256]: P0 halo h [60][60]; after P1 barrier rewritten as
//        x_init fp32 [56][76] (data cols 10..65, pads 0)
//   T1/T2/T3 bf16 row-major [62|66|76][56], vertical pad rows zeroed once
// Tasks: P1/P2/PA: 392 ROW tasks (1 y x 8 cols) -> b128 LDS reads/writes
//        PB: 196 COLUMN-PAIR tasks (8 rows x 2 cols) -> b32 packed reads (2 bf16/instr)
__global__ __launch_bounds__(256) void k34_dw(
    const unsigned short* __restrict__ h_in, const float* __restrict__ att,
    const float* __restrict__ w5, const float* __restrict__ b5,
    const float* __restrict__ w1x7, const float* __restrict__ b1x7,
    const float* __restrict__ w7x1, const float* __restrict__ b7x1,
    const float* __restrict__ w1x11, const float* __restrict__ b1x11,
    const float* __restrict__ w11x1, const float* __restrict__ b11x1,
    const float* __restrict__ w1x21, const float* __restrict__ b1x21,
    const float* __restrict__ w21x1, const float* __restrict__ b21x1,
    unsigned short* __restrict__ xs_out)
{
  __shared__ __align__(16) float B0[4256];
  __shared__ __align__(16) unsigned short T1[62 * 56];  // r = y+3
  __shared__ __align__(16) unsigned short T2[66 * 56];  // r = y+5
  __shared__ __align__(16) unsigned short T3[76 * 56];  // r = y+10
  __shared__ __align__(16) float wk5a[25];
  __shared__ __align__(16) float wk[78]; // [0,7)w1x7 [7,14)w7x1 [14,25)w1x11 [25,36)w11x1 [36,57)w1x21 [57,78)w21x1

  const int bid = blockIdx.x;
  const int b = bid >> 8, c = bid & 255;
  const int t = threadIdx.x;
  const size_t plane = (size_t)(b * 256 + c) * HW;
  const float a = att[b * 256 + c];

  if (t < 25) wk5a[t] = w5[c * 25 + t] * a;   // fold channel attention into dw5x5 weights
  if (t >= 32 && t < 110) {
    int k = t - 32;
    float v;
    if (k < 7) v = w1x7[c * 7 + k];
    else if (k < 14) v = w7x1[c * 7 + k - 7];
    else if (k < 25) v = w1x11[c * 11 + k - 14];
    else if (k < 36) v = w11x1[c * 11 + k - 25];
    else if (k < 57) v = w1x21[c * 21 + k - 36];
    else v = w21x1[c * 21 + k - 57];
    wk[k] = v;
  }
  { // zero vertical pad rows of T1/T2/T3 (once; PA never writes them)
    unsigned* T1d = (unsigned*)T1; unsigned* T2d = (unsigned*)T2; unsigned* T3d = (unsigned*)T3;
    for (int i = t; i < 1008; i += 256) {
      if (i < 84) T1d[i] = 0;                       // rows 0..2
      else if (i < 168) T1d[1652 + i - 84] = 0;     // rows 59..61
      else if (i < 308) T2d[i - 168] = 0;           // rows 0..4
      else if (i < 448) T2d[1708 + i - 308] = 0;    // rows 61..65
      else if (i < 728) T3d[i - 448] = 0;           // rows 0..9
      else T3d[1848 + i - 728] = 0;                 // rows 66..75
    }
  }
  { // P0: stage halo'd h (rows/cols -2..57) into B0[60][60] fp32 (cvt once here)
    const unsigned short* hp = h_in + plane;
    for (int idx = t; idx < 3600; idx += 256) {
      int ly = idx / 60, lx = idx - ly * 60;
      int gy = ly - 2, gx = lx - 2;
      float v = 0.f;
      if ((unsigned)gy < 56u && (unsigned)gx < 56u) v = bf2f(hp[gy * 56 + gx]);
      B0[idx] = v;
    }
  }
  __syncthreads();

  // P1: dw5x5 -> registers, ROW tasks (y, x0..x0+7), float4 window reads.
  float xr0[8], xr1[8];
  const float bias5 = b5[c];
#pragma unroll
  for (int rnd = 0; rnd < 2; ++rnd) {
    if (rnd == 1 && t >= 136) break;
    int tau = t + rnd * 256;
    int y = tau / 7, x0 = (tau - y * 7) * 8;
    float accv[8];
#pragma unroll
    for (int d = 0; d < 8; ++d) accv[d] = bias5;
#pragma unroll
    for (int ky = 0; ky < 5; ++ky) {
      float col[12];
      const float* rp = B0 + (y + ky) * 60 + x0;
#pragma unroll
      for (int j = 0; j < 12; j += 4) {
        float4 q = *(const float4*)(rp + j);
        col[j] = q.x; col[j + 1] = q.y; col[j + 2] = q.z; col[j + 3] = q.w;
      }
#pragma unroll
      for (int kx = 0; kx < 5; ++kx) {
        float wv = wk5a[ky * 5 + kx];
#pragma unroll
        for (int d = 0; d < 8; ++d) accv[d] += col[kx + d] * wv;
      }
    }
    if (rnd == 0) {
#pragma unroll
      for (int d = 0; d < 8; ++d) xr0[d] = accv[d];
    } else {
#pragma unroll
      for (int d = 0; d < 8; ++d) xr1[d] = accv[d];
    }
  }
  __syncthreads();

  // P2: rewrite B0 as padded x_init fp32 [56][76] (data at col+10), zero col pads.
#pragma unroll
  for (int rnd = 0; rnd < 2; ++rnd) {
    if (rnd == 1 && t >= 136) break;
    int tau = t + rnd * 256;
    int y = tau / 7, x0 = (tau - y * 7) * 8;
    float* wp = B0 + y * 76 + 10 + x0;
    const float* src = (rnd == 0) ? xr0 : xr1;
#pragma unroll
    for (int j = 0; j < 8; j += 2) {
      float2 q; q.x = src[j]; q.y = src[j + 1];
      *(float2*)(wp + j) = q;
    }
  }
  for (int i = t; i < 1120; i += 256) {
    int y = i / 20, j = i - y * 20;
    int lx = (j < 10) ? j : (56 + j);   // pads: cols 0..9 and 66..75 (data at 10..65)
    B0[y * 76 + lx] = 0.f;
  }
  __syncthreads();

  // PA: fused horizontal convs. ROW task (y, x0..x0+7). win = x_init[y][x0-10..x0+17].
  const float bb1 = b1x7[c], bb2 = b1x11[c], bb3 = b1x21[c];
#pragma unroll
  for (int rnd = 0; rnd < 2; ++rnd) {
    if (rnd == 1 && t >= 136) break;
    int tau = t + rnd * 256;
    int y = tau / 7, x0 = (tau - y * 7) * 8;
    float win[28];
    const float* rp = B0 + y * 76 + x0;
#pragma unroll
    for (int j = 0; j < 28; j += 4) {
      float4 q = *(const float4*)(rp + j);
      win[j] = q.x; win[j + 1] = q.y; win[j + 2] = q.z; win[j + 3] = q.w;
    }
    float o1[8], o2[8], o3[8];
#pragma unroll
    for (int d = 0; d < 8; ++d) { o1[d] = bb1; o2[d] = bb2; o3[d] = bb3; }
#pragma unroll
    for (int k = 0; k < 7; ++k) {
      float wv = wk[k];
#pragma unroll
      for (int d = 0; d < 8; ++d) o1[d] += win[d + k + 7] * wv;
    }
#pragma unroll
    for (int k = 0; k < 11; ++k) {
      float wv = wk[14 + k];
#pragma unroll
      for (int d = 0; d < 8; ++d) o2[d] += win[d + k + 5] * wv;
    }
#pragma unroll
    for (int k = 0; k < 21; ++k) {
      float wv = wk[36 + k];
#pragma unroll
      for (int d = 0; d < 8; ++d) o3[d] += win[d + k] * wv;
    }
    uint4 s1, s2, s3;
    s1.x = pack2(o1[0], o1[1]); s1.y = pack2(o1[2], o1[3]); s1.z = pack2(o1[4], o1[5]); s1.w = pack2(o1[6], o1[7]);
    s2.x = pack2(o2[0], o2[1]); s2.y = pack2(o2[2], o2[3]); s2.z = pack2(o2[4], o2[5]); s2.w = pack2(o2[6], o2[7]);
    s3.x = pack2(o3[0], o3[1]); s3.y = pack2(o3[2], o3[3]); s3.z = pack2(o3[4], o3[5]); s3.w = pack2(o3[6], o3[7]);
    *(uint4*)&T1[(y + 3) * 56 + x0] = s1;
    *(uint4*)&T2[(y + 5) * 56 + x0] = s2;
    *(uint4*)&T3[(y + 10) * 56 + x0] = s3;
  }
  __syncthreads();

  // PB: fused vertical convs + x_init add -> global bf16 store.
  // COLUMN-PAIR task: (8 rows y0..y0+7) x (2 cols x0,x0+1); 196 tasks, 1 round.
  // T reads are packed b32 (2 bf16); unpack via shift/mask (no cvt).
  const float vb = b7x1[c] + b11x1[c] + b21x1[c];
  unsigned short* op = xs_out + plane;
  if (t < 196) {
    int band = t / 28, xp = t - band * 28;
    int y0 = band * 8, x0 = xp * 2;
    float rlo[8], rhi[8];
#pragma unroll
    for (int d = 0; d < 8; ++d) {
      float2 q = *(const float2*)&B0[(y0 + d) * 76 + 10 + x0];
      rlo[d] = q.x + vb; rhi[d] = q.y + vb;
    }
    {
      float clo[14], chi[14];
#pragma unroll
      for (int j = 0; j < 14; ++j) {
        unsigned q = *(const unsigned*)&T1[(y0 + j) * 56 + x0];
        clo[j] = __uint_as_float(q << 16);
        chi[j] = __uint_as_float(q & 0xffff0000u);
      }
#pragma unroll
      for (int k = 0; k < 7; ++k) {
        float wv = wk[7 + k];
#pragma unroll
        for (int d = 0; d < 8; ++d) { rlo[d] += clo[d + k] * wv; rhi[d] += chi[d + k] * wv; }
      }
    }
    {
      float clo[18], chi[18];
#pragma unroll
      for (int j = 0; j < 18; ++j) {
        unsigned q = *(const unsigned*)&T2[(y0 + j) * 56 + x0];
        clo[j] = __uint_as_float(q << 16);
        chi[j] = __uint_as_float(q & 0xffff0000u);
      }
#pragma unroll
      for (int k = 0; k < 11; ++k) {
        float wv = wk[25 + k];
#pragma unroll
        for (int d = 0; d < 8; ++d) { rlo[d] += clo[d + k] * wv; rhi[d] += chi[d + k] * wv; }
      }
    }
    {
      float clo[28], chi[28];
#pragma unroll
      for (int j = 0; j < 28; ++j) {
        unsigned q = *(const unsigned*)&T3[(y0 + j) * 56 + x0];
        clo[j] = __uint_as_float(q << 16);
        chi[j] = __uint_as_float(q & 0xffff0000u);
      }
#pragma unroll
      for (int k = 0; k < 21; ++k) {
        float wv = wk[57 + k];
#pragma unroll
        for (int d = 0; d < 8; ++d) { rlo[d] += clo[d + k] * wv; rhi[d] += chi[d + k] * wv; }
      }
    }
#pragma unroll
    for (int d = 0; d < 8; ++d)
      *(unsigned*)&op[(y0 + d) * 56 + x0] = pack2(rlo[d], rhi[d]);
  }
}

// ---------------- K5: spatial_att = W*xs+b ; out = sa*(att*h) ; result = W*out+b ----------------
__global__ __launch_bounds__(256) void k5_final(
    const unsigned short* __restrict__ xs, const unsigned short* __restrict__ Wbf,
    const float* __restrict__ conv_b, const float* __restrict__ att,
    const unsigned short* __restrict__ h_in, float* __restrict__ outp)
{
  __shared__ __align__(16) unsigned short Bs[64 * 264];
  const int bid = blockIdx.x;
  const int b = bid / 49, tile = bid - 49 * (bid / 49);
  const int hw0 = tile * 64;
  const int t = threadIdx.x;

  { // stage xs (already bf16) transposed into LDS, no converts
    int g = t & 127, half = t >> 7;
    const unsigned short* p0 = xs + ((size_t)(b * 256 + 2 * g)) * HW + hw0 + half * 32;
    const unsigned short* p1 = p0 + HW;
    unsigned* Bd = (unsigned*)Bs;
#pragma unroll
    for (int i = 0; i < 32; i += 4) {
      ushort4 a4 = *(const ushort4*)(p0 + i);
      ushort4 c4 = *(const ushort4*)(p1 + i);
      int hw = half * 32 + i;
      Bd[(hw + 0) * 132 + g] = (unsigned)a4.x | ((unsigned)c4.x << 16);
      Bd[(hw + 1) * 132 + g] = (unsigned)a4.y | ((unsigned)c4.y << 16);
      Bd[(hw + 2) * 132 + g] = (unsigned)a4.z | ((unsigned)c4.z << 16);
      Bd[(hw + 3) * 132 + g] = (unsigned)a4.w | ((unsigned)c4.w << 16);
    }
  }
  __syncthreads();

  const int w = t >> 6, l = t & 63, hq = l & 15, g2 = l >> 4;
  const int wm0 = w * 64;
  const f32x4 vzero = {0.f, 0.f, 0.f, 0.f};
  f32x4 acc[4][4];
#pragma unroll
  for (int mi = 0; mi < 4; ++mi)
#pragma unroll
    for (int ni = 0; ni < 4; ++ni) acc[mi][ni] = vzero;

#pragma unroll
  for (int ks = 0; ks < 8; ++ks) {
    short8 a[4], bv[4];
#pragma unroll
    for (int mi = 0; mi < 4; ++mi)
      a[mi] = *(const short8*)(Wbf + (size_t)(wm0 + mi * 16 + hq) * 256 + ks * 32 + g2 * 8);
#pragma unroll
    for (int ni = 0; ni < 4; ++ni)
      bv[ni] = *(const short8*)(Bs + (ni * 16 + hq) * 264 + ks * 32 + g2 * 8);
#pragma unroll
    for (int mi = 0; mi < 4; ++mi)
#pragma unroll
      for (int ni = 0; ni < 4; ++ni)
        acc[mi][ni] = __builtin_amdgcn_mfma_f32_16x16x32_bf16(a[mi], bv[ni], acc[mi][ni], 0, 0, 0);
  }
  __syncthreads();

#pragma unroll
  for (int mi = 0; mi < 4; ++mi) {
#pragma unroll
    for (int r = 0; r < 4; ++r) {
      int o = wm0 + mi * 16 + g2 * 4 + r;
      float bias = conv_b[o];
      float av = att[b * 256 + o];
      const unsigned short* hp = h_in + ((size_t)(b * 256 + o)) * HW + hw0;
#pragma unroll
      for (int ni = 0; ni < 4; ++ni) {
        float sa = acc[mi][ni][r] + bias;
        float ov = sa * (av * bf2f(hp[ni * 16 + hq]));
        Bs[(ni * 16 + hq) * 264 + o] = bfb(ov);
      }
    }
  }
  __syncthreads();

  f32x4 acc2[4][4];
#pragma unroll
  for (int mi = 0; mi < 4; ++mi)
#pragma unroll
    for (int ni = 0; ni < 4; ++ni) acc2[mi][ni] = vzero;
#pragma unroll
  for (int ks = 0; ks < 8; ++ks) {
    short8 a[4], bv[4];
#pragma unroll
    for (int mi = 0; mi < 4; ++mi)
      a[mi] = *(const short8*)(Wbf + (size_t)(wm0 + mi * 16 + hq) * 256 + ks * 32 + g2 * 8);
#pragma unroll
    for (int ni = 0; ni < 4; ++ni)
      bv[ni] = *(const short8*)(Bs + (ni * 16 + hq) * 264 + ks * 32 + g2 * 8);
#pragma unroll
    for (int mi = 0; mi < 4; ++mi)
#pragma unroll
      for (int ni = 0; ni < 4; ++ni)
        acc2[mi][ni] = __builtin_amdgcn_mfma_f32_16x16x32_bf16(a[mi], bv[ni], acc2[mi][ni], 0, 0, 0);
  }

#pragma unroll
  for (int mi = 0; mi < 4; ++mi) {
#pragma unroll
    for (int r = 0; r < 4; ++r) {
      int o = wm0 + mi * 16 + g2 * 4 + r;
      float bias = conv_b[o];
      float* op = outp + ((size_t)(b * 256 + o)) * HW + hw0;
#pragma unroll
      for (int ni = 0; ni < 4; ++ni) op[ni * 16 + hq] = acc2[mi][ni][r] + bias;
    }
  }
}

extern "C" void kernel_launch(void* const* d_in, const int* in_sizes, int n_in,
                              void* d_out, int out_size, void* d_ws, size_t ws_size,
                              hipStream_t stream) {
  const float* x      = (const float*)d_in[0];
  const float* conv_w = (const float*)d_in[1];
  const float* conv_b = (const float*)d_in[2];
  const float* fc1_w  = (const float*)d_in[3];
  const float* fc1_b  = (const float*)d_in[4];
  const float* fc2_w  = (const float*)d_in[5];
  const float* fc2_b  = (const float*)d_in[6];
  const float* w5     = (const float*)d_in[7];
  const float* b5     = (const float*)d_in[8];
  const float* w1x7   = (const float*)d_in[9];
  const float* b1x7   = (const float*)d_in[10];
  const float* w7x1   = (const float*)d_in[11];
  const float* b7x1   = (const float*)d_in[12];
  const float* w1x11  = (const float*)d_in[13];
  const float* b1x11  = (const float*)d_in[14];
  const float* w11x1  = (const float*)d_in[15];
  const float* b11x1  = (const float*)d_in[16];
  const float* w1x21  = (const float*)d_in[17];
  const float* b1x21  = (const float*)d_in[18];
  const float* w21x1  = (const float*)d_in[19];
  const float* b21x1  = (const float*)d_in[20];
  float* out = (float*)d_out;

  char* ws = (char*)d_ws;
  unsigned short* Wbf = (unsigned short*)(ws);            // 131072 B
  float* psum   = (float*)(ws + 131072);                  // 16384 B
  unsigned* pme = (unsigned*)(ws + 147456);               // 16384 B
  float* attb   = (float*)(ws + 163840);                  // 16384 B
  unsigned short* hbuf = (unsigned short*)(ws + 180224);  // 25690112 B (h bf16)
  unsigned short* xbuf = (unsigned short*)(ws + 180224 + 25690112); // 25690112 B (xs bf16)

  k0_init<<<256, 256, 0, stream>>>(conv_w, Wbf, psum, pme);
  k1_conv_gelu_pool<<<784, 256, 0, stream>>>(x, Wbf, conv_b, hbuf, psum, pme);
  k2_att<<<16, 256, 0, stream>>>(psum, pme, fc1_w, fc1_b, fc2_w, fc2_b, attb);
  k34_dw<<<4096, 256, 0, stream>>>(hbuf, attb, w5, b5, w1x7, b1x7, w7x1, b7x1,
                                   w1x11, b1x11, w11x1, b11x1, w1x21, b1x21,
                                   w21x1, b21x1, xbuf);
  k5_final<<<784, 256, 0, stream>>>(xbuf, Wbf, conv_b, attb, hbuf, out);
}

// Round 9
// 226.481 us; speedup vs baseline: 1.1033x; 1.1033x over previous
//
#include <hip/hip_runtime.h>
#include <hip/hip_bf16.h>

#define HW 3136
#define NB 16

typedef float f32x4 __attribute__((ext_vector_type(4)));
typedef short short8 __attribute__((ext_vector_type(8)));

__device__ inline unsigned short bfb(float f) {
  union { __hip_bfloat16 h; unsigned short u; } cv;
  cv.h = __float2bfloat16(f);
  return cv.u;
}
__device__ inline unsigned pack2(float lo, float hi) {
  return (unsigned)bfb(lo) | ((unsigned)bfb(hi) << 16);
}
// order-preserving float<->uint encode for atomicMax
__device__ inline unsigned fenc(float f) {
  unsigned u = __float_as_uint(f);
  return (u & 0x80000000u) ? ~u : (u | 0x80000000u);
}
__device__ inline float fdec(unsigned e) {
  return (e & 0x80000000u) ? __uint_as_float(e & 0x7FFFFFFFu) : __uint_as_float(~e);
}
__device__ inline float bf2f(unsigned short u) {
  return __uint_as_float((unsigned)u << 16);
}

// ---------------- K0: convert W to bf16, zero pool buffers ----------------
__global__ __launch_bounds__(256) void k0_init(const float* __restrict__ conv_w,
                                               unsigned short* __restrict__ Wbf,
                                               float* __restrict__ psum,
                                               unsigned* __restrict__ pmaxe) {
  int i = blockIdx.x * 256 + threadIdx.x;
  Wbf[i] = bfb(conv_w[i]);
  if (i < 4096) psum[i] = 0.f;
  else if (i < 8192) pmaxe[i - 4096] = 0u;
}

// ---------------- K1: conv1x1 + bias + GELU -> h (bf16) ; fused channel pooling ----------------
__global__ __launch_bounds__(256) void k1_conv_gelu_pool(
    const float* __restrict__ x, const unsigned short* __restrict__ Wbf,
    const float* __restrict__ conv_b, unsigned short* __restrict__ h_out,
    float* __restrict__ psum, unsigned* __restrict__ pmaxe)
{
  __shared__ __align__(16) unsigned short Bs[64 * 264];
  const int bid = blockIdx.x;
  const int b = bid / 49, tile = bid - 49 * (bid / 49);
  const int hw0 = tile * 64;
  const int t = threadIdx.x;

  {
    int g = t & 127, half = t >> 7;
    const float* p0 = x + ((size_t)(b * 256 + 2 * g)) * HW + hw0 + half * 32;
    const float* p1 = p0 + HW;
    unsigned* Bd = (unsigned*)Bs;
#pragma unroll
    for (int i = 0; i < 32; i += 4) {
      float4 a4 = *(const float4*)(p0 + i);
      float4 c4 = *(const float4*)(p1 + i);
      int hw = half * 32 + i;
      Bd[(hw + 0) * 132 + g] = pack2(a4.x, c4.x);
      Bd[(hw + 1) * 132 + g] = pack2(a4.y, c4.y);
      Bd[(hw + 2) * 132 + g] = pack2(a4.z, c4.z);
      Bd[(hw + 3) * 132 + g] = pack2(a4.w, c4.w);
    }
  }
  __syncthreads();

  const int w = t >> 6, l = t & 63, hq = l & 15, g2 = l >> 4;
  const int wm0 = w * 64;
  const f32x4 vzero = {0.f, 0.f, 0.f, 0.f};
  f32x4 acc[4][4];
#pragma unroll
  for (int mi = 0; mi < 4; ++mi)
#pragma unroll
    for (int ni = 0; ni < 4; ++ni) acc[mi][ni] = vzero;

#pragma unroll
  for (int ks = 0; ks < 8; ++ks) {
    short8 a[4], bv[4];
#pragma unroll
    for (int mi = 0; mi < 4; ++mi)
      a[mi] = *(const short8*)(Wbf + (size_t)(wm0 + mi * 16 + hq) * 256 + ks * 32 + g2 * 8);
#pragma unroll
    for (int ni = 0; ni < 4; ++ni)
      bv[ni] = *(const short8*)(Bs + (ni * 16 + hq) * 264 + ks * 32 + g2 * 8);
#pragma unroll
    for (int mi = 0; mi < 4; ++mi)
#pragma unroll
      for (int ni = 0; ni < 4; ++ni)
        acc[mi][ni] = __builtin_amdgcn_mfma_f32_16x16x32_bf16(a[mi], bv[ni], acc[mi][ni], 0, 0, 0);
  }

#pragma unroll
  for (int mi = 0; mi < 4; ++mi) {
#pragma unroll
    for (int r = 0; r < 4; ++r) {
      int o = wm0 + mi * 16 + g2 * 4 + r;
      float bias = conv_b[o];
      float v[4];
#pragma unroll
      for (int ni = 0; ni < 4; ++ni) {
        float s = acc[mi][ni][r] + bias;
        v[ni] = 0.5f * s * (1.0f + erff(s * 0.70710678118654752f));
      }
      unsigned short* hp = h_out + ((size_t)(b * 256 + o)) * HW + hw0;
      hp[0 * 16 + hq] = bfb(v[0]);
      hp[1 * 16 + hq] = bfb(v[1]);
      hp[2 * 16 + hq] = bfb(v[2]);
      hp[3 * 16 + hq] = bfb(v[3]);
      float sm = v[0] + v[1] + v[2] + v[3];
      float mx = fmaxf(fmaxf(v[0], v[1]), fmaxf(v[2], v[3]));
#pragma unroll
      for (int d = 1; d < 16; d <<= 1) {
        sm += __shfl_xor(sm, d);
        mx = fmaxf(mx, __shfl_xor(mx, d));
      }
      if (hq == 0) {
        atomicAdd(psum + b * 256 + o, sm);
        atomicMax(pmaxe + b * 256 + o, fenc(mx));
      }
    }
  }
}

// ---------------- K2: channel attention FCs ----------------
__global__ __launch_bounds__(256) void k2_att(
    const float* __restrict__ psum, const unsigned* __restrict__ pmaxe,
    const float* __restrict__ fc1_w, const float* __restrict__ fc1_b,
    const float* __restrict__ fc2_w, const float* __restrict__ fc2_b,
    float* __restrict__ att)
{
  int b = blockIdx.x, t = threadIdx.x;
  __shared__ float hA[64], hM[64];
  if (t < 128) {
    int j = t & 63;
    bool ism = t >= 64;
    float s = fc1_b[j];
    for (int c = 0; c < 256; ++c) {
      float p = ism ? fdec(pmaxe[b * 256 + c]) : (psum[b * 256 + c] * (1.f / 3136.f));
      s += p * fc1_w[j * 256 + c];
    }
    s = fmaxf(s, 0.f);
    if (ism) hM[j] = s; else hA[j] = s;
  }
  __syncthreads();
  float s1 = fc2_b[t], s2 = s1;
  for (int j = 0; j < 64; ++j) {
    float wv = fc2_w[t * 64 + j];
    s1 += hA[j] * wv;
    s2 += hM[j] * wv;
  }
  att[b * 256 + t] = 1.f / (1.f + expf(-s1)) + 1.f / (1.f + expf(-s2));
}

// ---------------- K34 v8: fused depthwise chain, one plane per block ----------------
// = v3 (R4, 106us best) structure for P0/P1/P2/PA (scalar col-tasks, low bank conflict)
//   + bf16 HBM interfaces + PB column-pair packed reads (halved PB LDS instr count).
// LDS ~40.3KB -> 4 blocks/CU; NO min-waves cap (VGPR free, avoids spills).
//   B0 fp32 [4256]: P0 halo h [60][60]; after P1 barrier rewritten as
//        x_init fp32 [56][76] (data cols 10..65, pads 0)
//   T1/T2/T3 bf16 row-major [62|66|76][56], vertical pad rows zeroed once
// Tasks: P1/P2: 392 COL tasks (8 rows x 1 col), scalar b32 reads (2 lanes/bank = free)
//        PA: 392 ROW tasks (1 y x 8 cols), float4 win reads (v3 form)
//        PB: 196 COLUMN-PAIR tasks (8 rows x 2 cols), packed b32 T reads
__global__ __launch_bounds__(256) void k34_dw(
    const unsigned short* __restrict__ h_in, const float* __restrict__ att,
    const float* __restrict__ w5, const float* __restrict__ b5,
    const float* __restrict__ w1x7, const float* __restrict__ b1x7,
    const float* __restrict__ w7x1, const float* __restrict__ b7x1,
    const float* __restrict__ w1x11, const float* __restrict__ b1x11,
    const float* __restrict__ w11x1, const float* __restrict__ b11x1,
    const float* __restrict__ w1x21, const float* __restrict__ b1x21,
    const float* __restrict__ w21x1, const float* __restrict__ b21x1,
    unsigned short* __restrict__ xs_out)
{
  __shared__ __align__(16) float B0[4256];
  __shared__ __align__(16) unsigned short T1[62 * 56];  // r = y+3
  __shared__ __align__(16) unsigned short T2[66 * 56];  // r = y+5
  __shared__ __align__(16) unsigned short T3[76 * 56];  // r = y+10
  __shared__ __align__(16) float wk5a[25];
  __shared__ __align__(16) float wk[78]; // [0,7)w1x7 [7,14)w7x1 [14,25)w1x11 [25,36)w11x1 [36,57)w1x21 [57,78)w21x1

  const int bid = blockIdx.x;
  const int b = bid >> 8, c = bid & 255;
  const int t = threadIdx.x;
  const size_t plane = (size_t)(b * 256 + c) * HW;
  const float a = att[b * 256 + c];

  if (t < 25) wk5a[t] = w5[c * 25 + t] * a;   // fold channel attention into dw5x5 weights
  if (t >= 32 && t < 110) {
    int k = t - 32;
    float v;
    if (k < 7) v = w1x7[c * 7 + k];
    else if (k < 14) v = w7x1[c * 7 + k - 7];
    else if (k < 25) v = w1x11[c * 11 + k - 14];
    else if (k < 36) v = w11x1[c * 11 + k - 25];
    else if (k < 57) v = w1x21[c * 21 + k - 36];
    else v = w21x1[c * 21 + k - 57];
    wk[k] = v;
  }
  { // zero vertical pad rows of T1/T2/T3 (once; PA never writes them)
    unsigned* T1d = (unsigned*)T1; unsigned* T2d = (unsigned*)T2; unsigned* T3d = (unsigned*)T3;
    for (int i = t; i < 1008; i += 256) {
      if (i < 84) T1d[i] = 0;                       // rows 0..2
      else if (i < 168) T1d[1652 + i - 84] = 0;     // rows 59..61
      else if (i < 308) T2d[i - 168] = 0;           // rows 0..4
      else if (i < 448) T2d[1708 + i - 308] = 0;    // rows 61..65
      else if (i < 728) T3d[i - 448] = 0;           // rows 0..9
      else T3d[1848 + i - 728] = 0;                 // rows 66..75
    }
  }
  { // P0: stage halo'd h (rows/cols -2..57) into B0[60][60] fp32 (cvt once here)
    const unsigned short* hp = h_in + plane;
    for (int idx = t; idx < 3600; idx += 256) {
      int ly = idx / 60, lx = idx - ly * 60;
      int gy = ly - 2, gx = lx - 2;
      float v = 0.f;
      if ((unsigned)gy < 56u && (unsigned)gx < 56u) v = bf2f(hp[gy * 56 + gx]);
      B0[idx] = v;
    }
  }
  __syncthreads();

  // P1: dw5x5 -> registers. COL tasks (8 rows x 1 col), scalar b32 reads; 2 static rounds.
  float xv0[8], xv1[8];
  const float bias5 = b5[c];
  {
    int tau = t, yq = tau / 56, xx = tau - yq * 56, y0 = yq * 8;
    float accv[8];
#pragma unroll
    for (int d = 0; d < 8; ++d) accv[d] = bias5;
#pragma unroll
    for (int kx = 0; kx < 5; ++kx) {
      float col[12];
#pragma unroll
      for (int ry = 0; ry < 12; ++ry) col[ry] = B0[(y0 + ry) * 60 + xx + kx];
#pragma unroll
      for (int ky = 0; ky < 5; ++ky) {
        float wv = wk5a[ky * 5 + kx];
#pragma unroll
        for (int d = 0; d < 8; ++d) accv[d] += col[d + ky] * wv;
      }
    }
#pragma unroll
    for (int d = 0; d < 8; ++d) xv0[d] = accv[d];
  }
  if (t < 136) {
    int tau = t + 256, yq = tau / 56, xx = tau - yq * 56, y0 = yq * 8;
    float accv[8];
#pragma unroll
    for (int d = 0; d < 8; ++d) accv[d] = bias5;
#pragma unroll
    for (int kx = 0; kx < 5; ++kx) {
      float col[12];
#pragma unroll
      for (int ry = 0; ry < 12; ++ry) col[ry] = B0[(y0 + ry) * 60 + xx + kx];
#pragma unroll
      for (int ky = 0; ky < 5; ++ky) {
        float wv = wk5a[ky * 5 + kx];
#pragma unroll
        for (int d = 0; d < 8; ++d) accv[d] += col[d + ky] * wv;
      }
    }
#pragma unroll
    for (int d = 0; d < 8; ++d) xv1[d] = accv[d];
  }
  __syncthreads();

  // P2: rewrite B0 as padded x_init fp32 [56][76] (data at col+10), zero col pads (v3 form)
  {
    int tau = t, yq = tau / 56, xx = tau - yq * 56, y0 = yq * 8;
#pragma unroll
    for (int d = 0; d < 8; ++d) B0[(y0 + d) * 76 + 10 + xx] = xv0[d];
  }
  if (t < 136) {
    int tau = t + 256, yq = tau / 56, xx = tau - yq * 56, y0 = yq * 8;
#pragma unroll
    for (int d = 0; d < 8; ++d) B0[(y0 + d) * 76 + 10 + xx] = xv1[d];
  }
  for (int i = t; i < 1120; i += 256) {
    int y = i / 20, j = i - y * 20;
    int lx = (j < 10) ? j : (56 + j);   // pads: cols 0..9 and 66..75 (data at 10..65)
    B0[y * 76 + lx] = 0.f;
  }
  __syncthreads();

  // PA: fused horizontal convs. ROW task (y, x0..x0+7). win = x_init[y][x0-10..x0+17].
  const float bb1 = b1x7[c], bb2 = b1x11[c], bb3 = b1x21[c];
#pragma unroll
  for (int rnd = 0; rnd < 2; ++rnd) {
    if (rnd == 1 && t >= 136) break;
    int tau = t + rnd * 256;
    int y = tau / 7, x0 = (tau - y * 7) * 8;
    float win[28];
    const float* rp = B0 + y * 76 + x0;
#pragma unroll
    for (int j = 0; j < 28; j += 4) {
      float4 q = *(const float4*)(rp + j);
      win[j] = q.x; win[j + 1] = q.y; win[j + 2] = q.z; win[j + 3] = q.w;
    }
    float o1[8], o2[8], o3[8];
#pragma unroll
    for (int d = 0; d < 8; ++d) { o1[d] = bb1; o2[d] = bb2; o3[d] = bb3; }
#pragma unroll
    for (int k = 0; k < 7; ++k) {
      float wv = wk[k];
#pragma unroll
      for (int d = 0; d < 8; ++d) o1[d] += win[d + k + 7] * wv;
    }
#pragma unroll
    for (int k = 0; k < 11; ++k) {
      float wv = wk[14 + k];
#pragma unroll
      for (int d = 0; d < 8; ++d) o2[d] += win[d + k + 5] * wv;
    }
#pragma unroll
    for (int k = 0; k < 21; ++k) {
      float wv = wk[36 + k];
#pragma unroll
      for (int d = 0; d < 8; ++d) o3[d] += win[d + k] * wv;
    }
    uint4 s1, s2, s3;
    s1.x = pack2(o1[0], o1[1]); s1.y = pack2(o1[2], o1[3]); s1.z = pack2(o1[4], o1[5]); s1.w = pack2(o1[6], o1[7]);
    s2.x = pack2(o2[0], o2[1]); s2.y = pack2(o2[2], o2[3]); s2.z = pack2(o2[4], o2[5]); s2.w = pack2(o2[6], o2[7]);
    s3.x = pack2(o3[0], o3[1]); s3.y = pack2(o3[2], o3[3]); s3.z = pack2(o3[4], o3[5]); s3.w = pack2(o3[6], o3[7]);
    *(uint4*)&T1[(y + 3) * 56 + x0] = s1;
    *(uint4*)&T2[(y + 5) * 56 + x0] = s2;
    *(uint4*)&T3[(y + 10) * 56 + x0] = s3;
  }
  __syncthreads();

  // PB: fused vertical convs + x_init add -> global bf16 store.
  // COLUMN-PAIR task: (8 rows y0..y0+7) x (2 cols x0,x0+1); 196 tasks, 1 round.
  // T reads are packed b32 (2 bf16/instr); unpack via shift/mask (no cvt).
  const float vb = b7x1[c] + b11x1[c] + b21x1[c];
  unsigned short* op = xs_out + plane;
  if (t < 196) {
    int band = t / 28, xp = t - band * 28;
    int y0 = band * 8, x0 = xp * 2;
    float rlo[8], rhi[8];
#pragma unroll
    for (int d = 0; d < 8; ++d) {
      float2 q = *(const float2*)&B0[(y0 + d) * 76 + 10 + x0];
      rlo[d] = q.x + vb; rhi[d] = q.y + vb;
    }
    {
      float clo[14], chi[14];
#pragma unroll
      for (int j = 0; j < 14; ++j) {
        unsigned q = *(const unsigned*)&T1[(y0 + j) * 56 + x0];
        clo[j] = __uint_as_float(q << 16);
        chi[j] = __uint_as_float(q & 0xffff0000u);
      }
#pragma unroll
      for (int k = 0; k < 7; ++k) {
        float wv = wk[7 + k];
#pragma unroll
        for (int d = 0; d < 8; ++d) { rlo[d] += clo[d + k] * wv; rhi[d] += chi[d + k] * wv; }
      }
    }
    {
      float clo[18], chi[18];
#pragma unroll
      for (int j = 0; j < 18; ++j) {
        unsigned q = *(const unsigned*)&T2[(y0 + j) * 56 + x0];
        clo[j] = __uint_as_float(q << 16);
        chi[j] = __uint_as_float(q & 0xffff0000u);
      }
#pragma unroll
      for (int k = 0; k < 11; ++k) {
        float wv = wk[25 + k];
#pragma unroll
        for (int d = 0; d < 8; ++d) { rlo[d] += clo[d + k] * wv; rhi[d] += chi[d + k] * wv; }
      }
    }
    {
      float clo[28], chi[28];
#pragma unroll
      for (int j = 0; j < 28; ++j) {
        unsigned q = *(const unsigned*)&T3[(y0 + j) * 56 + x0];
        clo[j] = __uint_as_float(q << 16);
        chi[j] = __uint_as_float(q & 0xffff0000u);
      }
#pragma unroll
      for (int k = 0; k < 21; ++k) {
        float wv = wk[57 + k];
#pragma unroll
        for (int d = 0; d < 8; ++d) { rlo[d] += clo[d + k] * wv; rhi[d] += chi[d + k] * wv; }
      }
    }
#pragma unroll
    for (int d = 0; d < 8; ++d)
      *(unsigned*)&op[(y0 + d) * 56 + x0] = pack2(rlo[d], rhi[d]);
  }
}

// ---------------- K5: spatial_att = W*xs+b ; out = sa*(att*h) ; result = W*out+b ----------------
__global__ __launch_bounds__(256) void k5_final(
    const unsigned short* __restrict__ xs, const unsigned short* __restrict__ Wbf,
    const float* __restrict__ conv_b, const float* __restrict__ att,
    const unsigned short* __restrict__ h_in, float* __restrict__ outp)
{
  __shared__ __align__(16) unsigned short Bs[64 * 264];
  const int bid = blockIdx.x;
  const int b = bid / 49, tile = bid - 49 * (bid / 49);
  const int hw0 = tile * 64;
  const int t = threadIdx.x;

  { // stage xs (already bf16) transposed into LDS, no converts
    int g = t & 127, half = t >> 7;
    const unsigned short* p0 = xs + ((size_t)(b * 256 + 2 * g)) * HW + hw0 + half * 32;
    const unsigned short* p1 = p0 + HW;
    unsigned* Bd = (unsigned*)Bs;
#pragma unroll
    for (int i = 0; i < 32; i += 4) {
      ushort4 a4 = *(const ushort4*)(p0 + i);
      ushort4 c4 = *(const ushort4*)(p1 + i);
      int hw = half * 32 + i;
      Bd[(hw + 0) * 132 + g] = (unsigned)a4.x | ((unsigned)c4.x << 16);
      Bd[(hw + 1) * 132 + g] = (unsigned)a4.y | ((unsigned)c4.y << 16);
      Bd[(hw + 2) * 132 + g] = (unsigned)a4.z | ((unsigned)c4.z << 16);
      Bd[(hw + 3) * 132 + g] = (unsigned)a4.w | ((unsigned)c4.w << 16);
    }
  }
  __syncthreads();

  const int w = t >> 6, l = t & 63, hq = l & 15, g2 = l >> 4;
  const int wm0 = w * 64;
  const f32x4 vzero = {0.f, 0.f, 0.f, 0.f};
  f32x4 acc[4][4];
#pragma unroll
  for (int mi = 0; mi < 4; ++mi)
#pragma unroll
    for (int ni = 0; ni < 4; ++ni) acc[mi][ni] = vzero;

#pragma unroll
  for (int ks = 0; ks < 8; ++ks) {
    short8 a[4], bv[4];
#pragma unroll
    for (int mi = 0; mi < 4; ++mi)
      a[mi] = *(const short8*)(Wbf + (size_t)(wm0 + mi * 16 + hq) * 256 + ks * 32 + g2 * 8);
#pragma unroll
    for (int ni = 0; ni < 4; ++ni)
      bv[ni] = *(const short8*)(Bs + (ni * 16 + hq) * 264 + ks * 32 + g2 * 8);
#pragma unroll
    for (int mi = 0; mi < 4; ++mi)
#pragma unroll
      for (int ni = 0; ni < 4; ++ni)
        acc[mi][ni] = __builtin_amdgcn_mfma_f32_16x16x32_bf16(a[mi], bv[ni], acc[mi][ni], 0, 0, 0);
  }
  __syncthreads();

#pragma unroll
  for (int mi = 0; mi < 4; ++mi) {
#pragma unroll
    for (int r = 0; r < 4; ++r) {
      int o = wm0 + mi * 16 + g2 * 4 + r;
      float bias = conv_b[o];
      float av = att[b * 256 + o];
      const unsigned short* hp = h_in + ((size_t)(b * 256 + o)) * HW + hw0;
#pragma unroll
      for (int ni = 0; ni < 4; ++ni) {
        float sa = acc[mi][ni][r] + bias;
        float ov = sa * (av * bf2f(hp[ni * 16 + hq]));
        Bs[(ni * 16 + hq) * 264 + o] = bfb(ov);
      }
    }
  }
  __syncthreads();

  f32x4 acc2[4][4];
#pragma unroll
  for (int mi = 0; mi < 4; ++mi)
#pragma unroll
    for (int ni = 0; ni < 4; ++ni) acc2[mi][ni] = vzero;
#pragma unroll
  for (int ks = 0; ks < 8; ++ks) {
    short8 a[4], bv[4];
#pragma unroll
    for (int mi = 0; mi < 4; ++mi)
      a[mi] = *(const short8*)(Wbf + (size_t)(wm0 + mi * 16 + hq) * 256 + ks * 32 + g2 * 8);
#pragma unroll
    for (int ni = 0; ni < 4; ++ni)
      bv[ni] = *(const short8*)(Bs + (ni * 16 + hq) * 264 + ks * 32 + g2 * 8);
#pragma unroll
    for (int mi = 0; mi < 4; ++mi)
#pragma unroll
      for (int ni = 0; ni < 4; ++ni)
        acc2[mi][ni] = __builtin_amdgcn_mfma_f32_16x16x32_bf16(a[mi], bv[ni], acc2[mi][ni], 0, 0, 0);
  }

#pragma unroll
  for (int mi = 0; mi < 4; ++mi) {
#pragma unroll
    for (int r = 0; r < 4; ++r) {
      int o = wm0 + mi * 16 + g2 * 4 + r;
      float bias = conv_b[o];
      float* op = outp + ((size_t)(b * 256 + o)) * HW + hw0;
#pragma unroll
      for (int ni = 0; ni < 4; ++ni) op[ni * 16 + hq] = acc2[mi][ni][r] + bias;
    }
  }
}

extern "C" void kernel_launch(void* const* d_in, const int* in_sizes, int n_in,
                              void* d_out, int out_size, void* d_ws, size_t ws_size,
                              hipStream_t stream) {
  const float* x      = (const float*)d_in[0];
  const float* conv_w = (const float*)d_in[1];
  const float* conv_b = (const float*)d_in[2];
  const float* fc1_w  = (const float*)d_in[3];
  const float* fc1_b  = (const float*)d_in[4];
  const float* fc2_w  = (const float*)d_in[5];
  const float* fc2_b  = (const float*)d_in[6];
  const float* w5     = (const float*)d_in[7];
  const float* b5     = (const float*)d_in[8];
  const float* w1x7   = (const float*)d_in[9];
  const float* b1x7   = (const float*)d_in[10];
  const float* w7x1   = (const float*)d_in[11];
  const float* b7x1   = (const float*)d_in[12];
  const float* w1x11  = (const float*)d_in[13];
  const float* b1x11  = (const float*)d_in[14];
  const float* w11x1  = (const float*)d_in[15];
  const float* b11x1  = (const float*)d_in[16];
  const float* w1x21  = (const float*)d_in[17];
  const float* b1x21  = (const float*)d_in[18];
  const float* w21x1  = (const float*)d_in[19];
  const float* b21x1  = (const float*)d_in[20];
  float* out = (float*)d_out;

  char* ws = (char*)d_ws;
  unsigned short* Wbf = (unsigned short*)(ws);            // 131072 B
  float* psum   = (float*)(ws + 131072);                  // 16384 B
  unsigned* pme = (unsigned*)(ws + 147456);               // 16384 B
  float* attb   = (float*)(ws + 163840);                  // 16384 B
  unsigned short* hbuf = (unsigned short*)(ws + 180224);  // 25690112 B (h bf16)
  unsigned short* xbuf = (unsigned short*)(ws + 180224 + 25690112); // 25690112 B (xs bf16)

  k0_init<<<256, 256, 0, stream>>>(conv_w, Wbf, psum, pme);
  k1_conv_gelu_pool<<<784, 256, 0, stream>>>(x, Wbf, conv_b, hbuf, psum, pme);
  k2_att<<<16, 256, 0, stream>>>(psum, pme, fc1_w, fc1_b, fc2_w, fc2_b, attb);
  k34_dw<<<4096, 256, 0, stream>>>(hbuf, attb, w5, b5, w1x7, b1x7, w7x1, b7x1,
                                   w1x11, b1x11, w11x1, b11x1, w1x21, b1x21,
                                   w21x1, b21x1, xbuf);
  k5_final<<<784, 256, 0, stream>>>(xbuf, Wbf, conv_b, attb, hbuf, out);
}

// Round 10
// 204.348 us; speedup vs baseline: 1.2228x; 1.1083x over previous
//
#include <hip/hip_runtime.h>
#include <hip/hip_bf16.h>

#define HW 3136
#define NB 16

typedef float f32x4 __attribute__((ext_vector_type(4)));
typedef short short8 __attribute__((ext_vector_type(8)));
typedef unsigned short ushort8 __attribute__((ext_vector_type(8)));

__device__ inline unsigned short bfb(float f) {
  union { __hip_bfloat16 h; unsigned short u; } cv;
  cv.h = __float2bfloat16(f);
  return cv.u;
}
__device__ inline unsigned pack2(float lo, float hi) {
  return (unsigned)bfb(lo) | ((unsigned)bfb(hi) << 16);
}
// order-preserving float<->uint encode for atomicMax
__device__ inline unsigned fenc(float f) {
  unsigned u = __float_as_uint(f);
  return (u & 0x80000000u) ? ~u : (u | 0x80000000u);
}
__device__ inline float fdec(unsigned e) {
  return (e & 0x80000000u) ? __uint_as_float(e & 0x7FFFFFFFu) : __uint_as_float(~e);
}
__device__ inline float bf2f(unsigned short u) {
  return __uint_as_float((unsigned)u << 16);
}

// ---------------- K0: convert W to bf16, zero pool buffers ----------------
__global__ __launch_bounds__(256) void k0_init(const float* __restrict__ conv_w,
                                               unsigned short* __restrict__ Wbf,
                                               float* __restrict__ psum,
                                               unsigned* __restrict__ pmaxe) {
  int i = blockIdx.x * 256 + threadIdx.x;
  Wbf[i] = bfb(conv_w[i]);
  if (i < 4096) psum[i] = 0.f;
  else if (i < 8192) pmaxe[i - 4096] = 0u;
}

// ---------------- K1: conv1x1 + bias + GELU -> h (bf16) ; fused channel pooling ----------------
// Epilogue v9: gelu results -> Bs[hw][o] (bf16), then per-o column pass does
// in-register sum/max pooling (no shuffles), vectorized uint4 h stores, 2 atomics/thread.
__global__ __launch_bounds__(256) void k1_conv_gelu_pool(
    const float* __restrict__ x, const unsigned short* __restrict__ Wbf,
    const float* __restrict__ conv_b, unsigned short* __restrict__ h_out,
    float* __restrict__ psum, unsigned* __restrict__ pmaxe)
{
  __shared__ __align__(16) unsigned short Bs[64 * 264];
  const int bid = blockIdx.x;
  const int b = bid / 49, tile = bid - 49 * (bid / 49);
  const int hw0 = tile * 64;
  const int t = threadIdx.x;

  {
    int g = t & 127, half = t >> 7;
    const float* p0 = x + ((size_t)(b * 256 + 2 * g)) * HW + hw0 + half * 32;
    const float* p1 = p0 + HW;
    unsigned* Bd = (unsigned*)Bs;
#pragma unroll
    for (int i = 0; i < 32; i += 4) {
      float4 a4 = *(const float4*)(p0 + i);
      float4 c4 = *(const float4*)(p1 + i);
      int hw = half * 32 + i;
      Bd[(hw + 0) * 132 + g] = pack2(a4.x, c4.x);
      Bd[(hw + 1) * 132 + g] = pack2(a4.y, c4.y);
      Bd[(hw + 2) * 132 + g] = pack2(a4.z, c4.z);
      Bd[(hw + 3) * 132 + g] = pack2(a4.w, c4.w);
    }
  }
  __syncthreads();

  const int w = t >> 6, l = t & 63, hq = l & 15, g2 = l >> 4;
  const int wm0 = w * 64;
  const f32x4 vzero = {0.f, 0.f, 0.f, 0.f};
  f32x4 acc[4][4];
#pragma unroll
  for (int mi = 0; mi < 4; ++mi)
#pragma unroll
    for (int ni = 0; ni < 4; ++ni) acc[mi][ni] = vzero;

#pragma unroll
  for (int ks = 0; ks < 8; ++ks) {
    short8 a[4], bv[4];
#pragma unroll
    for (int mi = 0; mi < 4; ++mi)
      a[mi] = *(const short8*)(Wbf + (size_t)(wm0 + mi * 16 + hq) * 256 + ks * 32 + g2 * 8);
#pragma unroll
    for (int ni = 0; ni < 4; ++ni)
      bv[ni] = *(const short8*)(Bs + (ni * 16 + hq) * 264 + ks * 32 + g2 * 8);
#pragma unroll
    for (int mi = 0; mi < 4; ++mi)
#pragma unroll
      for (int ni = 0; ni < 4; ++ni)
        acc[mi][ni] = __builtin_amdgcn_mfma_f32_16x16x32_bf16(a[mi], bv[ni], acc[mi][ni], 0, 0, 0);
  }
  __syncthreads();  // all waves done reading Bs before overwrite

  // fragment phase: bias + exact GELU -> bf16 into Bs[hw][o]
#pragma unroll
  for (int mi = 0; mi < 4; ++mi) {
#pragma unroll
    for (int r = 0; r < 4; ++r) {
      int o = wm0 + mi * 16 + g2 * 4 + r;
      float bias = conv_b[o];
#pragma unroll
      for (int ni = 0; ni < 4; ++ni) {
        float s = acc[mi][ni][r] + bias;
        float v = 0.5f * s * (1.0f + erff(s * 0.70710678118654752f));
        Bs[(ni * 16 + hq) * 264 + o] = bfb(v);
      }
    }
  }
  __syncthreads();

  // column pass: thread t = channel o; pool + vectorized store
  {
    const int o = t;
    float sm = 0.f, mx = -1e30f;
    unsigned pk[32];
#pragma unroll
    for (int m = 0; m < 32; ++m) {
      unsigned short r0 = Bs[(2 * m) * 264 + o];
      unsigned short r1 = Bs[(2 * m + 1) * 264 + o];
      float f0 = bf2f(r0), f1 = bf2f(r1);
      sm += f0 + f1;
      mx = fmaxf(mx, fmaxf(f0, f1));
      pk[m] = (unsigned)r0 | ((unsigned)r1 << 16);
    }
    unsigned short* hp = h_out + ((size_t)(b * 256 + o)) * HW + hw0;
#pragma unroll
    for (int q = 0; q < 8; ++q) {
      uint4 s4;
      s4.x = pk[q * 4 + 0]; s4.y = pk[q * 4 + 1]; s4.z = pk[q * 4 + 2]; s4.w = pk[q * 4 + 3];
      *(uint4*)(hp + q * 8) = s4;
    }
    atomicAdd(psum + b * 256 + o, sm);
    atomicMax(pmaxe + b * 256 + o, fenc(mx));
  }
}

// ---------------- K2: channel attention FCs (v9: 4-way c-split FC1) ----------------
__global__ __launch_bounds__(256) void k2_att(
    const float* __restrict__ psum, const unsigned* __restrict__ pmaxe,
    const float* __restrict__ fc1_w, const float* __restrict__ fc1_b,
    const float* __restrict__ fc2_w, const float* __restrict__ fc2_b,
    float* __restrict__ att)
{
  const int b = blockIdx.x, t = threadIdx.x;
  __shared__ float pA[4][64], pM[4][64];
  __shared__ float hA[64], hM[64];
  {
    const int j = t & 63, seg = t >> 6;
    const int base = b * 256 + seg * 64;
    const float* wrow = fc1_w + j * 256 + seg * 64;
    float sA = 0.f, sM = 0.f;
#pragma unroll 8
    for (int c = 0; c < 64; ++c) {
      float wv = wrow[c];
      sA += psum[base + c] * wv;
      sM += fdec(pmaxe[base + c]) * wv;
    }
    pA[seg][j] = sA;
    pM[seg][j] = sM;
  }
  __syncthreads();
  if (t < 64) {
    float a = fc1_b[t] + (pA[0][t] + pA[1][t] + pA[2][t] + pA[3][t]) * (1.f / 3136.f);
    float m = fc1_b[t] + (pM[0][t] + pM[1][t] + pM[2][t] + pM[3][t]);
    hA[t] = fmaxf(a, 0.f);
    hM[t] = fmaxf(m, 0.f);
  }
  __syncthreads();
  float s1 = fc2_b[t], s2 = s1;
#pragma unroll 8
  for (int j = 0; j < 64; ++j) {
    float wv = fc2_w[t * 64 + j];
    s1 += hA[j] * wv;
    s2 += hM[j] * wv;
  }
  att[b * 256 + t] = 1.f / (1.f + expf(-s1)) + 1.f / (1.f + expf(-s2));
}

// ---------------- K34 v8 (unchanged, verified 106us) ----------------
__global__ __launch_bounds__(256) void k34_dw(
    const unsigned short* __restrict__ h_in, const float* __restrict__ att,
    const float* __restrict__ w5, const float* __restrict__ b5,
    const float* __restrict__ w1x7, const float* __restrict__ b1x7,
    const float* __restrict__ w7x1, const float* __restrict__ b7x1,
    const float* __restrict__ w1x11, const float* __restrict__ b1x11,
    const float* __restrict__ w11x1, const float* __restrict__ b11x1,
    const float* __restrict__ w1x21, const float* __restrict__ b1x21,
    const float* __restrict__ w21x1, const float* __restrict__ b21x1,
    unsigned short* __restrict__ xs_out)
{
  __shared__ __align__(16) float B0[4256];
  __shared__ __align__(16) unsigned short T1[62 * 56];  // r = y+3
  __shared__ __align__(16) unsigned short T2[66 * 56];  // r = y+5
  __shared__ __align__(16) unsigned short T3[76 * 56];  // r = y+10
  __shared__ __align__(16) float wk5a[25];
  __shared__ __align__(16) float wk[78]; // [0,7)w1x7 [7,14)w7x1 [14,25)w1x11 [25,36)w11x1 [36,57)w1x21 [57,78)w21x1

  const int bid = blockIdx.x;
  const int b = bid >> 8, c = bid & 255;
  const int t = threadIdx.x;
  const size_t plane = (size_t)(b * 256 + c) * HW;
  const float a = att[b * 256 + c];

  if (t < 25) wk5a[t] = w5[c * 25 + t] * a;
  if (t >= 32 && t < 110) {
    int k = t - 32;
    float v;
    if (k < 7) v = w1x7[c * 7 + k];
    else if (k < 14) v = w7x1[c * 7 + k - 7];
    else if (k < 25) v = w1x11[c * 11 + k - 14];
    else if (k < 36) v = w11x1[c * 11 + k - 25];
    else if (k < 57) v = w1x21[c * 21 + k - 36];
    else v = w21x1[c * 21 + k - 57];
    wk[k] = v;
  }
  {
    unsigned* T1d = (unsigned*)T1; unsigned* T2d = (unsigned*)T2; unsigned* T3d = (unsigned*)T3;
    for (int i = t; i < 1008; i += 256) {
      if (i < 84) T1d[i] = 0;
      else if (i < 168) T1d[1652 + i - 84] = 0;
      else if (i < 308) T2d[i - 168] = 0;
      else if (i < 448) T2d[1708 + i - 308] = 0;
      else if (i < 728) T3d[i - 448] = 0;
      else T3d[1848 + i - 728] = 0;
    }
  }
  {
    const unsigned short* hp = h_in + plane;
    for (int idx = t; idx < 3600; idx += 256) {
      int ly = idx / 60, lx = idx - ly * 60;
      int gy = ly - 2, gx = lx - 2;
      float v = 0.f;
      if ((unsigned)gy < 56u && (unsigned)gx < 56u) v = bf2f(hp[gy * 56 + gx]);
      B0[idx] = v;
    }
  }
  __syncthreads();

  float xv0[8], xv1[8];
  const float bias5 = b5[c];
  {
    int tau = t, yq = tau / 56, xx = tau - yq * 56, y0 = yq * 8;
    float accv[8];
#pragma unroll
    for (int d = 0; d < 8; ++d) accv[d] = bias5;
#pragma unroll
    for (int kx = 0; kx < 5; ++kx) {
      float col[12];
#pragma unroll
      for (int ry = 0; ry < 12; ++ry) col[ry] = B0[(y0 + ry) * 60 + xx + kx];
#pragma unroll
      for (int ky = 0; ky < 5; ++ky) {
        float wv = wk5a[ky * 5 + kx];
#pragma unroll
        for (int d = 0; d < 8; ++d) accv[d] += col[d + ky] * wv;
      }
    }
#pragma unroll
    for (int d = 0; d < 8; ++d) xv0[d] = accv[d];
  }
  if (t < 136) {
    int tau = t + 256, yq = tau / 56, xx = tau - yq * 56, y0 = yq * 8;
    float accv[8];
#pragma unroll
    for (int d = 0; d < 8; ++d) accv[d] = bias5;
#pragma unroll
    for (int kx = 0; kx < 5; ++kx) {
      float col[12];
#pragma unroll
      for (int ry = 0; ry < 12; ++ry) col[ry] = B0[(y0 + ry) * 60 + xx + kx];
#pragma unroll
      for (int ky = 0; ky < 5; ++ky) {
        float wv = wk5a[ky * 5 + kx];
#pragma unroll
        for (int d = 0; d < 8; ++d) accv[d] += col[d + ky] * wv;
      }
    }
#pragma unroll
    for (int d = 0; d < 8; ++d) xv1[d] = accv[d];
  }
  __syncthreads();

  {
    int tau = t, yq = tau / 56, xx = tau - yq * 56, y0 = yq * 8;
#pragma unroll
    for (int d = 0; d < 8; ++d) B0[(y0 + d) * 76 + 10 + xx] = xv0[d];
  }
  if (t < 136) {
    int tau = t + 256, yq = tau / 56, xx = tau - yq * 56, y0 = yq * 8;
#pragma unroll
    for (int d = 0; d < 8; ++d) B0[(y0 + d) * 76 + 10 + xx] = xv1[d];
  }
  for (int i = t; i < 1120; i += 256) {
    int y = i / 20, j = i - y * 20;
    int lx = (j < 10) ? j : (56 + j);
    B0[y * 76 + lx] = 0.f;
  }
  __syncthreads();

  const float bb1 = b1x7[c], bb2 = b1x11[c], bb3 = b1x21[c];
#pragma unroll
  for (int rnd = 0; rnd < 2; ++rnd) {
    if (rnd == 1 && t >= 136) break;
    int tau = t + rnd * 256;
    int y = tau / 7, x0 = (tau - y * 7) * 8;
    float win[28];
    const float* rp = B0 + y * 76 + x0;
#pragma unroll
    for (int j = 0; j < 28; j += 4) {
      float4 q = *(const float4*)(rp + j);
      win[j] = q.x; win[j + 1] = q.y; win[j + 2] = q.z; win[j + 3] = q.w;
    }
    float o1[8], o2[8], o3[8];
#pragma unroll
    for (int d = 0; d < 8; ++d) { o1[d] = bb1; o2[d] = bb2; o3[d] = bb3; }
#pragma unroll
    for (int k = 0; k < 7; ++k) {
      float wv = wk[k];
#pragma unroll
      for (int d = 0; d < 8; ++d) o1[d] += win[d + k + 7] * wv;
    }
#pragma unroll
    for (int k = 0; k < 11; ++k) {
      float wv = wk[14 + k];
#pragma unroll
      for (int d = 0; d < 8; ++d) o2[d] += win[d + k + 5] * wv;
    }
#pragma unroll
    for (int k = 0; k < 21; ++k) {
      float wv = wk[36 + k];
#pragma unroll
      for (int d = 0; d < 8; ++d) o3[d] += win[d + k] * wv;
    }
    uint4 s1, s2, s3;
    s1.x = pack2(o1[0], o1[1]); s1.y = pack2(o1[2], o1[3]); s1.z = pack2(o1[4], o1[5]); s1.w = pack2(o1[6], o1[7]);
    s2.x = pack2(o2[0], o2[1]); s2.y = pack2(o2[2], o2[3]); s2.z = pack2(o2[4], o2[5]); s2.w = pack2(o2[6], o2[7]);
    s3.x = pack2(o3[0], o3[1]); s3.y = pack2(o3[2], o3[3]); s3.z = pack2(o3[4], o3[5]); s3.w = pack2(o3[6], o3[7]);
    *(uint4*)&T1[(y + 3) * 56 + x0] = s1;
    *(uint4*)&T2[(y + 5) * 56 + x0] = s2;
    *(uint4*)&T3[(y + 10) * 56 + x0] = s3;
  }
  __syncthreads();

  const float vb = b7x1[c] + b11x1[c] + b21x1[c];
  unsigned short* op = xs_out + plane;
  if (t < 196) {
    int band = t / 28, xp = t - band * 28;
    int y0 = band * 8, x0 = xp * 2;
    float rlo[8], rhi[8];
#pragma unroll
    for (int d = 0; d < 8; ++d) {
      float2 q = *(const float2*)&B0[(y0 + d) * 76 + 10 + x0];
      rlo[d] = q.x + vb; rhi[d] = q.y + vb;
    }
    {
      float clo[14], chi[14];
#pragma unroll
      for (int j = 0; j < 14; ++j) {
        unsigned q = *(const unsigned*)&T1[(y0 + j) * 56 + x0];
        clo[j] = __uint_as_float(q << 16);
        chi[j] = __uint_as_float(q & 0xffff0000u);
      }
#pragma unroll
      for (int k = 0; k < 7; ++k) {
        float wv = wk[7 + k];
#pragma unroll
        for (int d = 0; d < 8; ++d) { rlo[d] += clo[d + k] * wv; rhi[d] += chi[d + k] * wv; }
      }
    }
    {
      float clo[18], chi[18];
#pragma unroll
      for (int j = 0; j < 18; ++j) {
        unsigned q = *(const unsigned*)&T2[(y0 + j) * 56 + x0];
        clo[j] = __uint_as_float(q << 16);
        chi[j] = __uint_as_float(q & 0xffff0000u);
      }
#pragma unroll
      for (int k = 0; k < 11; ++k) {
        float wv = wk[25 + k];
#pragma unroll
        for (int d = 0; d < 8; ++d) { rlo[d] += clo[d + k] * wv; rhi[d] += chi[d + k] * wv; }
      }
    }
    {
      float clo[28], chi[28];
#pragma unroll
      for (int j = 0; j < 28; ++j) {
        unsigned q = *(const unsigned*)&T3[(y0 + j) * 56 + x0];
        clo[j] = __uint_as_float(q << 16);
        chi[j] = __uint_as_float(q & 0xffff0000u);
      }
#pragma unroll
      for (int k = 0; k < 21; ++k) {
        float wv = wk[57 + k];
#pragma unroll
        for (int d = 0; d < 8; ++d) { rlo[d] += clo[d + k] * wv; rhi[d] += chi[d + k] * wv; }
      }
    }
#pragma unroll
    for (int d = 0; d < 8; ++d)
      *(unsigned*)&op[(y0 + d) * 56 + x0] = pack2(rlo[d], rhi[d]);
  }
}

// ---------------- K5: spatial_att = W*xs+b ; out = sa*(att*h) ; result = W*out+b ----------------
__global__ __launch_bounds__(256) void k5_final(
    const unsigned short* __restrict__ xs, const unsigned short* __restrict__ Wbf,
    const float* __restrict__ conv_b, const float* __restrict__ att,
    const unsigned short* __restrict__ h_in, float* __restrict__ outp)
{
  __shared__ __align__(16) unsigned short Bs[64 * 264];
  const int bid = blockIdx.x;
  const int b = bid / 49, tile = bid - 49 * (bid / 49);
  const int hw0 = tile * 64;
  const int t = threadIdx.x;

  { // stage xs (bf16) transposed into LDS, ushort8 (16B) loads
    int g = t & 127, half = t >> 7;
    const unsigned short* p0 = xs + ((size_t)(b * 256 + 2 * g)) * HW + hw0 + half * 32;
    const unsigned short* p1 = p0 + HW;
    unsigned* Bd = (unsigned*)Bs;
#pragma unroll
    for (int i = 0; i < 32; i += 8) {
      ushort8 a8 = *(const ushort8*)(p0 + i);
      ushort8 c8 = *(const ushort8*)(p1 + i);
      int hw = half * 32 + i;
#pragma unroll
      for (int e = 0; e < 8; ++e)
        Bd[(hw + e) * 132 + g] = (unsigned)a8[e] | ((unsigned)c8[e] << 16);
    }
  }
  __syncthreads();

  const int w = t >> 6, l = t & 63, hq = l & 15, g2 = l >> 4;
  const int wm0 = w * 64;
  const f32x4 vzero = {0.f, 0.f, 0.f, 0.f};
  f32x4 acc[4][4];
#pragma unroll
  for (int mi = 0; mi < 4; ++mi)
#pragma unroll
    for (int ni = 0; ni < 4; ++ni) acc[mi][ni] = vzero;

#pragma unroll
  for (int ks = 0; ks < 8; ++ks) {
    short8 a[4], bv[4];
#pragma unroll
    for (int mi = 0; mi < 4; ++mi)
      a[mi] = *(const short8*)(Wbf + (size_t)(wm0 + mi * 16 + hq) * 256 + ks * 32 + g2 * 8);
#pragma unroll
    for (int ni = 0; ni < 4; ++ni)
      bv[ni] = *(const short8*)(Bs + (ni * 16 + hq) * 264 + ks * 32 + g2 * 8);
#pragma unroll
    for (int mi = 0; mi < 4; ++mi)
#pragma unroll
      for (int ni = 0; ni < 4; ++ni)
        acc[mi][ni] = __builtin_amdgcn_mfma_f32_16x16x32_bf16(a[mi], bv[ni], acc[mi][ni], 0, 0, 0);
  }
  __syncthreads();

#pragma unroll
  for (int mi = 0; mi < 4; ++mi) {
#pragma unroll
    for (int r = 0; r < 4; ++r) {
      int o = wm0 + mi * 16 + g2 * 4 + r;
      float bias = conv_b[o];
      float av = att[b * 256 + o];
      const unsigned short* hp = h_in + ((size_t)(b * 256 + o)) * HW + hw0;
#pragma unroll
      for (int ni = 0; ni < 4; ++ni) {
        float sa = acc[mi][ni][r] + bias;
        float ov = sa * (av * bf2f(hp[ni * 16 + hq]));
        Bs[(ni * 16 + hq) * 264 + o] = bfb(ov);
      }
    }
  }
  __syncthreads();

  f32x4 acc2[4][4];
#pragma unroll
  for (int mi = 0; mi < 4; ++mi)
#pragma unroll
    for (int ni = 0; ni < 4; ++ni) acc2[mi][ni] = vzero;
#pragma unroll
  for (int ks = 0; ks < 8; ++ks) {
    short8 a[4], bv[4];
#pragma unroll
    for (int mi = 0; mi < 4; ++mi)
      a[mi] = *(const short8*)(Wbf + (size_t)(wm0 + mi * 16 + hq) * 256 + ks * 32 + g2 * 8);
#pragma unroll
    for (int ni = 0; ni < 4; ++ni)
      bv[ni] = *(const short8*)(Bs + (ni * 16 + hq) * 264 + ks * 32 + g2 * 8);
#pragma unroll
    for (int mi = 0; mi < 4; ++mi)
#pragma unroll
      for (int ni = 0; ni < 4; ++ni)
        acc2[mi][ni] = __builtin_amdgcn_mfma_f32_16x16x32_bf16(a[mi], bv[ni], acc2[mi][ni], 0, 0, 0);
  }

#pragma unroll
  for (int mi = 0; mi < 4; ++mi) {
#pragma unroll
    for (int r = 0; r < 4; ++r) {
      int o = wm0 + mi * 16 + g2 * 4 + r;
      float bias = conv_b[o];
      float* op = outp + ((size_t)(b * 256 + o)) * HW + hw0;
#pragma unroll
      for (int ni = 0; ni < 4; ++ni) op[ni * 16 + hq] = acc2[mi][ni][r] + bias;
    }
  }
}

extern "C" void kernel_launch(void* const* d_in, const int* in_sizes, int n_in,
                              void* d_out, int out_size, void* d_ws, size_t ws_size,
                              hipStream_t stream) {
  const float* x      = (const float*)d_in[0];
  const float* conv_w = (const float*)d_in[1];
  const float* conv_b = (const float*)d_in[2];
  const float* fc1_w  = (const float*)d_in[3];
  const float* fc1_b  = (const float*)d_in[4];
  const float* fc2_w  = (const float*)d_in[5];
  const float* fc2_b  = (const float*)d_in[6];
  const float* w5     = (const float*)d_in[7];
  const float* b5     = (const float*)d_in[8];
  const float* w1x7   = (const float*)d_in[9];
  const float* b1x7   = (const float*)d_in[10];
  const float* w7x1   = (const float*)d_in[11];
  const float* b7x1   = (const float*)d_in[12];
  const float* w1x11  = (const float*)d_in[13];
  const float* b1x11  = (const float*)d_in[14];
  const float* w11x1  = (const float*)d_in[15];
  const float* b11x1  = (const float*)d_in[16];
  const float* w1x21  = (const float*)d_in[17];
  const float* b1x21  = (const float*)d_in[18];
  const float* w21x1  = (const float*)d_in[19];
  const float* b21x1  = (const float*)d_in[20];
  float* out = (float*)d_out;

  char* ws = (char*)d_ws;
  unsigned short* Wbf = (unsigned short*)(ws);            // 131072 B
  float* psum   = (float*)(ws + 131072);                  // 16384 B
  unsigned* pme = (unsigned*)(ws + 147456);               // 16384 B
  float* attb   = (float*)(ws + 163840);                  // 16384 B
  unsigned short* hbuf = (unsigned short*)(ws + 180224);  // 25690112 B (h bf16)
  unsigned short* xbuf = (unsigned short*)(ws + 180224 + 25690112); // 25690112 B (xs bf16)

  k0_init<<<256, 256, 0, stream>>>(conv_w, Wbf, psum, pme);
  k1_conv_gelu_pool<<<784, 256, 0, stream>>>(x, Wbf, conv_b, hbuf, psum, pme);
  k2_att<<<16, 256, 0, stream>>>(psum, pme, fc1_w, fc1_b, fc2_w, fc2_b, attb);
  k34_dw<<<4096, 256, 0, stream>>>(hbuf, attb, w5, b5, w1x7, b1x7, w7x1, b7x1,
                                   w1x11, b1x11, w11x1, b11x1, w1x21, b1x21,
                                   w21x1, b21x1, xbuf);
  k5_final<<<784, 256, 0, stream>>>(xbuf, Wbf, conv_b, attb, hbuf, out);
}

// Round 11
// 186.295 us; speedup vs baseline: 1.3413x; 1.0969x over previous
//
#include <hip/hip_runtime.h>
#include <hip/hip_bf16.h>

#define HW 3136
#define NB 16

typedef float f32x4 __attribute__((ext_vector_type(4)));
typedef float f32x2 __attribute__((ext_vector_type(2)));
typedef short short8 __attribute__((ext_vector_type(8)));
typedef unsigned short ushort8 __attribute__((ext_vector_type(8)));

__device__ inline unsigned short bfb(float f) {
  union { __hip_bfloat16 h; unsigned short u; } cv;
  cv.h = __float2bfloat16(f);
  return cv.u;
}
__device__ inline unsigned pack2(float lo, float hi) {
  return (unsigned)bfb(lo) | ((unsigned)bfb(hi) << 16);
}
// order-preserving float<->uint encode for atomicMax
__device__ inline unsigned fenc(float f) {
  unsigned u = __float_as_uint(f);
  return (u & 0x80000000u) ? ~u : (u | 0x80000000u);
}
__device__ inline float fdec(unsigned e) {
  return (e & 0x80000000u) ? __uint_as_float(e & 0x7FFFFFFFu) : __uint_as_float(~e);
}
__device__ inline float bf2f(unsigned short u) {
  return __uint_as_float((unsigned)u << 16);
}

// ---------------- K0: convert W to bf16, zero pool buffers ----------------
__global__ __launch_bounds__(256) void k0_init(const float* __restrict__ conv_w,
                                               unsigned short* __restrict__ Wbf,
                                               float* __restrict__ psum,
                                               unsigned* __restrict__ pmaxe) {
  int i = blockIdx.x * 256 + threadIdx.x;
  Wbf[i] = bfb(conv_w[i]);
  if (i < 4096) psum[i] = 0.f;
  else if (i < 8192) pmaxe[i - 4096] = 0u;
}

// ---------------- K1: conv1x1 + bias + GELU -> h (bf16) ; fused channel pooling ----------------
__global__ __launch_bounds__(256) void k1_conv_gelu_pool(
    const float* __restrict__ x, const unsigned short* __restrict__ Wbf,
    const float* __restrict__ conv_b, unsigned short* __restrict__ h_out,
    float* __restrict__ psum, unsigned* __restrict__ pmaxe)
{
  __shared__ __align__(16) unsigned short Bs[64 * 264];
  const int bid = blockIdx.x;
  const int b = bid / 49, tile = bid - 49 * (bid / 49);
  const int hw0 = tile * 64;
  const int t = threadIdx.x;

  {
    int g = t & 127, half = t >> 7;
    const float* p0 = x + ((size_t)(b * 256 + 2 * g)) * HW + hw0 + half * 32;
    const float* p1 = p0 + HW;
    unsigned* Bd = (unsigned*)Bs;
#pragma unroll
    for (int i = 0; i < 32; i += 4) {
      float4 a4 = *(const float4*)(p0 + i);
      float4 c4 = *(const float4*)(p1 + i);
      int hw = half * 32 + i;
      Bd[(hw + 0) * 132 + g] = pack2(a4.x, c4.x);
      Bd[(hw + 1) * 132 + g] = pack2(a4.y, c4.y);
      Bd[(hw + 2) * 132 + g] = pack2(a4.z, c4.z);
      Bd[(hw + 3) * 132 + g] = pack2(a4.w, c4.w);
    }
  }
  __syncthreads();

  const int w = t >> 6, l = t & 63, hq = l & 15, g2 = l >> 4;
  const int wm0 = w * 64;
  const f32x4 vzero = {0.f, 0.f, 0.f, 0.f};
  f32x4 acc[4][4];
#pragma unroll
  for (int mi = 0; mi < 4; ++mi)
#pragma unroll
    for (int ni = 0; ni < 4; ++ni) acc[mi][ni] = vzero;

#pragma unroll
  for (int ks = 0; ks < 8; ++ks) {
    short8 a[4], bv[4];
#pragma unroll
    for (int mi = 0; mi < 4; ++mi)
      a[mi] = *(const short8*)(Wbf + (size_t)(wm0 + mi * 16 + hq) * 256 + ks * 32 + g2 * 8);
#pragma unroll
    for (int ni = 0; ni < 4; ++ni)
      bv[ni] = *(const short8*)(Bs + (ni * 16 + hq) * 264 + ks * 32 + g2 * 8);
#pragma unroll
    for (int mi = 0; mi < 4; ++mi)
#pragma unroll
      for (int ni = 0; ni < 4; ++ni)
        acc[mi][ni] = __builtin_amdgcn_mfma_f32_16x16x32_bf16(a[mi], bv[ni], acc[mi][ni], 0, 0, 0);
  }
  __syncthreads();  // all waves done reading Bs before overwrite

  // fragment phase: bias + exact GELU -> bf16 into Bs[hw][o]
#pragma unroll
  for (int mi = 0; mi < 4; ++mi) {
#pragma unroll
    for (int r = 0; r < 4; ++r) {
      int o = wm0 + mi * 16 + g2 * 4 + r;
      float bias = conv_b[o];
#pragma unroll
      for (int ni = 0; ni < 4; ++ni) {
        float s = acc[mi][ni][r] + bias;
        float v = 0.5f * s * (1.0f + erff(s * 0.70710678118654752f));
        Bs[(ni * 16 + hq) * 264 + o] = bfb(v);
      }
    }
  }
  __syncthreads();

  // column pass: thread t = channel o; pool + vectorized store
  {
    const int o = t;
    float sm = 0.f, mx = -1e30f;
    unsigned pk[32];
#pragma unroll
    for (int m = 0; m < 32; ++m) {
      unsigned short r0 = Bs[(2 * m) * 264 + o];
      unsigned short r1 = Bs[(2 * m + 1) * 264 + o];
      float f0 = bf2f(r0), f1 = bf2f(r1);
      sm += f0 + f1;
      mx = fmaxf(mx, fmaxf(f0, f1));
      pk[m] = (unsigned)r0 | ((unsigned)r1 << 16);
    }
    unsigned short* hp = h_out + ((size_t)(b * 256 + o)) * HW + hw0;
#pragma unroll
    for (int q = 0; q < 8; ++q) {
      uint4 s4;
      s4.x = pk[q * 4 + 0]; s4.y = pk[q * 4 + 1]; s4.z = pk[q * 4 + 2]; s4.w = pk[q * 4 + 3];
      *(uint4*)(hp + q * 8) = s4;
    }
    atomicAdd(psum + b * 256 + o, sm);
    atomicMax(pmaxe + b * 256 + o, fenc(mx));
  }
}

// ---------------- K2: channel attention FCs (4-way c-split FC1) ----------------
__global__ __launch_bounds__(256) void k2_att(
    const float* __restrict__ psum, const unsigned* __restrict__ pmaxe,
    const float* __restrict__ fc1_w, const float* __restrict__ fc1_b,
    const float* __restrict__ fc2_w, const float* __restrict__ fc2_b,
    float* __restrict__ att)
{
  const int b = blockIdx.x, t = threadIdx.x;
  __shared__ float pA[4][64], pM[4][64];
  __shared__ float hA[64], hM[64];
  {
    const int j = t & 63, seg = t >> 6;
    const int base = b * 256 + seg * 64;
    const float* wrow = fc1_w + j * 256 + seg * 64;
    float sA = 0.f, sM = 0.f;
#pragma unroll 8
    for (int c = 0; c < 64; ++c) {
      float wv = wrow[c];
      sA += psum[base + c] * wv;
      sM += fdec(pmaxe[base + c]) * wv;
    }
    pA[seg][j] = sA;
    pM[seg][j] = sM;
  }
  __syncthreads();
  if (t < 64) {
    float a = fc1_b[t] + (pA[0][t] + pA[1][t] + pA[2][t] + pA[3][t]) * (1.f / 3136.f);
    float m = fc1_b[t] + (pM[0][t] + pM[1][t] + pM[2][t] + pM[3][t]);
    hA[t] = fmaxf(a, 0.f);
    hM[t] = fmaxf(m, 0.f);
  }
  __syncthreads();
  float s1 = fc2_b[t], s2 = s1;
#pragma unroll 8
  for (int j = 0; j < 64; ++j) {
    float wv = fc2_w[t * 64 + j];
    s1 += hA[j] * wv;
    s2 += hM[j] * wv;
  }
  att[b * 256 + t] = 1.f / (1.f + expf(-s1)) + 1.f / (1.f + expf(-s2));
}

// ---------------- K34 v10: fused depthwise chain, one plane per block ----------------
// P1/PB use the SAME column-pair task mapping (t<196: 8 rows x 2 cols), so the dw5x5
// result acc2[] stays in registers from P1 to PB (PB x_init re-read deleted).
// P1: rolling 12-row window, 6 scalar reads/row (72 total), f32x2 packed FMAs.
// PA unchanged (row tasks). PB: f32x2 packed vertical convs.
__global__ __launch_bounds__(256) void k34_dw(
    const unsigned short* __restrict__ h_in, const float* __restrict__ att,
    const float* __restrict__ w5, const float* __restrict__ b5,
    const float* __restrict__ w1x7, const float* __restrict__ b1x7,
    const float* __restrict__ w7x1, const float* __restrict__ b7x1,
    const float* __restrict__ w1x11, const float* __restrict__ b1x11,
    const float* __restrict__ w11x1, const float* __restrict__ b11x1,
    const float* __restrict__ w1x21, const float* __restrict__ b1x21,
    const float* __restrict__ w21x1, const float* __restrict__ b21x1,
    unsigned short* __restrict__ xs_out)
{
  __shared__ __align__(16) float B0[4256];
  __shared__ __align__(16) unsigned short T1[62 * 56];  // r = y+3
  __shared__ __align__(16) unsigned short T2[66 * 56];  // r = y+5
  __shared__ __align__(16) unsigned short T3[76 * 56];  // r = y+10
  __shared__ __align__(16) float wk5a[25];
  __shared__ __align__(16) float wk[78]; // [0,7)w1x7 [7,14)w7x1 [14,25)w1x11 [25,36)w11x1 [36,57)w1x21 [57,78)w21x1

  const int bid = blockIdx.x;
  const int b = bid >> 8, c = bid & 255;
  const int t = threadIdx.x;
  const size_t plane = (size_t)(b * 256 + c) * HW;
  const float a = att[b * 256 + c];

  if (t < 25) wk5a[t] = w5[c * 25 + t] * a;
  if (t >= 32 && t < 110) {
    int k = t - 32;
    float v;
    if (k < 7) v = w1x7[c * 7 + k];
    else if (k < 14) v = w7x1[c * 7 + k - 7];
    else if (k < 25) v = w1x11[c * 11 + k - 14];
    else if (k < 36) v = w11x1[c * 11 + k - 25];
    else if (k < 57) v = w1x21[c * 21 + k - 36];
    else v = w21x1[c * 21 + k - 57];
    wk[k] = v;
  }
  {
    unsigned* T1d = (unsigned*)T1; unsigned* T2d = (unsigned*)T2; unsigned* T3d = (unsigned*)T3;
    for (int i = t; i < 1008; i += 256) {
      if (i < 84) T1d[i] = 0;
      else if (i < 168) T1d[1652 + i - 84] = 0;
      else if (i < 308) T2d[i - 168] = 0;
      else if (i < 448) T2d[1708 + i - 308] = 0;
      else if (i < 728) T3d[i - 448] = 0;
      else T3d[1848 + i - 728] = 0;
    }
  }
  {
    const unsigned short* hp = h_in + plane;
    for (int idx = t; idx < 3600; idx += 256) {
      int ly = idx / 60, lx = idx - ly * 60;
      int gy = ly - 2, gx = lx - 2;
      float v = 0.f;
      if ((unsigned)gy < 56u && (unsigned)gx < 56u) v = bf2f(hp[gy * 56 + gx]);
      B0[idx] = v;
    }
  }
  __syncthreads();

  // P1: dw5x5 -> registers (f32x2, column-pair task = PB's mapping). 196 active threads.
  const int band = t / 28, xp = t - band * 28;
  const int py0 = band * 8, px0 = xp * 2;
  f32x2 acc2[8];
  {
    const float bias5 = b5[c];
#pragma unroll
    for (int d = 0; d < 8; ++d) { acc2[d].x = bias5; acc2[d].y = bias5; }
  }
  if (t < 196) {
#pragma unroll
    for (int r = 0; r < 12; ++r) {
      float row6[6];
#pragma unroll
      for (int k6 = 0; k6 < 6; ++k6) row6[k6] = B0[(py0 + r) * 60 + px0 + k6];
      const int dlo = (r > 4) ? (r - 4) : 0;
      const int dhi = (r < 7) ? r : 7;
#pragma unroll
      for (int d = 0; d < 8; ++d) {
        if (d < dlo || d > dhi) continue;
        const int ky = r - d;
#pragma unroll
        for (int kx = 0; kx < 5; ++kx) {
          float wv = wk5a[ky * 5 + kx];
          f32x2 p; p.x = row6[kx]; p.y = row6[kx + 1];
          acc2[d] = acc2[d] + p * wv;
        }
      }
    }
  }
  __syncthreads();

  // P2: write x_init to B0 [56][76] (data at col+10) as b64; zero col pads.
  if (t < 196) {
#pragma unroll
    for (int d = 0; d < 8; ++d)
      *(f32x2*)&B0[(py0 + d) * 76 + 10 + px0] = acc2[d];
  }
  for (int i = t; i < 1120; i += 256) {
    int y = i / 20, j = i - y * 20;
    int lx = (j < 10) ? j : (56 + j);   // pads: cols 0..9 and 66..75 (data at 10..65)
    B0[y * 76 + lx] = 0.f;
  }
  __syncthreads();

  // PA: fused horizontal convs. ROW task (y, x0..x0+7). win = x_init[y][x0-10..x0+17].
  const float bb1 = b1x7[c], bb2 = b1x11[c], bb3 = b1x21[c];
#pragma unroll
  for (int rnd = 0; rnd < 2; ++rnd) {
    if (rnd == 1 && t >= 136) break;
    int tau = t + rnd * 256;
    int y = tau / 7, x0 = (tau - y * 7) * 8;
    float win[28];
    const float* rp = B0 + y * 76 + x0;
#pragma unroll
    for (int j = 0; j < 28; j += 4) {
      float4 q = *(const float4*)(rp + j);
      win[j] = q.x; win[j + 1] = q.y; win[j + 2] = q.z; win[j + 3] = q.w;
    }
    float o1[8], o2[8], o3[8];
#pragma unroll
    for (int d = 0; d < 8; ++d) { o1[d] = bb1; o2[d] = bb2; o3[d] = bb3; }
#pragma unroll
    for (int k = 0; k < 7; ++k) {
      float wv = wk[k];
#pragma unroll
      for (int d = 0; d < 8; ++d) o1[d] += win[d + k + 7] * wv;
    }
#pragma unroll
    for (int k = 0; k < 11; ++k) {
      float wv = wk[14 + k];
#pragma unroll
      for (int d = 0; d < 8; ++d) o2[d] += win[d + k + 5] * wv;
    }
#pragma unroll
    for (int k = 0; k < 21; ++k) {
      float wv = wk[36 + k];
#pragma unroll
      for (int d = 0; d < 8; ++d) o3[d] += win[d + k] * wv;
    }
    uint4 s1, s2, s3;
    s1.x = pack2(o1[0], o1[1]); s1.y = pack2(o1[2], o1[3]); s1.z = pack2(o1[4], o1[5]); s1.w = pack2(o1[6], o1[7]);
    s2.x = pack2(o2[0], o2[1]); s2.y = pack2(o2[2], o2[3]); s2.z = pack2(o2[4], o2[5]); s2.w = pack2(o2[6], o2[7]);
    s3.x = pack2(o3[0], o3[1]); s3.y = pack2(o3[2], o3[3]); s3.z = pack2(o3[4], o3[5]); s3.w = pack2(o3[6], o3[7]);
    *(uint4*)&T1[(y + 3) * 56 + x0] = s1;
    *(uint4*)&T2[(y + 5) * 56 + x0] = s2;
    *(uint4*)&T3[(y + 10) * 56 + x0] = s3;
  }
  __syncthreads();

  // PB: fused vertical convs (f32x2) + x_init from registers -> global bf16 store.
  const float vb = b7x1[c] + b11x1[c] + b21x1[c];
  unsigned short* op = xs_out + plane;
  if (t < 196) {
    f32x2 r2[8];
#pragma unroll
    for (int d = 0; d < 8; ++d) r2[d] = acc2[d] + vb;
    {
      f32x2 c2[14];
#pragma unroll
      for (int j = 0; j < 14; ++j) {
        unsigned q = *(const unsigned*)&T1[(py0 + j) * 56 + px0];
        c2[j].x = __uint_as_float(q << 16);
        c2[j].y = __uint_as_float(q & 0xffff0000u);
      }
#pragma unroll
      for (int k = 0; k < 7; ++k) {
        float wv = wk[7 + k];
#pragma unroll
        for (int d = 0; d < 8; ++d) r2[d] = r2[d] + c2[d + k] * wv;
      }
    }
    {
      f32x2 c2[18];
#pragma unroll
      for (int j = 0; j < 18; ++j) {
        unsigned q = *(const unsigned*)&T2[(py0 + j) * 56 + px0];
        c2[j].x = __uint_as_float(q << 16);
        c2[j].y = __uint_as_float(q & 0xffff0000u);
      }
#pragma unroll
      for (int k = 0; k < 11; ++k) {
        float wv = wk[25 + k];
#pragma unroll
        for (int d = 0; d < 8; ++d) r2[d] = r2[d] + c2[d + k] * wv;
      }
    }
    {
      f32x2 c2[28];
#pragma unroll
      for (int j = 0; j < 28; ++j) {
        unsigned q = *(const unsigned*)&T3[(py0 + j) * 56 + px0];
        c2[j].x = __uint_as_float(q << 16);
        c2[j].y = __uint_as_float(q & 0xffff0000u);
      }
#pragma unroll
      for (int k = 0; k < 21; ++k) {
        float wv = wk[57 + k];
#pragma unroll
        for (int d = 0; d < 8; ++d) r2[d] = r2[d] + c2[d + k] * wv;
      }
    }
#pragma unroll
    for (int d = 0; d < 8; ++d)
      *(unsigned*)&op[(py0 + d) * 56 + px0] = pack2(r2[d].x, r2[d].y);
  }
}

// ---------------- K5: spatial_att = W*xs+b ; out = sa*(att*h) ; result = W*out+b ----------------
__global__ __launch_bounds__(256) void k5_final(
    const unsigned short* __restrict__ xs, const unsigned short* __restrict__ Wbf,
    const float* __restrict__ conv_b, const float* __restrict__ att,
    const unsigned short* __restrict__ h_in, float* __restrict__ outp)
{
  __shared__ __align__(16) unsigned short Bs[64 * 264];
  const int bid = blockIdx.x;
  const int b = bid / 49, tile = bid - 49 * (bid / 49);
  const int hw0 = tile * 64;
  const int t = threadIdx.x;

  { // stage xs (bf16) transposed into LDS, ushort8 (16B) loads
    int g = t & 127, half = t >> 7;
    const unsigned short* p0 = xs + ((size_t)(b * 256 + 2 * g)) * HW + hw0 + half * 32;
    const unsigned short* p1 = p0 + HW;
    unsigned* Bd = (unsigned*)Bs;
#pragma unroll
    for (int i = 0; i < 32; i += 8) {
      ushort8 a8 = *(const ushort8*)(p0 + i);
      ushort8 c8 = *(const ushort8*)(p1 + i);
      int hw = half * 32 + i;
#pragma unroll
      for (int e = 0; e < 8; ++e)
        Bd[(hw + e) * 132 + g] = (unsigned)a8[e] | ((unsigned)c8[e] << 16);
    }
  }
  __syncthreads();

  const int w = t >> 6, l = t & 63, hq = l & 15, g2 = l >> 4;
  const int wm0 = w * 64;
  const f32x4 vzero = {0.f, 0.f, 0.f, 0.f};
  f32x4 acc[4][4];
#pragma unroll
  for (int mi = 0; mi < 4; ++mi)
#pragma unroll
    for (int ni = 0; ni < 4; ++ni) acc[mi][ni] = vzero;

#pragma unroll
  for (int ks = 0; ks < 8; ++ks) {
    short8 a[4], bv[4];
#pragma unroll
    for (int mi = 0; mi < 4; ++mi)
      a[mi] = *(const short8*)(Wbf + (size_t)(wm0 + mi * 16 + hq) * 256 + ks * 32 + g2 * 8);
#pragma unroll
    for (int ni = 0; ni < 4; ++ni)
      bv[ni] = *(const short8*)(Bs + (ni * 16 + hq) * 264 + ks * 32 + g2 * 8);
#pragma unroll
    for (int mi = 0; mi < 4; ++mi)
#pragma unroll
      for (int ni = 0; ni < 4; ++ni)
        acc[mi][ni] = __builtin_amdgcn_mfma_f32_16x16x32_bf16(a[mi], bv[ni], acc[mi][ni], 0, 0, 0);
  }
  __syncthreads();

#pragma unroll
  for (int mi = 0; mi < 4; ++mi) {
#pragma unroll
    for (int r = 0; r < 4; ++r) {
      int o = wm0 + mi * 16 + g2 * 4 + r;
      float bias = conv_b[o];
      float av = att[b * 256 + o];
      const unsigned short* hp = h_in + ((size_t)(b * 256 + o)) * HW + hw0;
#pragma unroll
      for (int ni = 0; ni < 4; ++ni) {
        float sa = acc[mi][ni][r] + bias;
        float ov = sa * (av * bf2f(hp[ni * 16 + hq]));
        Bs[(ni * 16 + hq) * 264 + o] = bfb(ov);
      }
    }
  }
  __syncthreads();

  f32x4 acc2[4][4];
#pragma unroll
  for (int mi = 0; mi < 4; ++mi)
#pragma unroll
    for (int ni = 0; ni < 4; ++ni) acc2[mi][ni] = vzero;
#pragma unroll
  for (int ks = 0; ks < 8; ++ks) {
    short8 a[4], bv[4];
#pragma unroll
    for (int mi = 0; mi < 4; ++mi)
      a[mi] = *(const short8*)(Wbf + (size_t)(wm0 + mi * 16 + hq) * 256 + ks * 32 + g2 * 8);
#pragma unroll
    for (int ni = 0; ni < 4; ++ni)
      bv[ni] = *(const short8*)(Bs + (ni * 16 + hq) * 264 + ks * 32 + g2 * 8);
#pragma unroll
    for (int mi = 0; mi < 4; ++mi)
#pragma unroll
      for (int ni = 0; ni < 4; ++ni)
        acc2[mi][ni] = __builtin_amdgcn_mfma_f32_16x16x32_bf16(a[mi], bv[ni], acc2[mi][ni], 0, 0, 0);
  }

#pragma unroll
  for (int mi = 0; mi < 4; ++mi) {
#pragma unroll
    for (int r = 0; r < 4; ++r) {
      int o = wm0 + mi * 16 + g2 * 4 + r;
      float bias = conv_b[o];
      float* op = outp + ((size_t)(b * 256 + o)) * HW + hw0;
#pragma unroll
      for (int ni = 0; ni < 4; ++ni) op[ni * 16 + hq] = acc2[mi][ni][r] + bias;
    }
  }
}

extern "C" void kernel_launch(void* const* d_in, const int* in_sizes, int n_in,
                              void* d_out, int out_size, void* d_ws, size_t ws_size,
                              hipStream_t stream) {
  const float* x      = (const float*)d_in[0];
  const float* conv_w = (const float*)d_in[1];
  const float* conv_b = (const float*)d_in[2];
  const float* fc1_w  = (const float*)d_in[3];
  const float* fc1_b  = (const float*)d_in[4];
  const float* fc2_w  = (const float*)d_in[5];
  const float* fc2_b  = (const float*)d_in[6];
  const float* w5     = (const float*)d_in[7];
  const float* b5     = (const float*)d_in[8];
  const float* w1x7   = (const float*)d_in[9];
  const float* b1x7   = (const float*)d_in[10];
  const float* w7x1   = (const float*)d_in[11];
  const float* b7x1   = (const float*)d_in[12];
  const float* w1x11  = (const float*)d_in[13];
  const float* b1x11  = (const float*)d_in[14];
  const float* w11x1  = (const float*)d_in[15];
  const float* b11x1  = (const float*)d_in[16];
  const float* w1x21  = (const float*)d_in[17];
  const float* b1x21  = (const float*)d_in[18];
  const float* w21x1  = (const float*)d_in[19];
  const float* b21x1  = (const float*)d_in[20];
  float* out = (float*)d_out;

  char* ws = (char*)d_ws;
  unsigned short* Wbf = (unsigned short*)(ws);            // 131072 B
  float* psum   = (float*)(ws + 131072);                  // 16384 B
  unsigned* pme = (unsigned*)(ws + 147456);               // 16384 B
  float* attb   = (float*)(ws + 163840);                  // 16384 B
  unsigned short* hbuf = (unsigned short*)(ws + 180224);  // 25690112 B (h bf16)
  unsigned short* xbuf = (unsigned short*)(ws + 180224 + 25690112); // 25690112 B (xs bf16)

  k0_init<<<256, 256, 0, stream>>>(conv_w, Wbf, psum, pme);
  k1_conv_gelu_pool<<<784, 256, 0, stream>>>(x, Wbf, conv_b, hbuf, psum, pme);
  k2_att<<<16, 256, 0, stream>>>(psum, pme, fc1_w, fc1_b, fc2_w, fc2_b, attb);
  k34_dw<<<4096, 256, 0, stream>>>(hbuf, attb, w5, b5, w1x7, b1x7, w7x1, b7x1,
                                   w1x11, b1x11, w11x1, b11x1, w1x21, b1x21,
                                   w21x1, b21x1, xbuf);
  k5_final<<<784, 256, 0, stream>>>(xbuf, Wbf, conv_b, attb, hbuf, out);
}

// Round 12
// 184.897 us; speedup vs baseline: 1.3514x; 1.0076x over previous
//
#include <hip/hip_runtime.h>
#include <hip/hip_bf16.h>

#define HW 3136
#define NB 16

typedef float f32x4 __attribute__((ext_vector_type(4)));
typedef float f32x2 __attribute__((ext_vector_type(2)));
typedef short short8 __attribute__((ext_vector_type(8)));
typedef unsigned short ushort8 __attribute__((ext_vector_type(8)));

__device__ inline unsigned short bfb(float f) {
  union { __hip_bfloat16 h; unsigned short u; } cv;
  cv.h = __float2bfloat16(f);
  return cv.u;
}
__device__ inline unsigned pack2(float lo, float hi) {
  return (unsigned)bfb(lo) | ((unsigned)bfb(hi) << 16);
}
// order-preserving float<->uint encode for atomicMax
__device__ inline unsigned fenc(float f) {
  unsigned u = __float_as_uint(f);
  return (u & 0x80000000u) ? ~u : (u | 0x80000000u);
}
__device__ inline float fdec(unsigned e) {
  return (e & 0x80000000u) ? __uint_as_float(e & 0x7FFFFFFFu) : __uint_as_float(~e);
}
__device__ inline float bf2f(unsigned short u) {
  return __uint_as_float((unsigned)u << 16);
}

// ---------------- K0: convert W to bf16, zero pool buffers ----------------
__global__ __launch_bounds__(256) void k0_init(const float* __restrict__ conv_w,
                                               unsigned short* __restrict__ Wbf,
                                               float* __restrict__ psum,
                                               unsigned* __restrict__ pmaxe) {
  int i = blockIdx.x * 256 + threadIdx.x;
  Wbf[i] = bfb(conv_w[i]);
  if (i < 4096) psum[i] = 0.f;
  else if (i < 8192) pmaxe[i - 4096] = 0u;
}

// ---------------- K1 v11: conv1x1 + bias + GELU -> h (bf16) ; fused channel pooling ----------------
// TILE = 32 hw (was 64): LDS 16.9KB -> 8 blocks/CU possible; grid 1568 -> ~6 blocks/CU
// (~24 waves/CU vs 12) to hide scattered-load latency. acc[4][2] per wave.
__global__ __launch_bounds__(256) void k1_conv_gelu_pool(
    const float* __restrict__ x, const unsigned short* __restrict__ Wbf,
    const float* __restrict__ conv_b, unsigned short* __restrict__ h_out,
    float* __restrict__ psum, unsigned* __restrict__ pmaxe)
{
  __shared__ __align__(16) unsigned short Bs[32 * 264];
  const int bid = blockIdx.x;
  const int b = bid / 98, tile = bid - 98 * (bid / 98);
  const int hw0 = tile * 32;
  const int t = threadIdx.x;

  { // stage x[b, :, hw0..hw0+32) transposed bf16 into Bs[hw][c]
    int g = t & 127, half = t >> 7;
    const float* p0 = x + ((size_t)(b * 256 + 2 * g)) * HW + hw0 + half * 16;
    const float* p1 = p0 + HW;
    unsigned* Bd = (unsigned*)Bs;
#pragma unroll
    for (int i = 0; i < 16; i += 4) {
      float4 a4 = *(const float4*)(p0 + i);
      float4 c4 = *(const float4*)(p1 + i);
      int hw = half * 16 + i;
      Bd[(hw + 0) * 132 + g] = pack2(a4.x, c4.x);
      Bd[(hw + 1) * 132 + g] = pack2(a4.y, c4.y);
      Bd[(hw + 2) * 132 + g] = pack2(a4.z, c4.z);
      Bd[(hw + 3) * 132 + g] = pack2(a4.w, c4.w);
    }
  }
  __syncthreads();

  const int w = t >> 6, l = t & 63, hq = l & 15, g2 = l >> 4;
  const int wm0 = w * 64;
  const f32x4 vzero = {0.f, 0.f, 0.f, 0.f};
  f32x4 acc[4][2];
#pragma unroll
  for (int mi = 0; mi < 4; ++mi)
#pragma unroll
    for (int ni = 0; ni < 2; ++ni) acc[mi][ni] = vzero;

#pragma unroll
  for (int ks = 0; ks < 8; ++ks) {
    short8 a[4], bv[2];
#pragma unroll
    for (int mi = 0; mi < 4; ++mi)
      a[mi] = *(const short8*)(Wbf + (size_t)(wm0 + mi * 16 + hq) * 256 + ks * 32 + g2 * 8);
#pragma unroll
    for (int ni = 0; ni < 2; ++ni)
      bv[ni] = *(const short8*)(Bs + (ni * 16 + hq) * 264 + ks * 32 + g2 * 8);
#pragma unroll
    for (int mi = 0; mi < 4; ++mi)
#pragma unroll
      for (int ni = 0; ni < 2; ++ni)
        acc[mi][ni] = __builtin_amdgcn_mfma_f32_16x16x32_bf16(a[mi], bv[ni], acc[mi][ni], 0, 0, 0);
  }
  __syncthreads();  // all waves done reading Bs before overwrite

  // fragment phase: bias + exact GELU -> bf16 into Bs[hw][o]
#pragma unroll
  for (int mi = 0; mi < 4; ++mi) {
#pragma unroll
    for (int r = 0; r < 4; ++r) {
      int o = wm0 + mi * 16 + g2 * 4 + r;
      float bias = conv_b[o];
#pragma unroll
      for (int ni = 0; ni < 2; ++ni) {
        float s = acc[mi][ni][r] + bias;
        float v = 0.5f * s * (1.0f + erff(s * 0.70710678118654752f));
        Bs[(ni * 16 + hq) * 264 + o] = bfb(v);
      }
    }
  }
  __syncthreads();

  // column pass: thread t = channel o; pool 32 rows + vectorized store
  {
    const int o = t;
    float sm = 0.f, mx = -1e30f;
    unsigned pk[16];
#pragma unroll
    for (int m = 0; m < 16; ++m) {
      unsigned short r0 = Bs[(2 * m) * 264 + o];
      unsigned short r1 = Bs[(2 * m + 1) * 264 + o];
      float f0 = bf2f(r0), f1 = bf2f(r1);
      sm += f0 + f1;
      mx = fmaxf(mx, fmaxf(f0, f1));
      pk[m] = (unsigned)r0 | ((unsigned)r1 << 16);
    }
    unsigned short* hp = h_out + ((size_t)(b * 256 + o)) * HW + hw0;
#pragma unroll
    for (int q = 0; q < 4; ++q) {
      uint4 s4;
      s4.x = pk[q * 4 + 0]; s4.y = pk[q * 4 + 1]; s4.z = pk[q * 4 + 2]; s4.w = pk[q * 4 + 3];
      *(uint4*)(hp + q * 8) = s4;
    }
    atomicAdd(psum + b * 256 + o, sm);
    atomicMax(pmaxe + b * 256 + o, fenc(mx));
  }
}

// ---------------- K2: channel attention FCs (4-way c-split FC1) ----------------
__global__ __launch_bounds__(256) void k2_att(
    const float* __restrict__ psum, const unsigned* __restrict__ pmaxe,
    const float* __restrict__ fc1_w, const float* __restrict__ fc1_b,
    const float* __restrict__ fc2_w, const float* __restrict__ fc2_b,
    float* __restrict__ att)
{
  const int b = blockIdx.x, t = threadIdx.x;
  __shared__ float pA[4][64], pM[4][64];
  __shared__ float hA[64], hM[64];
  {
    const int j = t & 63, seg = t >> 6;
    const int base = b * 256 + seg * 64;
    const float* wrow = fc1_w + j * 256 + seg * 64;
    float sA = 0.f, sM = 0.f;
#pragma unroll 8
    for (int c = 0; c < 64; ++c) {
      float wv = wrow[c];
      sA += psum[base + c] * wv;
      sM += fdec(pmaxe[base + c]) * wv;
    }
    pA[seg][j] = sA;
    pM[seg][j] = sM;
  }
  __syncthreads();
  if (t < 64) {
    float a = fc1_b[t] + (pA[0][t] + pA[1][t] + pA[2][t] + pA[3][t]) * (1.f / 3136.f);
    float m = fc1_b[t] + (pM[0][t] + pM[1][t] + pM[2][t] + pM[3][t]);
    hA[t] = fmaxf(a, 0.f);
    hM[t] = fmaxf(m, 0.f);
  }
  __syncthreads();
  float s1 = fc2_b[t], s2 = s1;
#pragma unroll 8
  for (int j = 0; j < 64; ++j) {
    float wv = fc2_w[t * 64 + j];
    s1 += hA[j] * wv;
    s2 += hM[j] * wv;
  }
  att[b * 256 + t] = 1.f / (1.f + expf(-s1)) + 1.f / (1.f + expf(-s2));
}

// ---------------- K34 v10 (unchanged): fused depthwise chain, one plane per block ----------------
__global__ __launch_bounds__(256) void k34_dw(
    const unsigned short* __restrict__ h_in, const float* __restrict__ att,
    const float* __restrict__ w5, const float* __restrict__ b5,
    const float* __restrict__ w1x7, const float* __restrict__ b1x7,
    const float* __restrict__ w7x1, const float* __restrict__ b7x1,
    const float* __restrict__ w1x11, const float* __restrict__ b1x11,
    const float* __restrict__ w11x1, const float* __restrict__ b11x1,
    const float* __restrict__ w1x21, const float* __restrict__ b1x21,
    const float* __restrict__ w21x1, const float* __restrict__ b21x1,
    unsigned short* __restrict__ xs_out)
{
  __shared__ __align__(16) float B0[4256];
  __shared__ __align__(16) unsigned short T1[62 * 56];  // r = y+3
  __shared__ __align__(16) unsigned short T2[66 * 56];  // r = y+5
  __shared__ __align__(16) unsigned short T3[76 * 56];  // r = y+10
  __shared__ __align__(16) float wk5a[25];
  __shared__ __align__(16) float wk[78]; // [0,7)w1x7 [7,14)w7x1 [14,25)w1x11 [25,36)w11x1 [36,57)w1x21 [57,78)w21x1

  const int bid = blockIdx.x;
  const int b = bid >> 8, c = bid & 255;
  const int t = threadIdx.x;
  const size_t plane = (size_t)(b * 256 + c) * HW;
  const float a = att[b * 256 + c];

  if (t < 25) wk5a[t] = w5[c * 25 + t] * a;
  if (t >= 32 && t < 110) {
    int k = t - 32;
    float v;
    if (k < 7) v = w1x7[c * 7 + k];
    else if (k < 14) v = w7x1[c * 7 + k - 7];
    else if (k < 25) v = w1x11[c * 11 + k - 14];
    else if (k < 36) v = w11x1[c * 11 + k - 25];
    else if (k < 57) v = w1x21[c * 21 + k - 36];
    else v = w21x1[c * 21 + k - 57];
    wk[k] = v;
  }
  {
    unsigned* T1d = (unsigned*)T1; unsigned* T2d = (unsigned*)T2; unsigned* T3d = (unsigned*)T3;
    for (int i = t; i < 1008; i += 256) {
      if (i < 84) T1d[i] = 0;
      else if (i < 168) T1d[1652 + i - 84] = 0;
      else if (i < 308) T2d[i - 168] = 0;
      else if (i < 448) T2d[1708 + i - 308] = 0;
      else if (i < 728) T3d[i - 448] = 0;
      else T3d[1848 + i - 728] = 0;
    }
  }
  {
    const unsigned short* hp = h_in + plane;
    for (int idx = t; idx < 3600; idx += 256) {
      int ly = idx / 60, lx = idx - ly * 60;
      int gy = ly - 2, gx = lx - 2;
      float v = 0.f;
      if ((unsigned)gy < 56u && (unsigned)gx < 56u) v = bf2f(hp[gy * 56 + gx]);
      B0[idx] = v;
    }
  }
  __syncthreads();

  // P1: dw5x5 -> registers (f32x2, column-pair task = PB's mapping). 196 active threads.
  const int band = t / 28, xp = t - band * 28;
  const int py0 = band * 8, px0 = xp * 2;
  f32x2 acc2[8];
  {
    const float bias5 = b5[c];
#pragma unroll
    for (int d = 0; d < 8; ++d) { acc2[d].x = bias5; acc2[d].y = bias5; }
  }
  if (t < 196) {
#pragma unroll
    for (int r = 0; r < 12; ++r) {
      float row6[6];
#pragma unroll
      for (int k6 = 0; k6 < 6; ++k6) row6[k6] = B0[(py0 + r) * 60 + px0 + k6];
      const int dlo = (r > 4) ? (r - 4) : 0;
      const int dhi = (r < 7) ? r : 7;
#pragma unroll
      for (int d = 0; d < 8; ++d) {
        if (d < dlo || d > dhi) continue;
        const int ky = r - d;
#pragma unroll
        for (int kx = 0; kx < 5; ++kx) {
          float wv = wk5a[ky * 5 + kx];
          f32x2 p; p.x = row6[kx]; p.y = row6[kx + 1];
          acc2[d] = acc2[d] + p * wv;
        }
      }
    }
  }
  __syncthreads();

  // P2: write x_init to B0 [56][76] (data at col+10) as b64; zero col pads.
  if (t < 196) {
#pragma unroll
    for (int d = 0; d < 8; ++d)
      *(f32x2*)&B0[(py0 + d) * 76 + 10 + px0] = acc2[d];
  }
  for (int i = t; i < 1120; i += 256) {
    int y = i / 20, j = i - y * 20;
    int lx = (j < 10) ? j : (56 + j);   // pads: cols 0..9 and 66..75 (data at 10..65)
    B0[y * 76 + lx] = 0.f;
  }
  __syncthreads();

  // PA: fused horizontal convs. ROW task (y, x0..x0+7). win = x_init[y][x0-10..x0+17].
  const float bb1 = b1x7[c], bb2 = b1x11[c], bb3 = b1x21[c];
#pragma unroll
  for (int rnd = 0; rnd < 2; ++rnd) {
    if (rnd == 1 && t >= 136) break;
    int tau = t + rnd * 256;
    int y = tau / 7, x0 = (tau - y * 7) * 8;
    float win[28];
    const float* rp = B0 + y * 76 + x0;
#pragma unroll
    for (int j = 0; j < 28; j += 4) {
      float4 q = *(const float4*)(rp + j);
      win[j] = q.x; win[j + 1] = q.y; win[j + 2] = q.z; win[j + 3] = q.w;
    }
    float o1[8], o2[8], o3[8];
#pragma unroll
    for (int d = 0; d < 8; ++d) { o1[d] = bb1; o2[d] = bb2; o3[d] = bb3; }
#pragma unroll
    for (int k = 0; k < 7; ++k) {
      float wv = wk[k];
#pragma unroll
      for (int d = 0; d < 8; ++d) o1[d] += win[d + k + 7] * wv;
    }
#pragma unroll
    for (int k = 0; k < 11; ++k) {
      float wv = wk[14 + k];
#pragma unroll
      for (int d = 0; d < 8; ++d) o2[d] += win[d + k + 5] * wv;
    }
#pragma unroll
    for (int k = 0; k < 21; ++k) {
      float wv = wk[36 + k];
#pragma unroll
      for (int d = 0; d < 8; ++d) o3[d] += win[d + k] * wv;
    }
    uint4 s1, s2, s3;
    s1.x = pack2(o1[0], o1[1]); s1.y = pack2(o1[2], o1[3]); s1.z = pack2(o1[4], o1[5]); s1.w = pack2(o1[6], o1[7]);
    s2.x = pack2(o2[0], o2[1]); s2.y = pack2(o2[2], o2[3]); s2.z = pack2(o2[4], o2[5]); s2.w = pack2(o2[6], o2[7]);
    s3.x = pack2(o3[0], o3[1]); s3.y = pack2(o3[2], o3[3]); s3.z = pack2(o3[4], o3[5]); s3.w = pack2(o3[6], o3[7]);
    *(uint4*)&T1[(y + 3) * 56 + x0] = s1;
    *(uint4*)&T2[(y + 5) * 56 + x0] = s2;
    *(uint4*)&T3[(y + 10) * 56 + x0] = s3;
  }
  __syncthreads();

  // PB: fused vertical convs (f32x2) + x_init from registers -> global bf16 store.
  const float vb = b7x1[c] + b11x1[c] + b21x1[c];
  unsigned short* op = xs_out + plane;
  if (t < 196) {
    f32x2 r2[8];
#pragma unroll
    for (int d = 0; d < 8; ++d) r2[d] = acc2[d] + vb;
    {
      f32x2 c2[14];
#pragma unroll
      for (int j = 0; j < 14; ++j) {
        unsigned q = *(const unsigned*)&T1[(py0 + j) * 56 + px0];
        c2[j].x = __uint_as_float(q << 16);
        c2[j].y = __uint_as_float(q & 0xffff0000u);
      }
#pragma unroll
      for (int k = 0; k < 7; ++k) {
        float wv = wk[7 + k];
#pragma unroll
        for (int d = 0; d < 8; ++d) r2[d] = r2[d] + c2[d + k] * wv;
      }
    }
    {
      f32x2 c2[18];
#pragma unroll
      for (int j = 0; j < 18; ++j) {
        unsigned q = *(const unsigned*)&T2[(py0 + j) * 56 + px0];
        c2[j].x = __uint_as_float(q << 16);
        c2[j].y = __uint_as_float(q & 0xffff0000u);
      }
#pragma unroll
      for (int k = 0; k < 11; ++k) {
        float wv = wk[25 + k];
#pragma unroll
        for (int d = 0; d < 8; ++d) r2[d] = r2[d] + c2[d + k] * wv;
      }
    }
    {
      f32x2 c2[28];
#pragma unroll
      for (int j = 0; j < 28; ++j) {
        unsigned q = *(const unsigned*)&T3[(py0 + j) * 56 + px0];
        c2[j].x = __uint_as_float(q << 16);
        c2[j].y = __uint_as_float(q & 0xffff0000u);
      }
#pragma unroll
      for (int k = 0; k < 21; ++k) {
        float wv = wk[57 + k];
#pragma unroll
        for (int d = 0; d < 8; ++d) r2[d] = r2[d] + c2[d + k] * wv;
      }
    }
#pragma unroll
    for (int d = 0; d < 8; ++d)
      *(unsigned*)&op[(py0 + d) * 56 + px0] = pack2(r2[d].x, r2[d].y);
  }
}

// ---------------- K5: spatial_att = W*xs+b ; out = sa*(att*h) ; result = W*out+b ----------------
__global__ __launch_bounds__(256) void k5_final(
    const unsigned short* __restrict__ xs, const unsigned short* __restrict__ Wbf,
    const float* __restrict__ conv_b, const float* __restrict__ att,
    const unsigned short* __restrict__ h_in, float* __restrict__ outp)
{
  __shared__ __align__(16) unsigned short Bs[64 * 264];
  const int bid = blockIdx.x;
  const int b = bid / 49, tile = bid - 49 * (bid / 49);
  const int hw0 = tile * 64;
  const int t = threadIdx.x;

  { // stage xs (bf16) transposed into LDS, ushort8 (16B) loads
    int g = t & 127, half = t >> 7;
    const unsigned short* p0 = xs + ((size_t)(b * 256 + 2 * g)) * HW + hw0 + half * 32;
    const unsigned short* p1 = p0 + HW;
    unsigned* Bd = (unsigned*)Bs;
#pragma unroll
    for (int i = 0; i < 32; i += 8) {
      ushort8 a8 = *(const ushort8*)(p0 + i);
      ushort8 c8 = *(const ushort8*)(p1 + i);
      int hw = half * 32 + i;
#pragma unroll
      for (int e = 0; e < 8; ++e)
        Bd[(hw + e) * 132 + g] = (unsigned)a8[e] | ((unsigned)c8[e] << 16);
    }
  }
  __syncthreads();

  const int w = t >> 6, l = t & 63, hq = l & 15, g2 = l >> 4;
  const int wm0 = w * 64;
  const f32x4 vzero = {0.f, 0.f, 0.f, 0.f};
  f32x4 acc[4][4];
#pragma unroll
  for (int mi = 0; mi < 4; ++mi)
#pragma unroll
    for (int ni = 0; ni < 4; ++ni) acc[mi][ni] = vzero;

#pragma unroll
  for (int ks = 0; ks < 8; ++ks) {
    short8 a[4], bv[4];
#pragma unroll
    for (int mi = 0; mi < 4; ++mi)
      a[mi] = *(const short8*)(Wbf + (size_t)(wm0 + mi * 16 + hq) * 256 + ks * 32 + g2 * 8);
#pragma unroll
    for (int ni = 0; ni < 4; ++ni)
      bv[ni] = *(const short8*)(Bs + (ni * 16 + hq) * 264 + ks * 32 + g2 * 8);
#pragma unroll
    for (int mi = 0; mi < 4; ++mi)
#pragma unroll
      for (int ni = 0; ni < 4; ++ni)
        acc[mi][ni] = __builtin_amdgcn_mfma_f32_16x16x32_bf16(a[mi], bv[ni], acc[mi][ni], 0, 0, 0);
  }
  __syncthreads();

#pragma unroll
  for (int mi = 0; mi < 4; ++mi) {
#pragma unroll
    for (int r = 0; r < 4; ++r) {
      int o = wm0 + mi * 16 + g2 * 4 + r;
      float bias = conv_b[o];
      float av = att[b * 256 + o];
      const unsigned short* hp = h_in + ((size_t)(b * 256 + o)) * HW + hw0;
#pragma unroll
      for (int ni = 0; ni < 4; ++ni) {
        float sa = acc[mi][ni][r] + bias;
        float ov = sa * (av * bf2f(hp[ni * 16 + hq]));
        Bs[(ni * 16 + hq) * 264 + o] = bfb(ov);
      }
    }
  }
  __syncthreads();

  f32x4 acc2[4][4];
#pragma unroll
  for (int mi = 0; mi < 4; ++mi)
#pragma unroll
    for (int ni = 0; ni < 4; ++ni) acc2[mi][ni] = vzero;
#pragma unroll
  for (int ks = 0; ks < 8; ++ks) {
    short8 a[4], bv[4];
#pragma unroll
    for (int mi = 0; mi < 4; ++mi)
      a[mi] = *(const short8*)(Wbf + (size_t)(wm0 + mi * 16 + hq) * 256 + ks * 32 + g2 * 8);
#pragma unroll
    for (int ni = 0; ni < 4; ++ni)
      bv[ni] = *(const short8*)(Bs + (ni * 16 + hq) * 264 + ks * 32 + g2 * 8);
#pragma unroll
    for (int mi = 0; mi < 4; ++mi)
#pragma unroll
      for (int ni = 0; ni < 4; ++ni)
        acc2[mi][ni] = __builtin_amdgcn_mfma_f32_16x16x32_bf16(a[mi], bv[ni], acc2[mi][ni], 0, 0, 0);
  }

#pragma unroll
  for (int mi = 0; mi < 4; ++mi) {
#pragma unroll
    for (int r = 0; r < 4; ++r) {
      int o = wm0 + mi * 16 + g2 * 4 + r;
      float bias = conv_b[o];
      float* op = outp + ((size_t)(b * 256 + o)) * HW + hw0;
#pragma unroll
      for (int ni = 0; ni < 4; ++ni) op[ni * 16 + hq] = acc2[mi][ni][r] + bias;
    }
  }
}

extern "C" void kernel_launch(void* const* d_in, const int* in_sizes, int n_in,
                              void* d_out, int out_size, void* d_ws, size_t ws_size,
                              hipStream_t stream) {
  const float* x      = (const float*)d_in[0];
  const float* conv_w = (const float*)d_in[1];
  const float* conv_b = (const float*)d_in[2];
  const float* fc1_w  = (const float*)d_in[3];
  const float* fc1_b  = (const float*)d_in[4];
  const float* fc2_w  = (const float*)d_in[5];
  const float* fc2_b  = (const float*)d_in[6];
  const float* w5     = (const float*)d_in[7];
  const float* b5     = (const float*)d_in[8];
  const float* w1x7   = (const float*)d_in[9];
  const float* b1x7   = (const float*)d_in[10];
  const float* w7x1   = (const float*)d_in[11];
  const float* b7x1   = (const float*)d_in[12];
  const float* w1x11  = (const float*)d_in[13];
  const float* b1x11  = (const float*)d_in[14];
  const float* w11x1  = (const float*)d_in[15];
  const float* b11x1  = (const float*)d_in[16];
  const float* w1x21  = (const float*)d_in[17];
  const float* b1x21  = (const float*)d_in[18];
  const float* w21x1  = (const float*)d_in[19];
  const float* b21x1  = (const float*)d_in[20];
  float* out = (float*)d_out;

  char* ws = (char*)d_ws;
  unsigned short* Wbf = (unsigned short*)(ws);            // 131072 B
  float* psum   = (float*)(ws + 131072);                  // 16384 B
  unsigned* pme = (unsigned*)(ws + 147456);               // 16384 B
  float* attb   = (float*)(ws + 163840);                  // 16384 B
  unsigned short* hbuf = (unsigned short*)(ws + 180224);  // 25690112 B (h bf16)
  unsigned short* xbuf = (unsigned short*)(ws + 180224 + 25690112); // 25690112 B (xs bf16)

  k0_init<<<256, 256, 0, stream>>>(conv_w, Wbf, psum, pme);
  k1_conv_gelu_pool<<<1568, 256, 0, stream>>>(x, Wbf, conv_b, hbuf, psum, pme);
  k2_att<<<16, 256, 0, stream>>>(psum, pme, fc1_w, fc1_b, fc2_w, fc2_b, attb);
  k34_dw<<<4096, 256, 0, stream>>>(hbuf, attb, w5, b5, w1x7, b1x7, w7x1, b7x1,
                                   w1x11, b1x11, w11x1, b11x1, w1x21, b1x21,
                                   w21x1, b21x1, xbuf);
  k5_final<<<784, 256, 0, stream>>>(xbuf, Wbf, conv_b, attb, hbuf, out);
}

// Round 13
// 180.583 us; speedup vs baseline: 1.3837x; 1.0239x over previous
//
#include <hip/hip_runtime.h>
#include <hip/hip_bf16.h>

#define HW 3136
#define NB 16

typedef float f32x4 __attribute__((ext_vector_type(4)));
typedef float f32x2 __attribute__((ext_vector_type(2)));
typedef short short8 __attribute__((ext_vector_type(8)));
typedef unsigned short ushort8 __attribute__((ext_vector_type(8)));

__device__ inline unsigned short bfb(float f) {
  union { __hip_bfloat16 h; unsigned short u; } cv;
  cv.h = __float2bfloat16(f);
  return cv.u;
}
__device__ inline unsigned pack2(float lo, float hi) {
  return (unsigned)bfb(lo) | ((unsigned)bfb(hi) << 16);
}
// order-preserving float<->uint encode for atomicMax
__device__ inline unsigned fenc(float f) {
  unsigned u = __float_as_uint(f);
  return (u & 0x80000000u) ? ~u : (u | 0x80000000u);
}
__device__ inline float fdec(unsigned e) {
  return (e & 0x80000000u) ? __uint_as_float(e & 0x7FFFFFFFu) : __uint_as_float(~e);
}
__device__ inline float bf2f(unsigned short u) {
  return __uint_as_float((unsigned)u << 16);
}
__device__ inline float lo16f(unsigned q) { return __uint_as_float(q << 16); }
__device__ inline float hi16f(unsigned q) { return __uint_as_float(q & 0xffff0000u); }

// ---------------- K0: convert W to bf16, zero pool buffers ----------------
__global__ __launch_bounds__(256) void k0_init(const float* __restrict__ conv_w,
                                               unsigned short* __restrict__ Wbf,
                                               float* __restrict__ psum,
                                               unsigned* __restrict__ pmaxe) {
  int i = blockIdx.x * 256 + threadIdx.x;
  Wbf[i] = bfb(conv_w[i]);
  if (i < 4096) psum[i] = 0.f;
  else if (i < 8192) pmaxe[i - 4096] = 0u;
}

// ---------------- K1 v11: conv1x1 + bias + GELU -> h (bf16) ; fused channel pooling ----------------
__global__ __launch_bounds__(256) void k1_conv_gelu_pool(
    const float* __restrict__ x, const unsigned short* __restrict__ Wbf,
    const float* __restrict__ conv_b, unsigned short* __restrict__ h_out,
    float* __restrict__ psum, unsigned* __restrict__ pmaxe)
{
  __shared__ __align__(16) unsigned short Bs[32 * 264];
  const int bid = blockIdx.x;
  const int b = bid / 98, tile = bid - 98 * (bid / 98);
  const int hw0 = tile * 32;
  const int t = threadIdx.x;

  { // stage x[b, :, hw0..hw0+32) transposed bf16 into Bs[hw][c]
    int g = t & 127, half = t >> 7;
    const float* p0 = x + ((size_t)(b * 256 + 2 * g)) * HW + hw0 + half * 16;
    const float* p1 = p0 + HW;
    unsigned* Bd = (unsigned*)Bs;
#pragma unroll
    for (int i = 0; i < 16; i += 4) {
      float4 a4 = *(const float4*)(p0 + i);
      float4 c4 = *(const float4*)(p1 + i);
      int hw = half * 16 + i;
      Bd[(hw + 0) * 132 + g] = pack2(a4.x, c4.x);
      Bd[(hw + 1) * 132 + g] = pack2(a4.y, c4.y);
      Bd[(hw + 2) * 132 + g] = pack2(a4.z, c4.z);
      Bd[(hw + 3) * 132 + g] = pack2(a4.w, c4.w);
    }
  }
  __syncthreads();

  const int w = t >> 6, l = t & 63, hq = l & 15, g2 = l >> 4;
  const int wm0 = w * 64;
  const f32x4 vzero = {0.f, 0.f, 0.f, 0.f};
  f32x4 acc[4][2];
#pragma unroll
  for (int mi = 0; mi < 4; ++mi)
#pragma unroll
    for (int ni = 0; ni < 2; ++ni) acc[mi][ni] = vzero;

#pragma unroll
  for (int ks = 0; ks < 8; ++ks) {
    short8 a[4], bv[2];
#pragma unroll
    for (int mi = 0; mi < 4; ++mi)
      a[mi] = *(const short8*)(Wbf + (size_t)(wm0 + mi * 16 + hq) * 256 + ks * 32 + g2 * 8);
#pragma unroll
    for (int ni = 0; ni < 2; ++ni)
      bv[ni] = *(const short8*)(Bs + (ni * 16 + hq) * 264 + ks * 32 + g2 * 8);
#pragma unroll
    for (int mi = 0; mi < 4; ++mi)
#pragma unroll
      for (int ni = 0; ni < 2; ++ni)
        acc[mi][ni] = __builtin_amdgcn_mfma_f32_16x16x32_bf16(a[mi], bv[ni], acc[mi][ni], 0, 0, 0);
  }
  __syncthreads();  // all waves done reading Bs before overwrite

  // fragment phase: bias + exact GELU -> bf16 into Bs[hw][o]
#pragma unroll
  for (int mi = 0; mi < 4; ++mi) {
#pragma unroll
    for (int r = 0; r < 4; ++r) {
      int o = wm0 + mi * 16 + g2 * 4 + r;
      float bias = conv_b[o];
#pragma unroll
      for (int ni = 0; ni < 2; ++ni) {
        float s = acc[mi][ni][r] + bias;
        float v = 0.5f * s * (1.0f + erff(s * 0.70710678118654752f));
        Bs[(ni * 16 + hq) * 264 + o] = bfb(v);
      }
    }
  }
  __syncthreads();

  // column pass: thread t = channel o; pool 32 rows + vectorized store
  {
    const int o = t;
    float sm = 0.f, mx = -1e30f;
    unsigned pk[16];
#pragma unroll
    for (int m = 0; m < 16; ++m) {
      unsigned short r0 = Bs[(2 * m) * 264 + o];
      unsigned short r1 = Bs[(2 * m + 1) * 264 + o];
      float f0 = bf2f(r0), f1 = bf2f(r1);
      sm += f0 + f1;
      mx = fmaxf(mx, fmaxf(f0, f1));
      pk[m] = (unsigned)r0 | ((unsigned)r1 << 16);
    }
    unsigned short* hp = h_out + ((size_t)(b * 256 + o)) * HW + hw0;
#pragma unroll
    for (int q = 0; q < 4; ++q) {
      uint4 s4;
      s4.x = pk[q * 4 + 0]; s4.y = pk[q * 4 + 1]; s4.z = pk[q * 4 + 2]; s4.w = pk[q * 4 + 3];
      *(uint4*)(hp + q * 8) = s4;
    }
    atomicAdd(psum + b * 256 + o, sm);
    atomicMax(pmaxe + b * 256 + o, fenc(mx));
  }
}

// ---------------- K2: channel attention FCs (4-way c-split FC1) ----------------
__global__ __launch_bounds__(256) void k2_att(
    const float* __restrict__ psum, const unsigned* __restrict__ pmaxe,
    const float* __restrict__ fc1_w, const float* __restrict__ fc1_b,
    const float* __restrict__ fc2_w, const float* __restrict__ fc2_b,
    float* __restrict__ att)
{
  const int b = blockIdx.x, t = threadIdx.x;
  __shared__ float pA[4][64], pM[4][64];
  __shared__ float hA[64], hM[64];
  {
    const int j = t & 63, seg = t >> 6;
    const int base = b * 256 + seg * 64;
    const float* wrow = fc1_w + j * 256 + seg * 64;
    float sA = 0.f, sM = 0.f;
#pragma unroll 8
    for (int c = 0; c < 64; ++c) {
      float wv = wrow[c];
      sA += psum[base + c] * wv;
      sM += fdec(pmaxe[base + c]) * wv;
    }
    pA[seg][j] = sA;
    pM[seg][j] = sM;
  }
  __syncthreads();
  if (t < 64) {
    float a = fc1_b[t] + (pA[0][t] + pA[1][t] + pA[2][t] + pA[3][t]) * (1.f / 3136.f);
    float m = fc1_b[t] + (pM[0][t] + pM[1][t] + pM[2][t] + pM[3][t]);
    hA[t] = fmaxf(a, 0.f);
    hM[t] = fmaxf(m, 0.f);
  }
  __syncthreads();
  float s1 = fc2_b[t], s2 = s1;
#pragma unroll 8
  for (int j = 0; j < 64; ++j) {
    float wv = fc2_w[t * 64 + j];
    s1 += hA[j] * wv;
    s2 += hM[j] * wv;
  }
  att[b * 256 + t] = 1.f / (1.f + expf(-s1)) + 1.f / (1.f + expf(-s2));
}

// ---------------- K34 v12: fused depthwise chain, one plane per block ----------------
// LDS ~31.5KB -> 5 blocks/CU (20 waves, +25% vs v10's 4):
//   B0h bf16 [4480]: P0 halo h [60][60] (pure u16 copy, h already bf16);
//       after P1 barrier rewritten as x_init bf16 [56][80] (data cols 10..65, 16B rows)
//   T1/T2/T3 bf16 row-major; all bf16 LDS accessed as packed u32 (2 vals/op, shift/mask)
// P1/PB share column-pair task mapping (t<196): x_init fp32 lives in acc2[] registers.
__global__ __launch_bounds__(256) void k34_dw(
    const unsigned short* __restrict__ h_in, const float* __restrict__ att,
    const float* __restrict__ w5, const float* __restrict__ b5,
    const float* __restrict__ w1x7, const float* __restrict__ b1x7,
    const float* __restrict__ w7x1, const float* __restrict__ b7x1,
    const float* __restrict__ w1x11, const float* __restrict__ b1x11,
    const float* __restrict__ w11x1, const float* __restrict__ b11x1,
    const float* __restrict__ w1x21, const float* __restrict__ b1x21,
    const float* __restrict__ w21x1, const float* __restrict__ b21x1,
    unsigned short* __restrict__ xs_out)
{
  __shared__ __align__(16) unsigned short B0h[4480];
  __shared__ __align__(16) unsigned short T1[62 * 56];  // r = y+3
  __shared__ __align__(16) unsigned short T2[66 * 56];  // r = y+5
  __shared__ __align__(16) unsigned short T3[76 * 56];  // r = y+10
  __shared__ __align__(16) float wk5a[25];
  __shared__ __align__(16) float wk[78]; // [0,7)w1x7 [7,14)w7x1 [14,25)w1x11 [25,36)w11x1 [36,57)w1x21 [57,78)w21x1

  const int bid = blockIdx.x;
  const int b = bid >> 8, c = bid & 255;
  const int t = threadIdx.x;
  const size_t plane = (size_t)(b * 256 + c) * HW;
  const float a = att[b * 256 + c];

  if (t < 25) wk5a[t] = w5[c * 25 + t] * a;
  if (t >= 32 && t < 110) {
    int k = t - 32;
    float v;
    if (k < 7) v = w1x7[c * 7 + k];
    else if (k < 14) v = w7x1[c * 7 + k - 7];
    else if (k < 25) v = w1x11[c * 11 + k - 14];
    else if (k < 36) v = w11x1[c * 11 + k - 25];
    else if (k < 57) v = w1x21[c * 21 + k - 36];
    else v = w21x1[c * 21 + k - 57];
    wk[k] = v;
  }
  {
    unsigned* T1d = (unsigned*)T1; unsigned* T2d = (unsigned*)T2; unsigned* T3d = (unsigned*)T3;
    for (int i = t; i < 1008; i += 256) {
      if (i < 84) T1d[i] = 0;
      else if (i < 168) T1d[1652 + i - 84] = 0;
      else if (i < 308) T2d[i - 168] = 0;
      else if (i < 448) T2d[1708 + i - 308] = 0;
      else if (i < 728) T3d[i - 448] = 0;
      else T3d[1848 + i - 728] = 0;
    }
  }
  { // P0: stage halo'd h (bf16, rows/cols -2..57) into B0h[60][60] — pure copy, u32 pairs
    const unsigned short* hp = h_in + plane;
    unsigned* Bd = (unsigned*)B0h;
    for (int i = t; i < 1800; i += 256) {  // 30 u32 per row (60 u16)
      int ly = i / 30, e = i - ly * 30;
      int gy = ly - 2, lx0 = 2 * e - 2;
      unsigned val = 0;
      if ((unsigned)gy < 56u) {
        if (lx0 >= 0 && lx0 + 1 < 56) {
          val = *(const unsigned*)&hp[gy * 56 + lx0];
        } else {
          unsigned short aa = ((unsigned)lx0 < 56u) ? hp[gy * 56 + lx0] : (unsigned short)0;
          unsigned short bb = ((unsigned)(lx0 + 1) < 56u) ? hp[gy * 56 + lx0 + 1] : (unsigned short)0;
          val = (unsigned)aa | ((unsigned)bb << 16);
        }
      }
      Bd[i] = val;
    }
  }
  __syncthreads();

  // P1: dw5x5 -> registers (f32x2, column-pair task = PB's mapping). 196 active threads.
  // Halo reads: 3 packed u32 per row (6 bf16), shift/mask unpack.
  const int band = t / 28, xp = t - band * 28;
  const int py0 = band * 8, px0 = xp * 2;
  f32x2 acc2[8];
  {
    const float bias5 = b5[c];
#pragma unroll
    for (int d = 0; d < 8; ++d) { acc2[d].x = bias5; acc2[d].y = bias5; }
  }
  if (t < 196) {
    const unsigned* Bd = (const unsigned*)B0h;
#pragma unroll
    for (int r = 0; r < 12; ++r) {
      const unsigned base = (py0 + r) * 30 + (px0 >> 1);
      unsigned q0 = Bd[base], q1 = Bd[base + 1], q2 = Bd[base + 2];
      float row6[6];
      row6[0] = lo16f(q0); row6[1] = hi16f(q0);
      row6[2] = lo16f(q1); row6[3] = hi16f(q1);
      row6[4] = lo16f(q2); row6[5] = hi16f(q2);
      const int dlo = (r > 4) ? (r - 4) : 0;
      const int dhi = (r < 7) ? r : 7;
#pragma unroll
      for (int d = 0; d < 8; ++d) {
        if (d < dlo || d > dhi) continue;
        const int ky = r - d;
#pragma unroll
        for (int kx = 0; kx < 5; ++kx) {
          float wv = wk5a[ky * 5 + kx];
          f32x2 p; p.x = row6[kx]; p.y = row6[kx + 1];
          acc2[d] = acc2[d] + p * wv;
        }
      }
    }
  }
  __syncthreads();

  // P2: write x_init (bf16) to B0h [56][80] (data at col+10); zero col pads.
  if (t < 196) {
    unsigned* Bd = (unsigned*)B0h;
#pragma unroll
    for (int d = 0; d < 8; ++d)
      Bd[(py0 + d) * 40 + ((10 + px0) >> 1)] = pack2(acc2[d].x, acc2[d].y);
  }
  { // pads: u16 cols 0..9 (u32 0..4) and 66..79 (u32 33..39) per row
    unsigned* Bd = (unsigned*)B0h;
    for (int i = t; i < 672; i += 256) {
      int y = i / 12, j = i - y * 12;
      int u32col = (j < 5) ? j : (28 + j);
      Bd[y * 40 + u32col] = 0;
    }
  }
  __syncthreads();

  // PA: fused horizontal convs. ROW task (y, x0..x0+7). win = padded cols x0..x0+27
  // (= data cols x0-10..x0+17), read as 3 uint4 + 1 uint2, unpack 28 bf16.
  const float bb1 = b1x7[c], bb2 = b1x11[c], bb3 = b1x21[c];
#pragma unroll
  for (int rnd = 0; rnd < 2; ++rnd) {
    if (rnd == 1 && t >= 136) break;
    int tau = t + rnd * 256;
    int y = tau / 7, x0 = (tau - y * 7) * 8;
    const unsigned* wp = (const unsigned*)B0h + y * 40 + (x0 >> 1);
    uint4 qa = *(const uint4*)(wp);
    uint4 qb = *(const uint4*)(wp + 4);
    uint4 qc = *(const uint4*)(wp + 8);
    uint2 qd = *(const uint2*)(wp + 12);
    float win[28];
    win[0]  = lo16f(qa.x); win[1]  = hi16f(qa.x);
    win[2]  = lo16f(qa.y); win[3]  = hi16f(qa.y);
    win[4]  = lo16f(qa.z); win[5]  = hi16f(qa.z);
    win[6]  = lo16f(qa.w); win[7]  = hi16f(qa.w);
    win[8]  = lo16f(qb.x); win[9]  = hi16f(qb.x);
    win[10] = lo16f(qb.y); win[11] = hi16f(qb.y);
    win[12] = lo16f(qb.z); win[13] = hi16f(qb.z);
    win[14] = lo16f(qb.w); win[15] = hi16f(qb.w);
    win[16] = lo16f(qc.x); win[17] = hi16f(qc.x);
    win[18] = lo16f(qc.y); win[19] = hi16f(qc.y);
    win[20] = lo16f(qc.z); win[21] = hi16f(qc.z);
    win[22] = lo16f(qc.w); win[23] = hi16f(qc.w);
    win[24] = lo16f(qd.x); win[25] = hi16f(qd.x);
    win[26] = lo16f(qd.y); win[27] = hi16f(qd.y);
    float o1[8], o2[8], o3[8];
#pragma unroll
    for (int d = 0; d < 8; ++d) { o1[d] = bb1; o2[d] = bb2; o3[d] = bb3; }
#pragma unroll
    for (int k = 0; k < 7; ++k) {
      float wv = wk[k];
#pragma unroll
      for (int d = 0; d < 8; ++d) o1[d] += win[d + k + 7] * wv;
    }
#pragma unroll
    for (int k = 0; k < 11; ++k) {
      float wv = wk[14 + k];
#pragma unroll
      for (int d = 0; d < 8; ++d) o2[d] += win[d + k + 5] * wv;
    }
#pragma unroll
    for (int k = 0; k < 21; ++k) {
      float wv = wk[36 + k];
#pragma unroll
      for (int d = 0; d < 8; ++d) o3[d] += win[d + k] * wv;
    }
    uint4 s1, s2, s3;
    s1.x = pack2(o1[0], o1[1]); s1.y = pack2(o1[2], o1[3]); s1.z = pack2(o1[4], o1[5]); s1.w = pack2(o1[6], o1[7]);
    s2.x = pack2(o2[0], o2[1]); s2.y = pack2(o2[2], o2[3]); s2.z = pack2(o2[4], o2[5]); s2.w = pack2(o2[6], o2[7]);
    s3.x = pack2(o3[0], o3[1]); s3.y = pack2(o3[2], o3[3]); s3.z = pack2(o3[4], o3[5]); s3.w = pack2(o3[6], o3[7]);
    *(uint4*)&T1[(y + 3) * 56 + x0] = s1;
    *(uint4*)&T2[(y + 5) * 56 + x0] = s2;
    *(uint4*)&T3[(y + 10) * 56 + x0] = s3;
  }
  __syncthreads();

  // PB: fused vertical convs (f32x2) + x_init from registers -> global bf16 store.
  const float vb = b7x1[c] + b11x1[c] + b21x1[c];
  unsigned short* op = xs_out + plane;
  if (t < 196) {
    f32x2 r2[8];
#pragma unroll
    for (int d = 0; d < 8; ++d) r2[d] = acc2[d] + vb;
    {
      f32x2 c2[14];
#pragma unroll
      for (int j = 0; j < 14; ++j) {
        unsigned q = *(const unsigned*)&T1[(py0 + j) * 56 + px0];
        c2[j].x = lo16f(q);
        c2[j].y = hi16f(q);
      }
#pragma unroll
      for (int k = 0; k < 7; ++k) {
        float wv = wk[7 + k];
#pragma unroll
        for (int d = 0; d < 8; ++d) r2[d] = r2[d] + c2[d + k] * wv;
      }
    }
    {
      f32x2 c2[18];
#pragma unroll
      for (int j = 0; j < 18; ++j) {
        unsigned q = *(const unsigned*)&T2[(py0 + j) * 56 + px0];
        c2[j].x = lo16f(q);
        c2[j].y = hi16f(q);
      }
#pragma unroll
      for (int k = 0; k < 11; ++k) {
        float wv = wk[25 + k];
#pragma unroll
        for (int d = 0; d < 8; ++d) r2[d] = r2[d] + c2[d + k] * wv;
      }
    }
    {
      f32x2 c2[28];
#pragma unroll
      for (int j = 0; j < 28; ++j) {
        unsigned q = *(const unsigned*)&T3[(py0 + j) * 56 + px0];
        c2[j].x = lo16f(q);
        c2[j].y = hi16f(q);
      }
#pragma unroll
      for (int k = 0; k < 21; ++k) {
        float wv = wk[57 + k];
#pragma unroll
        for (int d = 0; d < 8; ++d) r2[d] = r2[d] + c2[d + k] * wv;
      }
    }
#pragma unroll
    for (int d = 0; d < 8; ++d)
      *(unsigned*)&op[(py0 + d) * 56 + px0] = pack2(r2[d].x, r2[d].y);
  }
}

// ---------------- K5: spatial_att = W*xs+b ; out = sa*(att*h) ; result = W*out+b ----------------
__global__ __launch_bounds__(256) void k5_final(
    const unsigned short* __restrict__ xs, const unsigned short* __restrict__ Wbf,
    const float* __restrict__ conv_b, const float* __restrict__ att,
    const unsigned short* __restrict__ h_in, float* __restrict__ outp)
{
  __shared__ __align__(16) unsigned short Bs[64 * 264];
  const int bid = blockIdx.x;
  const int b = bid / 49, tile = bid - 49 * (bid / 49);
  const int hw0 = tile * 64;
  const int t = threadIdx.x;

  { // stage xs (bf16) transposed into LDS, ushort8 (16B) loads
    int g = t & 127, half = t >> 7;
    const unsigned short* p0 = xs + ((size_t)(b * 256 + 2 * g)) * HW + hw0 + half * 32;
    const unsigned short* p1 = p0 + HW;
    unsigned* Bd = (unsigned*)Bs;
#pragma unroll
    for (int i = 0; i < 32; i += 8) {
      ushort8 a8 = *(const ushort8*)(p0 + i);
      ushort8 c8 = *(const ushort8*)(p1 + i);
      int hw = half * 32 + i;
#pragma unroll
      for (int e = 0; e < 8; ++e)
        Bd[(hw + e) * 132 + g] = (unsigned)a8[e] | ((unsigned)c8[e] << 16);
    }
  }
  __syncthreads();

  const int w = t >> 6, l = t & 63, hq = l & 15, g2 = l >> 4;
  const int wm0 = w * 64;
  const f32x4 vzero = {0.f, 0.f, 0.f, 0.f};
  f32x4 acc[4][4];
#pragma unroll
  for (int mi = 0; mi < 4; ++mi)
#pragma unroll
    for (int ni = 0; ni < 4; ++ni) acc[mi][ni] = vzero;

#pragma unroll
  for (int ks = 0; ks < 8; ++ks) {
    short8 a[4], bv[4];
#pragma unroll
    for (int mi = 0; mi < 4; ++mi)
      a[mi] = *(const short8*)(Wbf + (size_t)(wm0 + mi * 16 + hq) * 256 + ks * 32 + g2 * 8);
#pragma unroll
    for (int ni = 0; ni < 4; ++ni)
      bv[ni] = *(const short8*)(Bs + (ni * 16 + hq) * 264 + ks * 32 + g2 * 8);
#pragma unroll
    for (int mi = 0; mi < 4; ++mi)
#pragma unroll
      for (int ni = 0; ni < 4; ++ni)
        acc[mi][ni] = __builtin_amdgcn_mfma_f32_16x16x32_bf16(a[mi], bv[ni], acc[mi][ni], 0, 0, 0);
  }
  __syncthreads();

#pragma unroll
  for (int mi = 0; mi < 4; ++mi) {
#pragma unroll
    for (int r = 0; r < 4; ++r) {
      int o = wm0 + mi * 16 + g2 * 4 + r;
      float bias = conv_b[o];
      float av = att[b * 256 + o];
      const unsigned short* hp = h_in + ((size_t)(b * 256 + o)) * HW + hw0;
#pragma unroll
      for (int ni = 0; ni < 4; ++ni) {
        float sa = acc[mi][ni][r] + bias;
        float ov = sa * (av * bf2f(hp[ni * 16 + hq]));
        Bs[(ni * 16 + hq) * 264 + o] = bfb(ov);
      }
    }
  }
  __syncthreads();

  f32x4 acc2[4][4];
#pragma unroll
  for (int mi = 0; mi < 4; ++mi)
#pragma unroll
    for (int ni = 0; ni < 4; ++ni) acc2[mi][ni] = vzero;
#pragma unroll
  for (int ks = 0; ks < 8; ++ks) {
    short8 a[4], bv[4];
#pragma unroll
    for (int mi = 0; mi < 4; ++mi)
      a[mi] = *(const short8*)(Wbf + (size_t)(wm0 + mi * 16 + hq) * 256 + ks * 32 + g2 * 8);
#pragma unroll
    for (int ni = 0; ni < 4; ++ni)
      bv[ni] = *(const short8*)(Bs + (ni * 16 + hq) * 264 + ks * 32 + g2 * 8);
#pragma unroll
    for (int mi = 0; mi < 4; ++mi)
#pragma unroll
      for (int ni = 0; ni < 4; ++ni)
        acc2[mi][ni] = __builtin_amdgcn_mfma_f32_16x16x32_bf16(a[mi], bv[ni], acc2[mi][ni], 0, 0, 0);
  }

#pragma unroll
  for (int mi = 0; mi < 4; ++mi) {
#pragma unroll
    for (int r = 0; r < 4; ++r) {
      int o = wm0 + mi * 16 + g2 * 4 + r;
      float bias = conv_b[o];
      float* op = outp + ((size_t)(b * 256 + o)) * HW + hw0;
#pragma unroll
      for (int ni = 0; ni < 4; ++ni) op[ni * 16 + hq] = acc2[mi][ni][r] + bias;
    }
  }
}

extern "C" void kernel_launch(void* const* d_in, const int* in_sizes, int n_in,
                              void* d_out, int out_size, void* d_ws, size_t ws_size,
                              hipStream_t stream) {
  const float* x      = (const float*)d_in[0];
  const float* conv_w = (const float*)d_in[1];
  const float* conv_b = (const float*)d_in[2];
  const float* fc1_w  = (const float*)d_in[3];
  const float* fc1_b  = (const float*)d_in[4];
  const float* fc2_w  = (const float*)d_in[5];
  const float* fc2_b  = (const float*)d_in[6];
  const float* w5     = (const float*)d_in[7];
  const float* b5     = (const float*)d_in[8];
  const float* w1x7   = (const float*)d_in[9];
  const float* b1x7   = (const float*)d_in[10];
  const float* w7x1   = (const float*)d_in[11];
  const float* b7x1   = (const float*)d_in[12];
  const float* w1x11  = (const float*)d_in[13];
  const float* b1x11  = (const float*)d_in[14];
  const float* w11x1  = (const float*)d_in[15];
  const float* b11x1  = (const float*)d_in[16];
  const float* w1x21  = (const float*)d_in[17];
  const float* b1x21  = (const float*)d_in[18];
  const float* w21x1  = (const float*)d_in[19];
  const float* b21x1  = (const float*)d_in[20];
  float* out = (float*)d_out;

  char* ws = (char*)d_ws;
  unsigned short* Wbf = (unsigned short*)(ws);            // 131072 B
  float* psum   = (float*)(ws + 131072);                  // 16384 B
  unsigned* pme = (unsigned*)(ws + 147456);               // 16384 B
  float* attb   = (float*)(ws + 163840);                  // 16384 B
  unsigned short* hbuf = (unsigned short*)(ws + 180224);  // 25690112 B (h bf16)
  unsigned short* xbuf = (unsigned short*)(ws + 180224 + 25690112); // 25690112 B (xs bf16)

  k0_init<<<256, 256, 0, stream>>>(conv_w, Wbf, psum, pme);
  k1_conv_gelu_pool<<<1568, 256, 0, stream>>>(x, Wbf, conv_b, hbuf, psum, pme);
  k2_att<<<16, 256, 0, stream>>>(psum, pme, fc1_w, fc1_b, fc2_w, fc2_b, attb);
  k34_dw<<<4096, 256, 0, stream>>>(hbuf, attb, w5, b5, w1x7, b1x7, w7x1, b7x1,
                                   w1x11, b1x11, w11x1, b11x1, w1x21, b1x21,
                                   w21x1, b21x1, xbuf);
  k5_final<<<784, 256, 0, stream>>>(xbuf, Wbf, conv_b, attb, hbuf, out);
}

// Round 14
// 179.427 us; speedup vs baseline: 1.3926x; 1.0064x over previous
//
#include <hip/hip_runtime.h>
#include <hip/hip_bf16.h>

#define HW 3136
#define NB 16

typedef float f32x4 __attribute__((ext_vector_type(4)));
typedef float f32x2 __attribute__((ext_vector_type(2)));
typedef short short8 __attribute__((ext_vector_type(8)));
typedef unsigned short ushort8 __attribute__((ext_vector_type(8)));

__device__ inline unsigned short bfb(float f) {
  union { __hip_bfloat16 h; unsigned short u; } cv;
  cv.h = __float2bfloat16(f);
  return cv.u;
}
__device__ inline unsigned pack2(float lo, float hi) {
  return (unsigned)bfb(lo) | ((unsigned)bfb(hi) << 16);
}
// order-preserving float<->uint encode for atomicMax
__device__ inline unsigned fenc(float f) {
  unsigned u = __float_as_uint(f);
  return (u & 0x80000000u) ? ~u : (u | 0x80000000u);
}
__device__ inline float fdec(unsigned e) {
  return (e & 0x80000000u) ? __uint_as_float(e & 0x7FFFFFFFu) : __uint_as_float(~e);
}
__device__ inline float bf2f(unsigned short u) {
  return __uint_as_float((unsigned)u << 16);
}
__device__ inline float lo16f(unsigned q) { return __uint_as_float(q << 16); }
__device__ inline float hi16f(unsigned q) { return __uint_as_float(q & 0xffff0000u); }

// ---------------- K0: convert W to bf16, zero pool buffers ----------------
__global__ __launch_bounds__(256) void k0_init(const float* __restrict__ conv_w,
                                               unsigned short* __restrict__ Wbf,
                                               float* __restrict__ psum,
                                               unsigned* __restrict__ pmaxe) {
  int i = blockIdx.x * 256 + threadIdx.x;
  Wbf[i] = bfb(conv_w[i]);
  if (i < 4096) psum[i] = 0.f;
  else if (i < 8192) pmaxe[i - 4096] = 0u;
}

// ---------------- K1 v11: conv1x1 + bias + GELU -> h (bf16) ; fused channel pooling ----------------
__global__ __launch_bounds__(256) void k1_conv_gelu_pool(
    const float* __restrict__ x, const unsigned short* __restrict__ Wbf,
    const float* __restrict__ conv_b, unsigned short* __restrict__ h_out,
    float* __restrict__ psum, unsigned* __restrict__ pmaxe)
{
  __shared__ __align__(16) unsigned short Bs[32 * 264];
  const int bid = blockIdx.x;
  const int b = bid / 98, tile = bid - 98 * (bid / 98);
  const int hw0 = tile * 32;
  const int t = threadIdx.x;

  { // stage x[b, :, hw0..hw0+32) transposed bf16 into Bs[hw][c]
    int g = t & 127, half = t >> 7;
    const float* p0 = x + ((size_t)(b * 256 + 2 * g)) * HW + hw0 + half * 16;
    const float* p1 = p0 + HW;
    unsigned* Bd = (unsigned*)Bs;
#pragma unroll
    for (int i = 0; i < 16; i += 4) {
      float4 a4 = *(const float4*)(p0 + i);
      float4 c4 = *(const float4*)(p1 + i);
      int hw = half * 16 + i;
      Bd[(hw + 0) * 132 + g] = pack2(a4.x, c4.x);
      Bd[(hw + 1) * 132 + g] = pack2(a4.y, c4.y);
      Bd[(hw + 2) * 132 + g] = pack2(a4.z, c4.z);
      Bd[(hw + 3) * 132 + g] = pack2(a4.w, c4.w);
    }
  }
  __syncthreads();

  const int w = t >> 6, l = t & 63, hq = l & 15, g2 = l >> 4;
  const int wm0 = w * 64;
  const f32x4 vzero = {0.f, 0.f, 0.f, 0.f};
  f32x4 acc[4][2];
#pragma unroll
  for (int mi = 0; mi < 4; ++mi)
#pragma unroll
    for (int ni = 0; ni < 2; ++ni) acc[mi][ni] = vzero;

#pragma unroll
  for (int ks = 0; ks < 8; ++ks) {
    short8 a[4], bv[2];
#pragma unroll
    for (int mi = 0; mi < 4; ++mi)
      a[mi] = *(const short8*)(Wbf + (size_t)(wm0 + mi * 16 + hq) * 256 + ks * 32 + g2 * 8);
#pragma unroll
    for (int ni = 0; ni < 2; ++ni)
      bv[ni] = *(const short8*)(Bs + (ni * 16 + hq) * 264 + ks * 32 + g2 * 8);
#pragma unroll
    for (int mi = 0; mi < 4; ++mi)
#pragma unroll
      for (int ni = 0; ni < 2; ++ni)
        acc[mi][ni] = __builtin_amdgcn_mfma_f32_16x16x32_bf16(a[mi], bv[ni], acc[mi][ni], 0, 0, 0);
  }
  __syncthreads();  // all waves done reading Bs before overwrite

  // fragment phase: bias + exact GELU -> bf16 into Bs[hw][o]
#pragma unroll
  for (int mi = 0; mi < 4; ++mi) {
#pragma unroll
    for (int r = 0; r < 4; ++r) {
      int o = wm0 + mi * 16 + g2 * 4 + r;
      float bias = conv_b[o];
#pragma unroll
      for (int ni = 0; ni < 2; ++ni) {
        float s = acc[mi][ni][r] + bias;
        float v = 0.5f * s * (1.0f + erff(s * 0.70710678118654752f));
        Bs[(ni * 16 + hq) * 264 + o] = bfb(v);
      }
    }
  }
  __syncthreads();

  // column pass: thread t = channel o; pool 32 rows + vectorized store
  {
    const int o = t;
    float sm = 0.f, mx = -1e30f;
    unsigned pk[16];
#pragma unroll
    for (int m = 0; m < 16; ++m) {
      unsigned short r0 = Bs[(2 * m) * 264 + o];
      unsigned short r1 = Bs[(2 * m + 1) * 264 + o];
      float f0 = bf2f(r0), f1 = bf2f(r1);
      sm += f0 + f1;
      mx = fmaxf(mx, fmaxf(f0, f1));
      pk[m] = (unsigned)r0 | ((unsigned)r1 << 16);
    }
    unsigned short* hp = h_out + ((size_t)(b * 256 + o)) * HW + hw0;
#pragma unroll
    for (int q = 0; q < 4; ++q) {
      uint4 s4;
      s4.x = pk[q * 4 + 0]; s4.y = pk[q * 4 + 1]; s4.z = pk[q * 4 + 2]; s4.w = pk[q * 4 + 3];
      *(uint4*)(hp + q * 8) = s4;
    }
    atomicAdd(psum + b * 256 + o, sm);
    atomicMax(pmaxe + b * 256 + o, fenc(mx));
  }
}

// ---------------- K2: channel attention FCs (4-way c-split FC1) ----------------
__global__ __launch_bounds__(256) void k2_att(
    const float* __restrict__ psum, const unsigned* __restrict__ pmaxe,
    const float* __restrict__ fc1_w, const float* __restrict__ fc1_b,
    const float* __restrict__ fc2_w, const float* __restrict__ fc2_b,
    float* __restrict__ att)
{
  const int b = blockIdx.x, t = threadIdx.x;
  __shared__ float pA[4][64], pM[4][64];
  __shared__ float hA[64], hM[64];
  {
    const int j = t & 63, seg = t >> 6;
    const int base = b * 256 + seg * 64;
    const float* wrow = fc1_w + j * 256 + seg * 64;
    float sA = 0.f, sM = 0.f;
#pragma unroll 8
    for (int c = 0; c < 64; ++c) {
      float wv = wrow[c];
      sA += psum[base + c] * wv;
      sM += fdec(pmaxe[base + c]) * wv;
    }
    pA[seg][j] = sA;
    pM[seg][j] = sM;
  }
  __syncthreads();
  if (t < 64) {
    float a = fc1_b[t] + (pA[0][t] + pA[1][t] + pA[2][t] + pA[3][t]) * (1.f / 3136.f);
    float m = fc1_b[t] + (pM[0][t] + pM[1][t] + pM[2][t] + pM[3][t]);
    hA[t] = fmaxf(a, 0.f);
    hM[t] = fmaxf(m, 0.f);
  }
  __syncthreads();
  float s1 = fc2_b[t], s2 = s1;
#pragma unroll 8
  for (int j = 0; j < 64; ++j) {
    float wv = fc2_w[t * 64 + j];
    s1 += hA[j] * wv;
    s2 += hM[j] * wv;
  }
  att[b * 256 + t] = 1.f / (1.f + expf(-s1)) + 1.f / (1.f + expf(-s2));
}

// ---------------- K34 v13: fused depthwise chain, one plane per block ----------------
// LDS ~31.5KB (5 blocks/CU). P1/P2/PB use 4-row x 4-col tasks (196 = 14 bands x 14 quads):
//  - P1: 3x ds_read_b64 per halo row (24 issues, was 36 b32), rolling immediate consume
//  - PB: one ds_read_b64 per T row (4 bf16 = both col-pairs; 48 issues, was 60 b32),
//        immediate consume -> no big window arrays (low VGPR)
//  - x_init fp32 lives in aL/aH registers from P1 to PB
// PA/P0/pads identical to v12. FMA totals unchanged (P1 200 pk, PB 312 pk per task).
__global__ __launch_bounds__(256) void k34_dw(
    const unsigned short* __restrict__ h_in, const float* __restrict__ att,
    const float* __restrict__ w5, const float* __restrict__ b5,
    const float* __restrict__ w1x7, const float* __restrict__ b1x7,
    const float* __restrict__ w7x1, const float* __restrict__ b7x1,
    const float* __restrict__ w1x11, const float* __restrict__ b1x11,
    const float* __restrict__ w11x1, const float* __restrict__ b11x1,
    const float* __restrict__ w1x21, const float* __restrict__ b1x21,
    const float* __restrict__ w21x1, const float* __restrict__ b21x1,
    unsigned short* __restrict__ xs_out)
{
  __shared__ __align__(16) unsigned short B0h[4480];
  __shared__ __align__(16) unsigned short T1[62 * 56];  // r = y+3
  __shared__ __align__(16) unsigned short T2[66 * 56];  // r = y+5
  __shared__ __align__(16) unsigned short T3[76 * 56];  // r = y+10
  __shared__ __align__(16) float wk5a[25];
  __shared__ __align__(16) float wk[78]; // [0,7)w1x7 [7,14)w7x1 [14,25)w1x11 [25,36)w11x1 [36,57)w1x21 [57,78)w21x1

  const int bid = blockIdx.x;
  const int b = bid >> 8, c = bid & 255;
  const int t = threadIdx.x;
  const size_t plane = (size_t)(b * 256 + c) * HW;
  const float a = att[b * 256 + c];

  if (t < 25) wk5a[t] = w5[c * 25 + t] * a;
  if (t >= 32 && t < 110) {
    int k = t - 32;
    float v;
    if (k < 7) v = w1x7[c * 7 + k];
    else if (k < 14) v = w7x1[c * 7 + k - 7];
    else if (k < 25) v = w1x11[c * 11 + k - 14];
    else if (k < 36) v = w11x1[c * 11 + k - 25];
    else if (k < 57) v = w1x21[c * 21 + k - 36];
    else v = w21x1[c * 21 + k - 57];
    wk[k] = v;
  }
  {
    unsigned* T1d = (unsigned*)T1; unsigned* T2d = (unsigned*)T2; unsigned* T3d = (unsigned*)T3;
    for (int i = t; i < 1008; i += 256) {
      if (i < 84) T1d[i] = 0;
      else if (i < 168) T1d[1652 + i - 84] = 0;
      else if (i < 308) T2d[i - 168] = 0;
      else if (i < 448) T2d[1708 + i - 308] = 0;
      else if (i < 728) T3d[i - 448] = 0;
      else T3d[1848 + i - 728] = 0;
    }
  }
  { // P0: stage halo'd h (bf16, rows/cols -2..57) into B0h[60][60] — pure copy, u32 pairs
    const unsigned short* hp = h_in + plane;
    unsigned* Bd = (unsigned*)B0h;
    for (int i = t; i < 1800; i += 256) {  // 30 u32 per row (60 u16)
      int ly = i / 30, e = i - ly * 30;
      int gy = ly - 2, lx0 = 2 * e - 2;
      unsigned val = 0;
      if ((unsigned)gy < 56u) {
        if (lx0 >= 0 && lx0 + 1 < 56) {
          val = *(const unsigned*)&hp[gy * 56 + lx0];
        } else {
          unsigned short aa = ((unsigned)lx0 < 56u) ? hp[gy * 56 + lx0] : (unsigned short)0;
          unsigned short bb = ((unsigned)(lx0 + 1) < 56u) ? hp[gy * 56 + lx0 + 1] : (unsigned short)0;
          val = (unsigned)aa | ((unsigned)bb << 16);
        }
      }
      Bd[i] = val;
    }
  }
  __syncthreads();

  // P1: dw5x5 -> registers. 4x4 task: band=t/14 (y0=4*band), quad=t%14 (x0=4*quad).
  // Output (y0+d, x0+e): halo rows y0+d..y0+d+4, halo cols x0+e..x0+e+4.
  // Per halo row r (0..7): win[i] = halo[y0+r][x0+i], i 0..9 (read 12 via 3 b64, use 0..7+kx).
  const int band = t / 14, quad = t - band * 14;
  const int y0 = band * 4, x0 = quad * 4;
  f32x2 aL[4], aH[4];
  {
    const float bias5 = b5[c];
#pragma unroll
    for (int d = 0; d < 4; ++d) {
      aL[d].x = bias5; aL[d].y = bias5;
      aH[d].x = bias5; aH[d].y = bias5;
    }
  }
  if (t < 196) {
    const unsigned* Bd = (const unsigned*)B0h;
#pragma unroll
    for (int r = 0; r < 8; ++r) {
      const int base = (y0 + r) * 30 + 2 * quad;   // u32 col = x0/2 = 2*quad (8B-aligned)
      uint2 qa = *(const uint2*)(Bd + base);
      uint2 qb = *(const uint2*)(Bd + base + 2);
      uint2 qc = *(const uint2*)(Bd + base + 4);
      float win[10];
      win[0] = lo16f(qa.x); win[1] = hi16f(qa.x);
      win[2] = lo16f(qa.y); win[3] = hi16f(qa.y);
      win[4] = lo16f(qb.x); win[5] = hi16f(qb.x);
      win[6] = lo16f(qb.y); win[7] = hi16f(qb.y);
      win[8] = lo16f(qc.x); win[9] = hi16f(qc.x);
#pragma unroll
      for (int d = 0; d < 4; ++d) {
        const int ky = r - d;
        if (ky < 0 || ky > 4) continue;
#pragma unroll
        for (int kx = 0; kx < 5; ++kx) {
          float wv = wk5a[ky * 5 + kx];
          f32x2 pL; pL.x = win[kx];     pL.y = win[kx + 1];
          f32x2 pH; pH.x = win[kx + 2]; pH.y = win[kx + 3];
          aL[d] = aL[d] + pL * wv;
          aH[d] = aH[d] + pH * wv;
        }
      }
    }
  }
  __syncthreads();

  // P2: write x_init (bf16) to B0h overlay [56][80] (data at u16 col+10); zero col pads.
  if (t < 196) {
    unsigned* Bd = (unsigned*)B0h;
#pragma unroll
    for (int d = 0; d < 4; ++d) {
      Bd[(y0 + d) * 40 + 5 + 2 * quad]     = pack2(aL[d].x, aL[d].y);  // u16 cols 10+x0, 11+x0
      Bd[(y0 + d) * 40 + 6 + 2 * quad]     = pack2(aH[d].x, aH[d].y);  // u16 cols 12+x0, 13+x0
    }
  }
  { // pads: u16 cols 0..9 (u32 0..4) and 66..79 (u32 33..39) per row
    unsigned* Bd = (unsigned*)B0h;
    for (int i = t; i < 672; i += 256) {
      int y = i / 12, j = i - y * 12;
      int u32col = (j < 5) ? j : (28 + j);
      Bd[y * 40 + u32col] = 0;
    }
  }
  __syncthreads();

  // PA: fused horizontal convs (unchanged from v12). ROW task (y, xa0..xa0+7).
  const float bb1 = b1x7[c], bb2 = b1x11[c], bb3 = b1x21[c];
#pragma unroll
  for (int rnd = 0; rnd < 2; ++rnd) {
    if (rnd == 1 && t >= 136) break;
    int tau = t + rnd * 256;
    int y = tau / 7, xa0 = (tau - y * 7) * 8;
    const unsigned* wp = (const unsigned*)B0h + y * 40 + (xa0 >> 1);
    uint4 qa = *(const uint4*)(wp);
    uint4 qb = *(const uint4*)(wp + 4);
    uint4 qc = *(const uint4*)(wp + 8);
    uint2 qd = *(const uint2*)(wp + 12);
    float win[28];
    win[0]  = lo16f(qa.x); win[1]  = hi16f(qa.x);
    win[2]  = lo16f(qa.y); win[3]  = hi16f(qa.y);
    win[4]  = lo16f(qa.z); win[5]  = hi16f(qa.z);
    win[6]  = lo16f(qa.w); win[7]  = hi16f(qa.w);
    win[8]  = lo16f(qb.x); win[9]  = hi16f(qb.x);
    win[10] = lo16f(qb.y); win[11] = hi16f(qb.y);
    win[12] = lo16f(qb.z); win[13] = hi16f(qb.z);
    win[14] = lo16f(qb.w); win[15] = hi16f(qb.w);
    win[16] = lo16f(qc.x); win[17] = hi16f(qc.x);
    win[18] = lo16f(qc.y); win[19] = hi16f(qc.y);
    win[20] = lo16f(qc.z); win[21] = hi16f(qc.z);
    win[22] = lo16f(qc.w); win[23] = hi16f(qc.w);
    win[24] = lo16f(qd.x); win[25] = hi16f(qd.x);
    win[26] = lo16f(qd.y); win[27] = hi16f(qd.y);
    float o1[8], o2[8], o3[8];
#pragma unroll
    for (int d = 0; d < 8; ++d) { o1[d] = bb1; o2[d] = bb2; o3[d] = bb3; }
#pragma unroll
    for (int k = 0; k < 7; ++k) {
      float wv = wk[k];
#pragma unroll
      for (int d = 0; d < 8; ++d) o1[d] += win[d + k + 7] * wv;
    }
#pragma unroll
    for (int k = 0; k < 11; ++k) {
      float wv = wk[14 + k];
#pragma unroll
      for (int d = 0; d < 8; ++d) o2[d] += win[d + k + 5] * wv;
    }
#pragma unroll
    for (int k = 0; k < 21; ++k) {
      float wv = wk[36 + k];
#pragma unroll
      for (int d = 0; d < 8; ++d) o3[d] += win[d + k] * wv;
    }
    uint4 s1, s2, s3;
    s1.x = pack2(o1[0], o1[1]); s1.y = pack2(o1[2], o1[3]); s1.z = pack2(o1[4], o1[5]); s1.w = pack2(o1[6], o1[7]);
    s2.x = pack2(o2[0], o2[1]); s2.y = pack2(o2[2], o2[3]); s2.z = pack2(o2[4], o2[5]); s2.w = pack2(o2[6], o2[7]);
    s3.x = pack2(o3[0], o3[1]); s3.y = pack2(o3[2], o3[3]); s3.z = pack2(o3[4], o3[5]); s3.w = pack2(o3[6], o3[7]);
    *(uint4*)&T1[(y + 3) * 56 + xa0] = s1;
    *(uint4*)&T2[(y + 5) * 56 + xa0] = s2;
    *(uint4*)&T3[(y + 10) * 56 + xa0] = s3;
  }
  __syncthreads();

  // PB: fused vertical convs, 4x4 task. One b64 per T row (both col-pairs), immediate consume.
  // out[y0+d] += sum_k T[(y0+d+k)] * w[k]  ->  iterate T row j = d+k.
  const float vb = b7x1[c] + b11x1[c] + b21x1[c];
  unsigned short* op = xs_out + plane;
  if (t < 196) {
    f32x2 rL[4], rH[4];
#pragma unroll
    for (int d = 0; d < 4; ++d) { rL[d] = aL[d] + vb; rH[d] = aH[d] + vb; }
    {
      const unsigned* T1d = (const unsigned*)T1;
#pragma unroll
      for (int j = 0; j < 10; ++j) {
        uint2 q = *(const uint2*)(T1d + (y0 + j) * 28 + 2 * quad);
        f32x2 cL; cL.x = lo16f(q.x); cL.y = hi16f(q.x);
        f32x2 cH; cH.x = lo16f(q.y); cH.y = hi16f(q.y);
#pragma unroll
        for (int d = 0; d < 4; ++d) {
          const int k = j - d;
          if (k < 0 || k > 6) continue;
          float wv = wk[7 + k];
          rL[d] = rL[d] + cL * wv;
          rH[d] = rH[d] + cH * wv;
        }
      }
    }
    {
      const unsigned* T2d = (const unsigned*)T2;
#pragma unroll
      for (int j = 0; j < 14; ++j) {
        uint2 q = *(const uint2*)(T2d + (y0 + j) * 28 + 2 * quad);
        f32x2 cL; cL.x = lo16f(q.x); cL.y = hi16f(q.x);
        f32x2 cH; cH.x = lo16f(q.y); cH.y = hi16f(q.y);
#pragma unroll
        for (int d = 0; d < 4; ++d) {
          const int k = j - d;
          if (k < 0 || k > 10) continue;
          float wv = wk[25 + k];
          rL[d] = rL[d] + cL * wv;
          rH[d] = rH[d] + cH * wv;
        }
      }
    }
    {
      const unsigned* T3d = (const unsigned*)T3;
#pragma unroll
      for (int j = 0; j < 24; ++j) {
        uint2 q = *(const uint2*)(T3d + (y0 + j) * 28 + 2 * quad);
        f32x2 cL; cL.x = lo16f(q.x); cL.y = hi16f(q.x);
        f32x2 cH; cH.x = lo16f(q.y); cH.y = hi16f(q.y);
#pragma unroll
        for (int d = 0; d < 4; ++d) {
          const int k = j - d;
          if (k < 0 || k > 20) continue;
          float wv = wk[57 + k];
          rL[d] = rL[d] + cL * wv;
          rH[d] = rH[d] + cH * wv;
        }
      }
    }
#pragma unroll
    for (int d = 0; d < 4; ++d) {
      uint2 s;
      s.x = pack2(rL[d].x, rL[d].y);
      s.y = pack2(rH[d].x, rH[d].y);
      *(uint2*)&op[(y0 + d) * 56 + x0] = s;
    }
  }
}

// ---------------- K5: spatial_att = W*xs+b ; out = sa*(att*h) ; result = W*out+b ----------------
__global__ __launch_bounds__(256) void k5_final(
    const unsigned short* __restrict__ xs, const unsigned short* __restrict__ Wbf,
    const float* __restrict__ conv_b, const float* __restrict__ att,
    const unsigned short* __restrict__ h_in, float* __restrict__ outp)
{
  __shared__ __align__(16) unsigned short Bs[64 * 264];
  const int bid = blockIdx.x;
  const int b = bid / 49, tile = bid - 49 * (bid / 49);
  const int hw0 = tile * 64;
  const int t = threadIdx.x;

  { // stage xs (bf16) transposed into LDS, ushort8 (16B) loads
    int g = t & 127, half = t >> 7;
    const unsigned short* p0 = xs + ((size_t)(b * 256 + 2 * g)) * HW + hw0 + half * 32;
    const unsigned short* p1 = p0 + HW;
    unsigned* Bd = (unsigned*)Bs;
#pragma unroll
    for (int i = 0; i < 32; i += 8) {
      ushort8 a8 = *(const ushort8*)(p0 + i);
      ushort8 c8 = *(const ushort8*)(p1 + i);
      int hw = half * 32 + i;
#pragma unroll
      for (int e = 0; e < 8; ++e)
        Bd[(hw + e) * 132 + g] = (unsigned)a8[e] | ((unsigned)c8[e] << 16);
    }
  }
  __syncthreads();

  const int w = t >> 6, l = t & 63, hq = l & 15, g2 = l >> 4;
  const int wm0 = w * 64;
  const f32x4 vzero = {0.f, 0.f, 0.f, 0.f};
  f32x4 acc[4][4];
#pragma unroll
  for (int mi = 0; mi < 4; ++mi)
#pragma unroll
    for (int ni = 0; ni < 4; ++ni) acc[mi][ni] = vzero;

#pragma unroll
  for (int ks = 0; ks < 8; ++ks) {
    short8 a[4], bv[4];
#pragma unroll
    for (int mi = 0; mi < 4; ++mi)
      a[mi] = *(const short8*)(Wbf + (size_t)(wm0 + mi * 16 + hq) * 256 + ks * 32 + g2 * 8);
#pragma unroll
    for (int ni = 0; ni < 4; ++ni)
      bv[ni] = *(const short8*)(Bs + (ni * 16 + hq) * 264 + ks * 32 + g2 * 8);
#pragma unroll
    for (int mi = 0; mi < 4; ++mi)
#pragma unroll
      for (int ni = 0; ni < 4; ++ni)
        acc[mi][ni] = __builtin_amdgcn_mfma_f32_16x16x32_bf16(a[mi], bv[ni], acc[mi][ni], 0, 0, 0);
  }
  __syncthreads();

#pragma unroll
  for (int mi = 0; mi < 4; ++mi) {
#pragma unroll
    for (int r = 0; r < 4; ++r) {
      int o = wm0 + mi * 16 + g2 * 4 + r;
      float bias = conv_b[o];
      float av = att[b * 256 + o];
      const unsigned short* hp = h_in + ((size_t)(b * 256 + o)) * HW + hw0;
#pragma unroll
      for (int ni = 0; ni < 4; ++ni) {
        float sa = acc[mi][ni][r] + bias;
        float ov = sa * (av * bf2f(hp[ni * 16 + hq]));
        Bs[(ni * 16 + hq) * 264 + o] = bfb(ov);
      }
    }
  }
  __syncthreads();

  f32x4 acc2[4][4];
#pragma unroll
  for (int mi = 0; mi < 4; ++mi)
#pragma unroll
    for (int ni = 0; ni < 4; ++ni) acc2[mi][ni] = vzero;
#pragma unroll
  for (int ks = 0; ks < 8; ++ks) {
    short8 a[4], bv[4];
#pragma unroll
    for (int mi = 0; mi < 4; ++mi)
      a[mi] = *(const short8*)(Wbf + (size_t)(wm0 + mi * 16 + hq) * 256 + ks * 32 + g2 * 8);
#pragma unroll
    for (int ni = 0; ni < 4; ++ni)
      bv[ni] = *(const short8*)(Bs + (ni * 16 + hq) * 264 + ks * 32 + g2 * 8);
#pragma unroll
    for (int mi = 0; mi < 4; ++mi)
#pragma unroll
      for (int ni = 0; ni < 4; ++ni)
        acc2[mi][ni] = __builtin_amdgcn_mfma_f32_16x16x32_bf16(a[mi], bv[ni], acc2[mi][ni], 0, 0, 0);
  }

#pragma unroll
  for (int mi = 0; mi < 4; ++mi) {
#pragma unroll
    for (int r = 0; r < 4; ++r) {
      int o = wm0 + mi * 16 + g2 * 4 + r;
      float bias = conv_b[o];
      float* op = outp + ((size_t)(b * 256 + o)) * HW + hw0;
#pragma unroll
      for (int ni = 0; ni < 4; ++ni) op[ni * 16 + hq] = acc2[mi][ni][r] + bias;
    }
  }
}

extern "C" void kernel_launch(void* const* d_in, const int* in_sizes, int n_in,
                              void* d_out, int out_size, void* d_ws, size_t ws_size,
                              hipStream_t stream) {
  const float* x      = (const float*)d_in[0];
  const float* conv_w = (const float*)d_in[1];
  const float* conv_b = (const float*)d_in[2];
  const float* fc1_w  = (const float*)d_in[3];
  const float* fc1_b  = (const float*)d_in[4];
  const float* fc2_w  = (const float*)d_in[5];
  const float* fc2_b  = (const float*)d_in[6];
  const float* w5     = (const float*)d_in[7];
  const float* b5     = (const float*)d_in[8];
  const float* w1x7   = (const float*)d_in[9];
  const float* b1x7   = (const float*)d_in[10];
  const float* w7x1   = (const float*)d_in[11];
  const float* b7x1   = (const float*)d_in[12];
  const float* w1x11  = (const float*)d_in[13];
  const float* b1x11  = (const float*)d_in[14];
  const float* w11x1  = (const float*)d_in[15];
  const float* b11x1  = (const float*)d_in[16];
  const float* w1x21  = (const float*)d_in[17];
  const float* b1x21  = (const float*)d_in[18];
  const float* w21x1  = (const float*)d_in[19];
  const float* b21x1  = (const float*)d_in[20];
  float* out = (float*)d_out;

  char* ws = (char*)d_ws;
  unsigned short* Wbf = (unsigned short*)(ws);            // 131072 B
  float* psum   = (float*)(ws + 131072);                  // 16384 B
  unsigned* pme = (unsigned*)(ws + 147456);               // 16384 B
  float* attb   = (float*)(ws + 163840);                  // 16384 B
  unsigned short* hbuf = (unsigned short*)(ws + 180224);  // 25690112 B (h bf16)
  unsigned short* xbuf = (unsigned short*)(ws + 180224 + 25690112); // 25690112 B (xs bf16)

  k0_init<<<256, 256, 0, stream>>>(conv_w, Wbf, psum, pme);
  k1_conv_gelu_pool<<<1568, 256, 0, stream>>>(x, Wbf, conv_b, hbuf, psum, pme);
  k2_att<<<16, 256, 0, stream>>>(psum, pme, fc1_w, fc1_b, fc2_w, fc2_b, attb);
  k34_dw<<<4096, 256, 0, stream>>>(hbuf, attb, w5, b5, w1x7, b1x7, w7x1, b7x1,
                                   w1x11, b1x11, w11x1, b11x1, w1x21, b1x21,
                                   w21x1, b21x1, xbuf);
  k5_final<<<784, 256, 0, stream>>>(xbuf, Wbf, conv_b, attb, hbuf, out);
}

// Round 15
// 177.747 us; speedup vs baseline: 1.4058x; 1.0095x over previous
//
#include <hip/hip_runtime.h>
#include <hip/hip_bf16.h>

#define HW 3136
#define NB 16

typedef float f32x4 __attribute__((ext_vector_type(4)));
typedef float f32x2 __attribute__((ext_vector_type(2)));
typedef short short8 __attribute__((ext_vector_type(8)));
typedef unsigned short ushort8 __attribute__((ext_vector_type(8)));

__device__ inline unsigned short bfb(float f) {
  union { __hip_bfloat16 h; unsigned short u; } cv;
  cv.h = __float2bfloat16(f);
  return cv.u;
}
__device__ inline unsigned pack2(float lo, float hi) {
  return (unsigned)bfb(lo) | ((unsigned)bfb(hi) << 16);
}
// order-preserving float<->uint encode for atomicMax
__device__ inline unsigned fenc(float f) {
  unsigned u = __float_as_uint(f);
  return (u & 0x80000000u) ? ~u : (u | 0x80000000u);
}
__device__ inline float fdec(unsigned e) {
  return (e & 0x80000000u) ? __uint_as_float(e & 0x7FFFFFFFu) : __uint_as_float(~e);
}
__device__ inline float bf2f(unsigned short u) {
  return __uint_as_float((unsigned)u << 16);
}
__device__ inline float lo16f(unsigned q) { return __uint_as_float(q << 16); }
__device__ inline float hi16f(unsigned q) { return __uint_as_float(q & 0xffff0000u); }

// ---------------- K0: convert W to bf16, zero pool buffers ----------------
__global__ __launch_bounds__(256) void k0_init(const float* __restrict__ conv_w,
                                               unsigned short* __restrict__ Wbf,
                                               float* __restrict__ psum,
                                               unsigned* __restrict__ pmaxe) {
  int i = blockIdx.x * 256 + threadIdx.x;
  Wbf[i] = bfb(conv_w[i]);
  if (i < 4096) psum[i] = 0.f;
  else if (i < 8192) pmaxe[i - 4096] = 0u;
}

// ---------------- K1 v14: conv1x1 + bias + GELU -> h (bf16) ; fused channel pooling ----------------
// Two-pass staging kills the global-read scatter:
//   pass1: COALESCED reads (8 lanes x float4 = 128B per channel row) -> bf16 row-major
//          Xs[256][38] u16 (dword stride 19: pass1 u32 writes bank-free)
//   pass2: LDS transpose Xs[c][hw] -> Bs[hw][c] via u32 pair reads + bit shuffles
// LDS = 19456(Xs) + 16896(Bs) = 36352B -> 4 blocks/CU. MFMA/epilogue unchanged.
__global__ __launch_bounds__(256) void k1_conv_gelu_pool(
    const float* __restrict__ x, const unsigned short* __restrict__ Wbf,
    const float* __restrict__ conv_b, unsigned short* __restrict__ h_out,
    float* __restrict__ psum, unsigned* __restrict__ pmaxe)
{
  __shared__ __align__(16) unsigned short Xs[256 * 38];
  __shared__ __align__(16) unsigned short Bs[32 * 264];
  const int bid = blockIdx.x;
  const int b = bid / 98, tile = bid - 98 * (bid / 98);
  const int hw0 = tile * 32;
  const int t = threadIdx.x;

  { // pass 1: coalesced global read -> bf16 row-major Xs
    unsigned* Xd = (unsigned*)Xs;
#pragma unroll
    for (int r = 0; r < 8; ++r) {
      int task = t + 256 * r;
      int c = task >> 3, e = task & 7;
      float4 q = *(const float4*)(x + ((size_t)(b * 256 + c)) * HW + hw0 + 4 * e);
      Xd[19 * c + 2 * e]     = pack2(q.x, q.y);
      Xd[19 * c + 2 * e + 1] = pack2(q.z, q.w);
    }
  }
  __syncthreads();

  { // pass 2: LDS transpose -> Bs[hw][c] (dword g holds channels 2g,2g+1)
    const unsigned* Xd = (const unsigned*)Xs;
    unsigned* Bd = (unsigned*)Bs;
    int g = t & 127, half = t >> 7;
#pragma unroll
    for (int i = 0; i < 8; ++i) {
      int hp = half * 8 + i;                   // hw pair: hw = 2hp, 2hp+1
      unsigned qa = Xd[38 * g + hp];           // channel 2g
      unsigned qb = Xd[38 * g + 19 + hp];      // channel 2g+1
      Bd[(2 * hp) * 132 + g]     = (qa & 0xFFFFu) | (qb << 16);
      Bd[(2 * hp + 1) * 132 + g] = (qa >> 16) | (qb & 0xFFFF0000u);
    }
  }
  __syncthreads();

  const int w = t >> 6, l = t & 63, hq = l & 15, g2 = l >> 4;
  const int wm0 = w * 64;
  const f32x4 vzero = {0.f, 0.f, 0.f, 0.f};
  f32x4 acc[4][2];
#pragma unroll
  for (int mi = 0; mi < 4; ++mi)
#pragma unroll
    for (int ni = 0; ni < 2; ++ni) acc[mi][ni] = vzero;

#pragma unroll
  for (int ks = 0; ks < 8; ++ks) {
    short8 a[4], bv[2];
#pragma unroll
    for (int mi = 0; mi < 4; ++mi)
      a[mi] = *(const short8*)(Wbf + (size_t)(wm0 + mi * 16 + hq) * 256 + ks * 32 + g2 * 8);
#pragma unroll
    for (int ni = 0; ni < 2; ++ni)
      bv[ni] = *(const short8*)(Bs + (ni * 16 + hq) * 264 + ks * 32 + g2 * 8);
#pragma unroll
    for (int mi = 0; mi < 4; ++mi)
#pragma unroll
      for (int ni = 0; ni < 2; ++ni)
        acc[mi][ni] = __builtin_amdgcn_mfma_f32_16x16x32_bf16(a[mi], bv[ni], acc[mi][ni], 0, 0, 0);
  }
  __syncthreads();  // all waves done reading Bs before overwrite

  // fragment phase: bias + exact GELU -> bf16 into Bs[hw][o]
#pragma unroll
  for (int mi = 0; mi < 4; ++mi) {
#pragma unroll
    for (int r = 0; r < 4; ++r) {
      int o = wm0 + mi * 16 + g2 * 4 + r;
      float bias = conv_b[o];
#pragma unroll
      for (int ni = 0; ni < 2; ++ni) {
        float s = acc[mi][ni][r] + bias;
        float v = 0.5f * s * (1.0f + erff(s * 0.70710678118654752f));
        Bs[(ni * 16 + hq) * 264 + o] = bfb(v);
      }
    }
  }
  __syncthreads();

  // column pass: thread t = channel o; pool 32 rows + vectorized store
  {
    const int o = t;
    float sm = 0.f, mx = -1e30f;
    unsigned pk[16];
#pragma unroll
    for (int m = 0; m < 16; ++m) {
      unsigned short r0 = Bs[(2 * m) * 264 + o];
      unsigned short r1 = Bs[(2 * m + 1) * 264 + o];
      float f0 = bf2f(r0), f1 = bf2f(r1);
      sm += f0 + f1;
      mx = fmaxf(mx, fmaxf(f0, f1));
      pk[m] = (unsigned)r0 | ((unsigned)r1 << 16);
    }
    unsigned short* hp = h_out + ((size_t)(b * 256 + o)) * HW + hw0;
#pragma unroll
    for (int q = 0; q < 4; ++q) {
      uint4 s4;
      s4.x = pk[q * 4 + 0]; s4.y = pk[q * 4 + 1]; s4.z = pk[q * 4 + 2]; s4.w = pk[q * 4 + 3];
      *(uint4*)(hp + q * 8) = s4;
    }
    atomicAdd(psum + b * 256 + o, sm);
    atomicMax(pmaxe + b * 256 + o, fenc(mx));
  }
}

// ---------------- K2: channel attention FCs (4-way c-split FC1) ----------------
__global__ __launch_bounds__(256) void k2_att(
    const float* __restrict__ psum, const unsigned* __restrict__ pmaxe,
    const float* __restrict__ fc1_w, const float* __restrict__ fc1_b,
    const float* __restrict__ fc2_w, const float* __restrict__ fc2_b,
    float* __restrict__ att)
{
  const int b = blockIdx.x, t = threadIdx.x;
  __shared__ float pA[4][64], pM[4][64];
  __shared__ float hA[64], hM[64];
  {
    const int j = t & 63, seg = t >> 6;
    const int base = b * 256 + seg * 64;
    const float* wrow = fc1_w + j * 256 + seg * 64;
    float sA = 0.f, sM = 0.f;
#pragma unroll 8
    for (int c = 0; c < 64; ++c) {
      float wv = wrow[c];
      sA += psum[base + c] * wv;
      sM += fdec(pmaxe[base + c]) * wv;
    }
    pA[seg][j] = sA;
    pM[seg][j] = sM;
  }
  __syncthreads();
  if (t < 64) {
    float a = fc1_b[t] + (pA[0][t] + pA[1][t] + pA[2][t] + pA[3][t]) * (1.f / 3136.f);
    float m = fc1_b[t] + (pM[0][t] + pM[1][t] + pM[2][t] + pM[3][t]);
    hA[t] = fmaxf(a, 0.f);
    hM[t] = fmaxf(m, 0.f);
  }
  __syncthreads();
  float s1 = fc2_b[t], s2 = s1;
#pragma unroll 8
  for (int j = 0; j < 64; ++j) {
    float wv = fc2_w[t * 64 + j];
    s1 += hA[j] * wv;
    s2 += hM[j] * wv;
  }
  att[b * 256 + t] = 1.f / (1.f + expf(-s1)) + 1.f / (1.f + expf(-s2));
}

// ---------------- K34 v13 (unchanged): fused depthwise chain, one plane per block ----------------
__global__ __launch_bounds__(256) void k34_dw(
    const unsigned short* __restrict__ h_in, const float* __restrict__ att,
    const float* __restrict__ w5, const float* __restrict__ b5,
    const float* __restrict__ w1x7, const float* __restrict__ b1x7,
    const float* __restrict__ w7x1, const float* __restrict__ b7x1,
    const float* __restrict__ w1x11, const float* __restrict__ b1x11,
    const float* __restrict__ w11x1, const float* __restrict__ b11x1,
    const float* __restrict__ w1x21, const float* __restrict__ b1x21,
    const float* __restrict__ w21x1, const float* __restrict__ b21x1,
    unsigned short* __restrict__ xs_out)
{
  __shared__ __align__(16) unsigned short B0h[4480];
  __shared__ __align__(16) unsigned short T1[62 * 56];  // r = y+3
  __shared__ __align__(16) unsigned short T2[66 * 56];  // r = y+5
  __shared__ __align__(16) unsigned short T3[76 * 56];  // r = y+10
  __shared__ __align__(16) float wk5a[25];
  __shared__ __align__(16) float wk[78]; // [0,7)w1x7 [7,14)w7x1 [14,25)w1x11 [25,36)w11x1 [36,57)w1x21 [57,78)w21x1

  const int bid = blockIdx.x;
  const int b = bid >> 8, c = bid & 255;
  const int t = threadIdx.x;
  const size_t plane = (size_t)(b * 256 + c) * HW;
  const float a = att[b * 256 + c];

  if (t < 25) wk5a[t] = w5[c * 25 + t] * a;
  if (t >= 32 && t < 110) {
    int k = t - 32;
    float v;
    if (k < 7) v = w1x7[c * 7 + k];
    else if (k < 14) v = w7x1[c * 7 + k - 7];
    else if (k < 25) v = w1x11[c * 11 + k - 14];
    else if (k < 36) v = w11x1[c * 11 + k - 25];
    else if (k < 57) v = w1x21[c * 21 + k - 36];
    else v = w21x1[c * 21 + k - 57];
    wk[k] = v;
  }
  {
    unsigned* T1d = (unsigned*)T1; unsigned* T2d = (unsigned*)T2; unsigned* T3d = (unsigned*)T3;
    for (int i = t; i < 1008; i += 256) {
      if (i < 84) T1d[i] = 0;
      else if (i < 168) T1d[1652 + i - 84] = 0;
      else if (i < 308) T2d[i - 168] = 0;
      else if (i < 448) T2d[1708 + i - 308] = 0;
      else if (i < 728) T3d[i - 448] = 0;
      else T3d[1848 + i - 728] = 0;
    }
  }
  { // P0: stage halo'd h (bf16, rows/cols -2..57) into B0h[60][60] — pure copy, u32 pairs
    const unsigned short* hp = h_in + plane;
    unsigned* Bd = (unsigned*)B0h;
    for (int i = t; i < 1800; i += 256) {  // 30 u32 per row (60 u16)
      int ly = i / 30, e = i - ly * 30;
      int gy = ly - 2, lx0 = 2 * e - 2;
      unsigned val = 0;
      if ((unsigned)gy < 56u) {
        if (lx0 >= 0 && lx0 + 1 < 56) {
          val = *(const unsigned*)&hp[gy * 56 + lx0];
        } else {
          unsigned short aa = ((unsigned)lx0 < 56u) ? hp[gy * 56 + lx0] : (unsigned short)0;
          unsigned short bb = ((unsigned)(lx0 + 1) < 56u) ? hp[gy * 56 + lx0 + 1] : (unsigned short)0;
          val = (unsigned)aa | ((unsigned)bb << 16);
        }
      }
      Bd[i] = val;
    }
  }
  __syncthreads();

  // P1: dw5x5 -> registers. 4x4 task: band=t/14 (y0=4*band), quad=t%14 (x0=4*quad).
  const int band = t / 14, quad = t - band * 14;
  const int y0 = band * 4, x0 = quad * 4;
  f32x2 aL[4], aH[4];
  {
    const float bias5 = b5[c];
#pragma unroll
    for (int d = 0; d < 4; ++d) {
      aL[d].x = bias5; aL[d].y = bias5;
      aH[d].x = bias5; aH[d].y = bias5;
    }
  }
  if (t < 196) {
    const unsigned* Bd = (const unsigned*)B0h;
#pragma unroll
    for (int r = 0; r < 8; ++r) {
      const int base = (y0 + r) * 30 + 2 * quad;
      uint2 qa = *(const uint2*)(Bd + base);
      uint2 qb = *(const uint2*)(Bd + base + 2);
      uint2 qc = *(const uint2*)(Bd + base + 4);
      float win[10];
      win[0] = lo16f(qa.x); win[1] = hi16f(qa.x);
      win[2] = lo16f(qa.y); win[3] = hi16f(qa.y);
      win[4] = lo16f(qb.x); win[5] = hi16f(qb.x);
      win[6] = lo16f(qb.y); win[7] = hi16f(qb.y);
      win[8] = lo16f(qc.x); win[9] = hi16f(qc.x);
#pragma unroll
      for (int d = 0; d < 4; ++d) {
        const int ky = r - d;
        if (ky < 0 || ky > 4) continue;
#pragma unroll
        for (int kx = 0; kx < 5; ++kx) {
          float wv = wk5a[ky * 5 + kx];
          f32x2 pL; pL.x = win[kx];     pL.y = win[kx + 1];
          f32x2 pH; pH.x = win[kx + 2]; pH.y = win[kx + 3];
          aL[d] = aL[d] + pL * wv;
          aH[d] = aH[d] + pH * wv;
        }
      }
    }
  }
  __syncthreads();

  // P2: write x_init (bf16) to B0h overlay [56][80] (data at u16 col+10); zero col pads.
  if (t < 196) {
    unsigned* Bd = (unsigned*)B0h;
#pragma unroll
    for (int d = 0; d < 4; ++d) {
      Bd[(y0 + d) * 40 + 5 + 2 * quad] = pack2(aL[d].x, aL[d].y);
      Bd[(y0 + d) * 40 + 6 + 2 * quad] = pack2(aH[d].x, aH[d].y);
    }
  }
  {
    unsigned* Bd = (unsigned*)B0h;
    for (int i = t; i < 672; i += 256) {
      int y = i / 12, j = i - y * 12;
      int u32col = (j < 5) ? j : (28 + j);
      Bd[y * 40 + u32col] = 0;
    }
  }
  __syncthreads();

  // PA: fused horizontal convs. ROW task (y, xa0..xa0+7).
  const float bb1 = b1x7[c], bb2 = b1x11[c], bb3 = b1x21[c];
#pragma unroll
  for (int rnd = 0; rnd < 2; ++rnd) {
    if (rnd == 1 && t >= 136) break;
    int tau = t + rnd * 256;
    int y = tau / 7, xa0 = (tau - y * 7) * 8;
    const unsigned* wp = (const unsigned*)B0h + y * 40 + (xa0 >> 1);
    uint4 qa = *(const uint4*)(wp);
    uint4 qb = *(const uint4*)(wp + 4);
    uint4 qc = *(const uint4*)(wp + 8);
    uint2 qd = *(const uint2*)(wp + 12);
    float win[28];
    win[0]  = lo16f(qa.x); win[1]  = hi16f(qa.x);
    win[2]  = lo16f(qa.y); win[3]  = hi16f(qa.y);
    win[4]  = lo16f(qa.z); win[5]  = hi16f(qa.z);
    win[6]  = lo16f(qa.w); win[7]  = hi16f(qa.w);
    win[8]  = lo16f(qb.x); win[9]  = hi16f(qb.x);
    win[10] = lo16f(qb.y); win[11] = hi16f(qb.y);
    win[12] = lo16f(qb.z); win[13] = hi16f(qb.z);
    win[14] = lo16f(qb.w); win[15] = hi16f(qb.w);
    win[16] = lo16f(qc.x); win[17] = hi16f(qc.x);
    win[18] = lo16f(qc.y); win[19] = hi16f(qc.y);
    win[20] = lo16f(qc.z); win[21] = hi16f(qc.z);
    win[22] = lo16f(qc.w); win[23] = hi16f(qc.w);
    win[24] = lo16f(qd.x); win[25] = hi16f(qd.x);
    win[26] = lo16f(qd.y); win[27] = hi16f(qd.y);
    float o1[8], o2[8], o3[8];
#pragma unroll
    for (int d = 0; d < 8; ++d) { o1[d] = bb1; o2[d] = bb2; o3[d] = bb3; }
#pragma unroll
    for (int k = 0; k < 7; ++k) {
      float wv = wk[k];
#pragma unroll
      for (int d = 0; d < 8; ++d) o1[d] += win[d + k + 7] * wv;
    }
#pragma unroll
    for (int k = 0; k < 11; ++k) {
      float wv = wk[14 + k];
#pragma unroll
      for (int d = 0; d < 8; ++d) o2[d] += win[d + k + 5] * wv;
    }
#pragma unroll
    for (int k = 0; k < 21; ++k) {
      float wv = wk[36 + k];
#pragma unroll
      for (int d = 0; d < 8; ++d) o3[d] += win[d + k] * wv;
    }
    uint4 s1, s2, s3;
    s1.x = pack2(o1[0], o1[1]); s1.y = pack2(o1[2], o1[3]); s1.z = pack2(o1[4], o1[5]); s1.w = pack2(o1[6], o1[7]);
    s2.x = pack2(o2[0], o2[1]); s2.y = pack2(o2[2], o2[3]); s2.z = pack2(o2[4], o2[5]); s2.w = pack2(o2[6], o2[7]);
    s3.x = pack2(o3[0], o3[1]); s3.y = pack2(o3[2], o3[3]); s3.z = pack2(o3[4], o3[5]); s3.w = pack2(o3[6], o3[7]);
    *(uint4*)&T1[(y + 3) * 56 + xa0] = s1;
    *(uint4*)&T2[(y + 5) * 56 + xa0] = s2;
    *(uint4*)&T3[(y + 10) * 56 + xa0] = s3;
  }
  __syncthreads();

  // PB: fused vertical convs, 4x4 task. One b64 per T row, immediate consume.
  const float vb = b7x1[c] + b11x1[c] + b21x1[c];
  unsigned short* op = xs_out + plane;
  if (t < 196) {
    f32x2 rL[4], rH[4];
#pragma unroll
    for (int d = 0; d < 4; ++d) { rL[d] = aL[d] + vb; rH[d] = aH[d] + vb; }
    {
      const unsigned* T1d = (const unsigned*)T1;
#pragma unroll
      for (int j = 0; j < 10; ++j) {
        uint2 q = *(const uint2*)(T1d + (y0 + j) * 28 + 2 * quad);
        f32x2 cL; cL.x = lo16f(q.x); cL.y = hi16f(q.x);
        f32x2 cH; cH.x = lo16f(q.y); cH.y = hi16f(q.y);
#pragma unroll
        for (int d = 0; d < 4; ++d) {
          const int k = j - d;
          if (k < 0 || k > 6) continue;
          float wv = wk[7 + k];
          rL[d] = rL[d] + cL * wv;
          rH[d] = rH[d] + cH * wv;
        }
      }
    }
    {
      const unsigned* T2d = (const unsigned*)T2;
#pragma unroll
      for (int j = 0; j < 14; ++j) {
        uint2 q = *(const uint2*)(T2d + (y0 + j) * 28 + 2 * quad);
        f32x2 cL; cL.x = lo16f(q.x); cL.y = hi16f(q.x);
        f32x2 cH; cH.x = lo16f(q.y); cH.y = hi16f(q.y);
#pragma unroll
        for (int d = 0; d < 4; ++d) {
          const int k = j - d;
          if (k < 0 || k > 10) continue;
          float wv = wk[25 + k];
          rL[d] = rL[d] + cL * wv;
          rH[d] = rH[d] + cH * wv;
        }
      }
    }
    {
      const unsigned* T3d = (const unsigned*)T3;
#pragma unroll
      for (int j = 0; j < 24; ++j) {
        uint2 q = *(const uint2*)(T3d + (y0 + j) * 28 + 2 * quad);
        f32x2 cL; cL.x = lo16f(q.x); cL.y = hi16f(q.x);
        f32x2 cH; cH.x = lo16f(q.y); cH.y = hi16f(q.y);
#pragma unroll
        for (int d = 0; d < 4; ++d) {
          const int k = j - d;
          if (k < 0 || k > 20) continue;
          float wv = wk[57 + k];
          rL[d] = rL[d] + cL * wv;
          rH[d] = rH[d] + cH * wv;
        }
      }
    }
#pragma unroll
    for (int d = 0; d < 4; ++d) {
      uint2 s;
      s.x = pack2(rL[d].x, rL[d].y);
      s.y = pack2(rH[d].x, rH[d].y);
      *(uint2*)&op[(y0 + d) * 56 + x0] = s;
    }
  }
}

// ---------------- K5: spatial_att = W*xs+b ; out = sa*(att*h) ; result = W*out+b ----------------
__global__ __launch_bounds__(256) void k5_final(
    const unsigned short* __restrict__ xs, const unsigned short* __restrict__ Wbf,
    const float* __restrict__ conv_b, const float* __restrict__ att,
    const unsigned short* __restrict__ h_in, float* __restrict__ outp)
{
  __shared__ __align__(16) unsigned short Bs[64 * 264];
  const int bid = blockIdx.x;
  const int b = bid / 49, tile = bid - 49 * (bid / 49);
  const int hw0 = tile * 64;
  const int t = threadIdx.x;

  { // stage xs (bf16) transposed into LDS, ushort8 (16B) loads
    int g = t & 127, half = t >> 7;
    const unsigned short* p0 = xs + ((size_t)(b * 256 + 2 * g)) * HW + hw0 + half * 32;
    const unsigned short* p1 = p0 + HW;
    unsigned* Bd = (unsigned*)Bs;
#pragma unroll
    for (int i = 0; i < 32; i += 8) {
      ushort8 a8 = *(const ushort8*)(p0 + i);
      ushort8 c8 = *(const ushort8*)(p1 + i);
      int hw = half * 32 + i;
#pragma unroll
      for (int e = 0; e < 8; ++e)
        Bd[(hw + e) * 132 + g] = (unsigned)a8[e] | ((unsigned)c8[e] << 16);
    }
  }
  __syncthreads();

  const int w = t >> 6, l = t & 63, hq = l & 15, g2 = l >> 4;
  const int wm0 = w * 64;
  const f32x4 vzero = {0.f, 0.f, 0.f, 0.f};
  f32x4 acc[4][4];
#pragma unroll
  for (int mi = 0; mi < 4; ++mi)
#pragma unroll
    for (int ni = 0; ni < 4; ++ni) acc[mi][ni] = vzero;

#pragma unroll
  for (int ks = 0; ks < 8; ++ks) {
    short8 a[4], bv[4];
#pragma unroll
    for (int mi = 0; mi < 4; ++mi)
      a[mi] = *(const short8*)(Wbf + (size_t)(wm0 + mi * 16 + hq) * 256 + ks * 32 + g2 * 8);
#pragma unroll
    for (int ni = 0; ni < 4; ++ni)
      bv[ni] = *(const short8*)(Bs + (ni * 16 + hq) * 264 + ks * 32 + g2 * 8);
#pragma unroll
    for (int mi = 0; mi < 4; ++mi)
#pragma unroll
      for (int ni = 0; ni < 4; ++ni)
        acc[mi][ni] = __builtin_amdgcn_mfma_f32_16x16x32_bf16(a[mi], bv[ni], acc[mi][ni], 0, 0, 0);
  }
  __syncthreads();

#pragma unroll
  for (int mi = 0; mi < 4; ++mi) {
#pragma unroll
    for (int r = 0; r < 4; ++r) {
      int o = wm0 + mi * 16 + g2 * 4 + r;
      float bias = conv_b[o];
      float av = att[b * 256 + o];
      const unsigned short* hp = h_in + ((size_t)(b * 256 + o)) * HW + hw0;
#pragma unroll
      for (int ni = 0; ni < 4; ++ni) {
        float sa = acc[mi][ni][r] + bias;
        float ov = sa * (av * bf2f(hp[ni * 16 + hq]));
        Bs[(ni * 16 + hq) * 264 + o] = bfb(ov);
      }
    }
  }
  __syncthreads();

  f32x4 acc2[4][4];
#pragma unroll
  for (int mi = 0; mi < 4; ++mi)
#pragma unroll
    for (int ni = 0; ni < 4; ++ni) acc2[mi][ni] = vzero;
#pragma unroll
  for (int ks = 0; ks < 8; ++ks) {
    short8 a[4], bv[4];
#pragma unroll
    for (int mi = 0; mi < 4; ++mi)
      a[mi] = *(const short8*)(Wbf + (size_t)(wm0 + mi * 16 + hq) * 256 + ks * 32 + g2 * 8);
#pragma unroll
    for (int ni = 0; ni < 4; ++ni)
      bv[ni] = *(const short8*)(Bs + (ni * 16 + hq) * 264 + ks * 32 + g2 * 8);
#pragma unroll
    for (int mi = 0; mi < 4; ++mi)
#pragma unroll
      for (int ni = 0; ni < 4; ++ni)
        acc2[mi][ni] = __builtin_amdgcn_mfma_f32_16x16x32_bf16(a[mi], bv[ni], acc2[mi][ni], 0, 0, 0);
  }

#pragma unroll
  for (int mi = 0; mi < 4; ++mi) {
#pragma unroll
    for (int r = 0; r < 4; ++r) {
      int o = wm0 + mi * 16 + g2 * 4 + r;
      float bias = conv_b[o];
      float* op = outp + ((size_t)(b * 256 + o)) * HW + hw0;
#pragma unroll
      for (int ni = 0; ni < 4; ++ni) op[ni * 16 + hq] = acc2[mi][ni][r] + bias;
    }
  }
}

extern "C" void kernel_launch(void* const* d_in, const int* in_sizes, int n_in,
                              void* d_out, int out_size, void* d_ws, size_t ws_size,
                              hipStream_t stream) {
  const float* x      = (const float*)d_in[0];
  const float* conv_w = (const float*)d_in[1];
  const float* conv_b = (const float*)d_in[2];
  const float* fc1_w  = (const float*)d_in[3];
  const float* fc1_b  = (const float*)d_in[4];
  const float* fc2_w  = (const float*)d_in[5];
  const float* fc2_b  = (const float*)d_in[6];
  const float* w5     = (const float*)d_in[7];
  const float* b5     = (const float*)d_in[8];
  const float* w1x7   = (const float*)d_in[9];
  const float* b1x7   = (const float*)d_in[10];
  const float* w7x1   = (const float*)d_in[11];
  const float* b7x1   = (const float*)d_in[12];
  const float* w1x11  = (const float*)d_in[13];
  const float* b1x11  = (const float*)d_in[14];
  const float* w11x1  = (const float*)d_in[15];
  const float* b11x1  = (const float*)d_in[16];
  const float* w1x21  = (const float*)d_in[17];
  const float* b1x21  = (const float*)d_in[18];
  const float* w21x1  = (const float*)d_in[19];
  const float* b21x1  = (const float*)d_in[20];
  float* out = (float*)d_out;

  char* ws = (char*)d_ws;
  unsigned short* Wbf = (unsigned short*)(ws);            // 131072 B
  float* psum   = (float*)(ws + 131072);                  // 16384 B
  unsigned* pme = (unsigned*)(ws + 147456);               // 16384 B
  float* attb   = (float*)(ws + 163840);                  // 16384 B
  unsigned short* hbuf = (unsigned short*)(ws + 180224);  // 25690112 B (h bf16)
  unsigned short* xbuf = (unsigned short*)(ws + 180224 + 25690112); // 25690112 B (xs bf16)

  k0_init<<<256, 256, 0, stream>>>(conv_w, Wbf, psum, pme);
  k1_conv_gelu_pool<<<1568, 256, 0, stream>>>(x, Wbf, conv_b, hbuf, psum, pme);
  k2_att<<<16, 256, 0, stream>>>(psum, pme, fc1_w, fc1_b, fc2_w, fc2_b, attb);
  k34_dw<<<4096, 256, 0, stream>>>(hbuf, attb, w5, b5, w1x7, b1x7, w7x1, b7x1,
                                   w1x11, b1x11, w11x1, b11x1, w1x21, b1x21,
                                   w21x1, b21x1, xbuf);
  k5_final<<<784, 256, 0, stream>>>(xbuf, Wbf, conv_b, attb, hbuf, out);
}